// Round 1
// baseline (16899.390 us; speedup 1.0000x reference)
//
#include <hip/hip_runtime.h>
#include <math.h>

namespace {
constexpr int kB = 32;
constexpr int kS = 500;
constexpr int kD = 256;
constexpr int kH = 8;
constexpr int kNEV = 256;
}
// -ln(10000)/127
#define LKC (-0.07252236513366287)

__device__ __forceinline__ float gelu_f(float x){
  return 0.5f * x * (1.0f + erff(x * 0.7071067811865476f));
}

// ---------------- GEMM: C[M,N] = [C +] act(A[M,K] @ W[N,K]^T + bias[N]) ----------------
// Requires M%64==0, N%64==0, K%16==0.
template<bool DOGELU, bool ACC>
__global__ __launch_bounds__(256) void gemm64(const float* __restrict__ A,
    const float* __restrict__ W, const float* __restrict__ bias,
    float* __restrict__ C, int M, int N, int K){
  __shared__ __align__(16) float As[16][64];
  __shared__ __align__(16) float Bs[16][64];
  const int t  = threadIdx.x;
  const int m0 = blockIdx.y * 64, n0 = blockIdx.x * 64;
  const int tm = t & 15, tn = t >> 4;
  const int lr = t >> 2, lk = (t & 3) * 4;
  float acc[4][4] = {};
  const float* Ap = A + (size_t)(m0 + lr) * K + lk;
  const float* Wp = W + (size_t)(n0 + lr) * K + lk;
  for(int k0 = 0; k0 < K; k0 += 16){
    float4 av = *(const float4*)(Ap + k0);
    float4 wv = *(const float4*)(Wp + k0);
    As[lk+0][lr]=av.x; As[lk+1][lr]=av.y; As[lk+2][lr]=av.z; As[lk+3][lr]=av.w;
    Bs[lk+0][lr]=wv.x; Bs[lk+1][lr]=wv.y; Bs[lk+2][lr]=wv.z; Bs[lk+3][lr]=wv.w;
    __syncthreads();
    #pragma unroll
    for(int kk = 0; kk < 16; ++kk){
      float4 a4 = *(const float4*)&As[kk][tm*4];
      float4 b4 = *(const float4*)&Bs[kk][tn*4];
      float ar[4] = {a4.x, a4.y, a4.z, a4.w};
      float br[4] = {b4.x, b4.y, b4.z, b4.w};
      #pragma unroll
      for(int i = 0; i < 4; ++i)
        #pragma unroll
        for(int j = 0; j < 4; ++j)
          acc[i][j] += ar[i] * br[j];
    }
    __syncthreads();
  }
  #pragma unroll
  for(int i = 0; i < 4; ++i){
    int m = m0 + tm*4 + i;
    float* cp = C + (size_t)m * N + n0 + tn*4;
    #pragma unroll
    for(int j = 0; j < 4; ++j){
      float v = acc[i][j] + bias[n0 + tn*4 + j];
      if(DOGELU) v = gelu_f(v);
      if(ACC) cp[j] += v; else cp[j] = v;
    }
  }
}

// ---------------- mel compress: (B,80,2000) -> (B,16,2000) ----------------
__global__ __launch_bounds__(256) void mel_kernel(const float* __restrict__ mel,
    const float* __restrict__ W, const float* __restrict__ bias, float* __restrict__ xm){
  __shared__ float Ws[16][80];
  __shared__ float bs[16];
  const int t = threadIdx.x;
  for(int i = t; i < 16*80; i += 256) Ws[i/80][i%80] = W[i];
  if(t < 16) bs[t] = bias[t];
  __syncthreads();
  int blk = blockIdx.x;
  int b = blk >> 3;
  int tc = (blk & 7) * 256 + t;
  if(tc >= 2000) return;
  float acc[16];
  #pragma unroll
  for(int o = 0; o < 16; ++o) acc[o] = bs[o];
  for(int c = 0; c < 80; ++c){
    float v = mel[((size_t)b*80 + c)*2000 + tc];
    #pragma unroll
    for(int o = 0; o < 16; ++o) acc[o] += v * Ws[o][c];
  }
  #pragma unroll
  for(int o = 0; o < 16; ++o) xm[((size_t)b*16 + o)*2000 + tc] = acc[o];
}

// ---------------- im2col for conv1: A[(b*1000+t1), 16*7] ----------------
__global__ __launch_bounds__(256) void im2col1(const float* __restrict__ xm, float* __restrict__ A){
  size_t idx = (size_t)blockIdx.x * 256 + threadIdx.x; // 32000*112 exact
  int col = idx % 112;
  size_t row = idx / 112;
  int t1 = row % 1000, b = row / 1000;
  int i = col / 7, k = col % 7;
  int src = 2*t1 + k - 3;
  A[idx] = (src >= 0 && src < 2000) ? xm[((size_t)b*16 + i)*2000 + src] : 0.f;
}

// ---------------- GroupNorm(1) stats over h1 (B,1000,128) ----------------
__global__ __launch_bounds__(256) void gn_stats(const float* __restrict__ h1, float* __restrict__ stats){
  int b = blockIdx.x, t = threadIdx.x;
  __shared__ double rs[256], rq[256];
  double s = 0, q = 0;
  const float* p = h1 + (size_t)b * 128000;
  for(int i = t; i < 128000; i += 256){ double v = p[i]; s += v; q += v*v; }
  rs[t] = s; rq[t] = q; __syncthreads();
  for(int s2 = 128; s2 > 0; s2 >>= 1){
    if(t < s2){ rs[t] += rs[t+s2]; rq[t] += rq[t+s2]; }
    __syncthreads();
  }
  if(t == 0){
    double mean = rs[0] / 128000.0;
    double var  = rq[0] / 128000.0 - mean*mean;
    stats[b*2]   = (float)mean;
    stats[b*2+1] = (float)(1.0 / sqrt(var + 1e-5));
  }
}

// ---------------- im2col for conv2 with fused GroupNorm ----------------
__global__ __launch_bounds__(256) void im2col2(const float* __restrict__ h1,
    const float* __restrict__ stats, const float* __restrict__ gg,
    const float* __restrict__ gb, float* __restrict__ A){
  size_t idx = (size_t)blockIdx.x * 256 + threadIdx.x; // 16000*896 exact
  int col = idx % 896;
  size_t row = idx / 896;
  int t2 = row % 500, b = row / 500;
  int i = col / 7, k = col % 7;
  int src = 2*t2 + k - 3;
  float v = 0.f;
  if(src >= 0 && src < 1000){
    float raw = h1[((size_t)b*1000 + src)*128 + i];
    v = (raw - stats[b*2]) * stats[b*2+1] * gg[i] + gb[i];
  }
  A[idx] = v;
}

// ---------------- post-conv: LN(D) + sinpos + star table -> X ----------------
__global__ __launch_bounds__(256) void postconv(const float* __restrict__ xp,
    const float* __restrict__ cg, const float* __restrict__ cb,
    const float* __restrict__ star, const float* __restrict__ stab,
    float* __restrict__ x){
  int row = blockIdx.x, t = threadIdx.x;
  int s = row % 500, b = row / 500;
  __shared__ float red[256];
  float v = xp[(size_t)row*256 + t];
  red[t] = v; __syncthreads();
  for(int s2 = 128; s2 > 0; s2 >>= 1){ if(t < s2) red[t] += red[t+s2]; __syncthreads(); }
  float mean = red[0] / 256.f; __syncthreads();
  float d = v - mean;
  red[t] = d*d; __syncthreads();
  for(int s2 = 128; s2 > 0; s2 >>= 1){ if(t < s2) red[t] += red[t+s2]; __syncthreads(); }
  float rstd = 1.f / sqrtf(red[0]/256.f + 1e-5f);
  int j = t & 127;
  double f = exp((double)j * LKC);
  double a = (double)s * f;
  float pe = (float)(t < 128 ? sin(a) : cos(a));
  int bucket = (int)(star[b] * 2.0f);
  bucket = bucket < 0 ? 0 : (bucket > 19 ? 19 : bucket);
  x[(size_t)row*256 + t] = d*rstd*cg[t] + cb[t] + pe + stab[bucket*256 + t];
}

// ---------------- event features -> combined (B*NEV, 768) ----------------
__global__ __launch_bounds__(256) void event_feat(const int* __restrict__ events, float* __restrict__ comb){
  int blk = blockIdx.x;           // 8192
  int e = blk & 255, b = blk >> 8;
  const int* ev = events + b*256;
  int t = threadIdx.x;
  auto gof = [&](int i){ int j = i < 1 ? 1 : i; int d = ev[j] - ev[j-1]; return d < 1 ? 1 : d; };
  int gi = gof(e);
  double rb = 1.0, ra = 1.0;
  if(e != 0){
    rb = (double)gi / (double)gof(e-1);
    rb = rb < 0.1 ? 0.1 : (rb > 10.0 ? 10.0 : rb);
  }
  if(e != 255){
    ra = (double)gof(e+1) / (double)gi;
    ra = ra < 0.1 ? 0.1 : (ra > 10.0 ? 10.0 : ra);
  }
  int rbi = (int)(rb * 50.0);
  int rai = (int)(ra * 50.0);
  int gap = 5 * gi;
  int j = t & 127;
  double f = exp((double)j * LKC);
  double a0 = (double)rbi * f, a1 = (double)rai * f, a2 = (double)gap * f;
  size_t base = (size_t)blk * 768;
  comb[base + t]       = (float)(t < 128 ? sin(a0) : cos(a0));
  comb[base + 256 + t] = (float)(t < 128 ? sin(a1) : cos(a1));
  comb[base + 512 + t] = (float)(t < 128 ? sin(a2) : cos(a2));
}

// ---------------- scatter-add events into X ----------------
__global__ __launch_bounds__(256) void ev_scatter(const float* __restrict__ evout,
    const int* __restrict__ events, const unsigned char* __restrict__ mask,
    float* __restrict__ x){
  int blk = blockIdx.x; // 8192
  int e = blk & 255, b = blk >> 8;
  if(mask[b*256 + e]) return;
  int tp = events[b*256 + e] >> 2;
  tp = tp < 0 ? 0 : (tp > 499 ? 499 : tp);
  int t = threadIdx.x;
  atomicAdd(&x[((size_t)b*500 + tp)*256 + t], evout[(size_t)blk*256 + t]);
}

// ---------------- LayerNorm rows of 256 ----------------
__global__ __launch_bounds__(256) void ln_rows(const float* __restrict__ x,
    const float* __restrict__ g, const float* __restrict__ b, float* __restrict__ out){
  int row = blockIdx.x, t = threadIdx.x;
  __shared__ float red[256];
  float v = x[(size_t)row*256 + t];
  red[t] = v; __syncthreads();
  for(int s2 = 128; s2 > 0; s2 >>= 1){ if(t < s2) red[t] += red[t+s2]; __syncthreads(); }
  float mean = red[0] / 256.f; __syncthreads();
  float d = v - mean;
  red[t] = d*d; __syncthreads();
  for(int s2 = 128; s2 > 0; s2 >>= 1){ if(t < s2) red[t] += red[t+s2]; __syncthreads(); }
  float rstd = 1.f / sqrtf(red[0]/256.f + 1e-5f);
  out[(size_t)row*256 + t] = d*rstd*g[t] + b[t];
}

// ---------------- attention: qkv (B,S,768) -> o (B,S,256) ----------------
__global__ __launch_bounds__(256) void attn_kernel(const float* __restrict__ qkv, float* __restrict__ o){
  int blk = blockIdx.x;              // B*H*20
  int qb = blk % 20;
  int bh = blk / 20;
  int h = bh % 8, b = bh / 8;
  const int t = threadIdx.x;
  __shared__ float qs[32];
  __shared__ float sc[500];
  __shared__ float red[256];
  const float scale = 0.17677669529663687f; // 1/sqrt(32)
  const float* base = qkv + (size_t)b * kS * 768;
  for(int q = qb*25; q < qb*25 + 25; ++q){
    if(t < 32) qs[t] = base[(size_t)q*768 + h*32 + t] * scale;
    __syncthreads();
    for(int k = t; k < 500; k += 256){
      const float* kp = base + (size_t)k*768 + 256 + h*32;
      float d = 0.f;
      #pragma unroll
      for(int dd = 0; dd < 32; ++dd) d += qs[dd] * kp[dd];
      sc[k] = d;
    }
    __syncthreads();
    float m = -1e30f;
    for(int k = t; k < 500; k += 256) m = fmaxf(m, sc[k]);
    red[t] = m; __syncthreads();
    for(int s2 = 128; s2 > 0; s2 >>= 1){ if(t < s2) red[t] = fmaxf(red[t], red[t+s2]); __syncthreads(); }
    m = red[0]; __syncthreads();
    float ps = 0.f;
    for(int k = t; k < 500; k += 256){ float e = expf(sc[k] - m); sc[k] = e; ps += e; }
    red[t] = ps; __syncthreads();
    for(int s2 = 128; s2 > 0; s2 >>= 1){ if(t < s2) red[t] += red[t+s2]; __syncthreads(); }
    float inv = 1.f / red[0];
    __syncthreads();
    int d = t & 31, grp = t >> 5;   // 8 groups of 32
    const float* vbase = base + 512 + h*32 + d;
    float acc = 0.f;
    for(int k = grp; k < 500; k += 8) acc += sc[k] * vbase[(size_t)k * 768];
    red[t] = acc; __syncthreads();
    if(t < 32){
      float s_ = 0.f;
      #pragma unroll
      for(int g2 = 0; g2 < 8; ++g2) s_ += red[g2*32 + t];
      o[((size_t)(b*kS + q))*256 + h*32 + t] = s_ * inv;
    }
    __syncthreads();
  }
}

// ---------------- attention pooling + LN + head ----------------
__global__ __launch_bounds__(256) void pool_head(const float* __restrict__ x,
    const float* __restrict__ pq, const float* __restrict__ og, const float* __restrict__ ob,
    const float* __restrict__ ohW, const float* __restrict__ ohb, float* __restrict__ out){
  int b = blockIdx.x, t = threadIdx.x;
  __shared__ float lg[500];
  __shared__ float red[256];
  const float* xb = x + (size_t)b * 500 * 256;
  for(int s = t; s < 500; s += 256){
    const float* xr = xb + (size_t)s * 256;
    float d = 0.f;
    for(int c = 0; c < 256; ++c) d += xr[c] * pq[c];
    lg[s] = d * 0.0625f; // / sqrt(256)
  }
  __syncthreads();
  float m = -1e30f;
  for(int s = t; s < 500; s += 256) m = fmaxf(m, lg[s]);
  red[t] = m; __syncthreads();
  for(int s2 = 128; s2 > 0; s2 >>= 1){ if(t < s2) red[t] = fmaxf(red[t], red[t+s2]); __syncthreads(); }
  m = red[0]; __syncthreads();
  float ps = 0.f;
  for(int s = t; s < 500; s += 256){ float e = expf(lg[s] - m); lg[s] = e; ps += e; }
  red[t] = ps; __syncthreads();
  for(int s2 = 128; s2 > 0; s2 >>= 1){ if(t < s2) red[t] += red[t+s2]; __syncthreads(); }
  float inv = 1.f / red[0];
  __syncthreads();
  float acc = 0.f;
  for(int s = 0; s < 500; ++s) acc += lg[s] * xb[(size_t)s*256 + t];
  acc *= inv;                       // pooled[t]
  __syncthreads();
  red[t] = acc; __syncthreads();
  for(int s2 = 128; s2 > 0; s2 >>= 1){ if(t < s2) red[t] += red[t+s2]; __syncthreads(); }
  float mean = red[0] / 256.f; __syncthreads();
  float d = acc - mean;
  red[t] = d*d; __syncthreads();
  for(int s2 = 128; s2 > 0; s2 >>= 1){ if(t < s2) red[t] += red[t+s2]; __syncthreads(); }
  float rstd = 1.f / sqrtf(red[0]/256.f + 1e-5f);
  __syncthreads();
  float val = (d*rstd*og[t] + ob[t]) * ohW[t];
  red[t] = val; __syncthreads();
  for(int s2 = 128; s2 > 0; s2 >>= 1){ if(t < s2) red[t] += red[t+s2]; __syncthreads(); }
  if(t == 0) out[b] = red[0] + ohb[0];
}

extern "C" void kernel_launch(void* const* d_in, const int* in_sizes, int n_in,
                              void* d_out, int out_size, void* d_ws, size_t ws_size,
                              hipStream_t stream){
  const float* mel      = (const float*)d_in[0];
  const int*   events   = (const int*)d_in[1];
  const unsigned char* emask = (const unsigned char*)d_in[2];
  const float* star     = (const float*)d_in[3];
  const float* mel_W    = (const float*)d_in[4];
  const float* mel_b    = (const float*)d_in[5];
  const float* conv1_w  = (const float*)d_in[6];
  const float* conv1_b  = (const float*)d_in[7];
  const float* gn_g     = (const float*)d_in[8];
  const float* gn_b     = (const float*)d_in[9];
  const float* conv2_w  = (const float*)d_in[10];
  const float* conv2_b  = (const float*)d_in[11];
  const float* cn_g     = (const float*)d_in[12];
  const float* cn_b     = (const float*)d_in[13];
  const float* star_tab = (const float*)d_in[14];
  const float* ep_W1    = (const float*)d_in[15];
  const float* ep_b1    = (const float*)d_in[16];
  const float* ep_W2    = (const float*)d_in[17];
  const float* ep_b2    = (const float*)d_in[18];
  const float* tl_Wqkv  = (const float*)d_in[19];
  const float* tl_bqkv  = (const float*)d_in[20];
  const float* tl_Wo    = (const float*)d_in[21];
  const float* tl_bo    = (const float*)d_in[22];
  const float* tl_ln1g  = (const float*)d_in[23];
  const float* tl_ln1b  = (const float*)d_in[24];
  const float* tl_ln2g  = (const float*)d_in[25];
  const float* tl_ln2b  = (const float*)d_in[26];
  const float* tl_W1    = (const float*)d_in[27];
  const float* tl_b1    = (const float*)d_in[28];
  const float* tl_W2    = (const float*)d_in[29];
  const float* tl_b2    = (const float*)d_in[30];
  const float* pool_q   = (const float*)d_in[31];
  const float* on_g     = (const float*)d_in[32];
  const float* on_b     = (const float*)d_in[33];
  const float* oh_W     = (const float*)d_in[34];
  const float* oh_b     = (const float*)d_in[35];
  (void)in_sizes; (void)n_in; (void)out_size; (void)ws_size;

  float* ws   = (float*)d_ws;
  float* X    = ws;                 // 4,096,000 floats (B,S,D)
  float* XN   = ws + 4096000;       // 4,096,000
  float* OO   = ws + 8192000;       // 4,096,000
  float* BIG  = ws + 12288000;      // 16,384,000
  float* STATS= ws + 28672000;      // 64

  float* XMEL = OO;                 // (B,16,2000) 1.024M — dead after im2col1
  float* H1   = XN;                 // (B,1000,128) 4.096M
  float* XPRE = OO;                 // (B,S,D) conv2 out — overwrites dead XMEL
  float* COMB = BIG;                // (8192,768)
  float* EHID = BIG + 6291456;      // (8192,256)
  float* EVO  = BIG + 8388608;      // (8192,256)

  // ---- prologue ----
  mel_kernel<<<kB*8, 256, 0, stream>>>(mel, mel_W, mel_b, XMEL);
  im2col1<<<14000, 256, 0, stream>>>(XMEL, BIG);
  gemm64<true,false><<<dim3(128/64, 32000/64), 256, 0, stream>>>(BIG, conv1_w, conv1_b, H1, 32000, 128, 112);
  gn_stats<<<kB, 256, 0, stream>>>(H1, STATS);
  im2col2<<<56000, 256, 0, stream>>>(H1, STATS, gn_g, gn_b, BIG);
  gemm64<true,false><<<dim3(256/64, 16000/64), 256, 0, stream>>>(BIG, conv2_w, conv2_b, XPRE, 16000, 256, 896);
  postconv<<<16000, 256, 0, stream>>>(XPRE, cn_g, cn_b, star, star_tab, X);
  // events
  event_feat<<<kB*kNEV, 256, 0, stream>>>(events, COMB);
  gemm64<true,false><<<dim3(256/64, 8192/64), 256, 0, stream>>>(COMB, ep_W1, ep_b1, EHID, 8192, 256, 768);
  gemm64<false,false><<<dim3(256/64, 8192/64), 256, 0, stream>>>(EHID, ep_W2, ep_b2, EVO, 8192, 256, 256);
  ev_scatter<<<kB*kNEV, 256, 0, stream>>>(EVO, events, emask, X);

  // ---- transformer layers ----
  for(int i = 0; i < 6; ++i){
    ln_rows<<<16000, 256, 0, stream>>>(X, tl_ln1g + i*256, tl_ln1b + i*256, XN);
    gemm64<false,false><<<dim3(768/64, 16000/64), 256, 0, stream>>>(XN, tl_Wqkv + (size_t)i*768*256, tl_bqkv + i*768, BIG, 16000, 768, 256);
    attn_kernel<<<kB*kH*20, 256, 0, stream>>>(BIG, OO);
    gemm64<false,true><<<dim3(256/64, 16000/64), 256, 0, stream>>>(OO, tl_Wo + (size_t)i*256*256, tl_bo + i*256, X, 16000, 256, 256);
    ln_rows<<<16000, 256, 0, stream>>>(X, tl_ln2g + i*256, tl_ln2b + i*256, XN);
    gemm64<true,false><<<dim3(1024/64, 16000/64), 256, 0, stream>>>(XN, tl_W1 + (size_t)i*1024*256, tl_b1 + i*1024, BIG, 16000, 1024, 256);
    gemm64<false,true><<<dim3(256/64, 16000/64), 256, 0, stream>>>(BIG, tl_W2 + (size_t)i*256*1024, tl_b2 + i*256, X, 16000, 256, 1024);
  }

  // ---- pooling + head ----
  pool_head<<<kB, 256, 0, stream>>>(X, pool_q, on_g, on_b, oh_W, oh_b, (float*)d_out);
}

// Round 2
// 4539.772 us; speedup vs baseline: 3.7225x; 3.7225x over previous
//
#include <hip/hip_runtime.h>
#include <math.h>

namespace {
constexpr int kB = 32;
constexpr int kS = 500;
constexpr int kD = 256;
constexpr int kH = 8;
constexpr int kNEV = 256;
}
// -ln(10000)/127
#define LKC (-0.07252236513366287)

__device__ __forceinline__ float gelu_f(float x){
  return 0.5f * x * (1.0f + erff(x * 0.7071067811865476f));
}

// ---------------- GEMM: C[M,N] = [C +] act(A[M,K] @ W[N,K]^T + bias[N]) ----------------
// Requires M%64==0, N%64==0, K%16==0.
template<bool DOGELU, bool ACC>
__global__ __launch_bounds__(256) void gemm64(const float* __restrict__ A,
    const float* __restrict__ W, const float* __restrict__ bias,
    float* __restrict__ C, int M, int N, int K){
  __shared__ __align__(16) float As[16][64];
  __shared__ __align__(16) float Bs[16][64];
  const int t  = threadIdx.x;
  const int m0 = blockIdx.y * 64, n0 = blockIdx.x * 64;
  const int tm = t & 15, tn = t >> 4;
  const int lr = t >> 2, lk = (t & 3) * 4;
  float acc[4][4] = {};
  const float* Ap = A + (size_t)(m0 + lr) * K + lk;
  const float* Wp = W + (size_t)(n0 + lr) * K + lk;
  for(int k0 = 0; k0 < K; k0 += 16){
    float4 av = *(const float4*)(Ap + k0);
    float4 wv = *(const float4*)(Wp + k0);
    As[lk+0][lr]=av.x; As[lk+1][lr]=av.y; As[lk+2][lr]=av.z; As[lk+3][lr]=av.w;
    Bs[lk+0][lr]=wv.x; Bs[lk+1][lr]=wv.y; Bs[lk+2][lr]=wv.z; Bs[lk+3][lr]=wv.w;
    __syncthreads();
    #pragma unroll
    for(int kk = 0; kk < 16; ++kk){
      float4 a4 = *(const float4*)&As[kk][tm*4];
      float4 b4 = *(const float4*)&Bs[kk][tn*4];
      float ar[4] = {a4.x, a4.y, a4.z, a4.w};
      float br[4] = {b4.x, b4.y, b4.z, b4.w};
      #pragma unroll
      for(int i = 0; i < 4; ++i)
        #pragma unroll
        for(int j = 0; j < 4; ++j)
          acc[i][j] += ar[i] * br[j];
    }
    __syncthreads();
  }
  #pragma unroll
  for(int i = 0; i < 4; ++i){
    int m = m0 + tm*4 + i;
    float* cp = C + (size_t)m * N + n0 + tn*4;
    #pragma unroll
    for(int j = 0; j < 4; ++j){
      float v = acc[i][j] + bias[n0 + tn*4 + j];
      if(DOGELU) v = gelu_f(v);
      if(ACC) cp[j] += v; else cp[j] = v;
    }
  }
}

// ---------------- mel compress: (B,80,2000) -> (B,16,2000) ----------------
__global__ __launch_bounds__(256) void mel_kernel(const float* __restrict__ mel,
    const float* __restrict__ W, const float* __restrict__ bias, float* __restrict__ xm){
  __shared__ float Ws[16][80];
  __shared__ float bs[16];
  const int t = threadIdx.x;
  for(int i = t; i < 16*80; i += 256) Ws[i/80][i%80] = W[i];
  if(t < 16) bs[t] = bias[t];
  __syncthreads();
  int blk = blockIdx.x;
  int b = blk >> 3;
  int tc = (blk & 7) * 256 + t;
  if(tc >= 2000) return;
  float acc[16];
  #pragma unroll
  for(int o = 0; o < 16; ++o) acc[o] = bs[o];
  for(int c = 0; c < 80; ++c){
    float v = mel[((size_t)b*80 + c)*2000 + tc];
    #pragma unroll
    for(int o = 0; o < 16; ++o) acc[o] += v * Ws[o][c];
  }
  #pragma unroll
  for(int o = 0; o < 16; ++o) xm[((size_t)b*16 + o)*2000 + tc] = acc[o];
}

// ---------------- im2col for conv1: A[(b*1000+t1), 16*7] ----------------
__global__ __launch_bounds__(256) void im2col1(const float* __restrict__ xm, float* __restrict__ A){
  size_t idx = (size_t)blockIdx.x * 256 + threadIdx.x; // 32000*112 exact
  int col = idx % 112;
  size_t row = idx / 112;
  int t1 = row % 1000, b = row / 1000;
  int i = col / 7, k = col % 7;
  int src = 2*t1 + k - 3;
  A[idx] = (src >= 0 && src < 2000) ? xm[((size_t)b*16 + i)*2000 + src] : 0.f;
}

// ---------------- GroupNorm(1) stats over h1 (B,1000,128) ----------------
__global__ __launch_bounds__(256) void gn_stats(const float* __restrict__ h1, float* __restrict__ stats){
  int b = blockIdx.x, t = threadIdx.x;
  __shared__ double rs[256], rq[256];
  double s = 0, q = 0;
  const float* p = h1 + (size_t)b * 128000;
  for(int i = t; i < 128000; i += 256){ double v = p[i]; s += v; q += v*v; }
  rs[t] = s; rq[t] = q; __syncthreads();
  for(int s2 = 128; s2 > 0; s2 >>= 1){
    if(t < s2){ rs[t] += rs[t+s2]; rq[t] += rq[t+s2]; }
    __syncthreads();
  }
  if(t == 0){
    double mean = rs[0] / 128000.0;
    double var  = rq[0] / 128000.0 - mean*mean;
    stats[b*2]   = (float)mean;
    stats[b*2+1] = (float)(1.0 / sqrt(var + 1e-5));
  }
}

// ---------------- im2col for conv2 with fused GroupNorm ----------------
__global__ __launch_bounds__(256) void im2col2(const float* __restrict__ h1,
    const float* __restrict__ stats, const float* __restrict__ gg,
    const float* __restrict__ gb, float* __restrict__ A){
  size_t idx = (size_t)blockIdx.x * 256 + threadIdx.x; // 16000*896 exact
  int col = idx % 896;
  size_t row = idx / 896;
  int t2 = row % 500, b = row / 500;
  int i = col / 7, k = col % 7;
  int src = 2*t2 + k - 3;
  float v = 0.f;
  if(src >= 0 && src < 1000){
    float raw = h1[((size_t)b*1000 + src)*128 + i];
    v = (raw - stats[b*2]) * stats[b*2+1] * gg[i] + gb[i];
  }
  A[idx] = v;
}

// ---------------- post-conv: LN(D) + sinpos + star table -> X ----------------
__global__ __launch_bounds__(256) void postconv(const float* __restrict__ xp,
    const float* __restrict__ cg, const float* __restrict__ cb,
    const float* __restrict__ star, const float* __restrict__ stab,
    float* __restrict__ x){
  int row = blockIdx.x, t = threadIdx.x;
  int s = row % 500, b = row / 500;
  __shared__ float red[256];
  float v = xp[(size_t)row*256 + t];
  red[t] = v; __syncthreads();
  for(int s2 = 128; s2 > 0; s2 >>= 1){ if(t < s2) red[t] += red[t+s2]; __syncthreads(); }
  float mean = red[0] / 256.f; __syncthreads();
  float d = v - mean;
  red[t] = d*d; __syncthreads();
  for(int s2 = 128; s2 > 0; s2 >>= 1){ if(t < s2) red[t] += red[t+s2]; __syncthreads(); }
  float rstd = 1.f / sqrtf(red[0]/256.f + 1e-5f);
  int j = t & 127;
  double f = exp((double)j * LKC);
  double a = (double)s * f;
  float pe = (float)(t < 128 ? sin(a) : cos(a));
  int bucket = (int)(star[b] * 2.0f);
  bucket = bucket < 0 ? 0 : (bucket > 19 ? 19 : bucket);
  x[(size_t)row*256 + t] = d*rstd*cg[t] + cb[t] + pe + stab[bucket*256 + t];
}

// ---------------- event features -> combined (B*NEV, 768) ----------------
__global__ __launch_bounds__(256) void event_feat(const int* __restrict__ events, float* __restrict__ comb){
  int blk = blockIdx.x;           // 8192
  int e = blk & 255, b = blk >> 8;
  const int* ev = events + b*256;
  int t = threadIdx.x;
  auto gof = [&](int i){ int j = i < 1 ? 1 : i; int d = ev[j] - ev[j-1]; return d < 1 ? 1 : d; };
  int gi = gof(e);
  double rb = 1.0, ra = 1.0;
  if(e != 0){
    rb = (double)gi / (double)gof(e-1);
    rb = rb < 0.1 ? 0.1 : (rb > 10.0 ? 10.0 : rb);
  }
  if(e != 255){
    ra = (double)gof(e+1) / (double)gi;
    ra = ra < 0.1 ? 0.1 : (ra > 10.0 ? 10.0 : ra);
  }
  int rbi = (int)(rb * 50.0);
  int rai = (int)(ra * 50.0);
  int gap = 5 * gi;
  int j = t & 127;
  double f = exp((double)j * LKC);
  double a0 = (double)rbi * f, a1 = (double)rai * f, a2 = (double)gap * f;
  size_t base = (size_t)blk * 768;
  comb[base + t]       = (float)(t < 128 ? sin(a0) : cos(a0));
  comb[base + 256 + t] = (float)(t < 128 ? sin(a1) : cos(a1));
  comb[base + 512 + t] = (float)(t < 128 ? sin(a2) : cos(a2));
}

// ---------------- scatter-add events into X ----------------
__global__ __launch_bounds__(256) void ev_scatter(const float* __restrict__ evout,
    const int* __restrict__ events, const unsigned char* __restrict__ mask,
    float* __restrict__ x){
  int blk = blockIdx.x; // 8192
  int e = blk & 255, b = blk >> 8;
  if(mask[b*256 + e]) return;
  int tp = events[b*256 + e] >> 2;
  tp = tp < 0 ? 0 : (tp > 499 ? 499 : tp);
  int t = threadIdx.x;
  atomicAdd(&x[((size_t)b*500 + tp)*256 + t], evout[(size_t)blk*256 + t]);
}

// ---------------- LayerNorm rows of 256 ----------------
__global__ __launch_bounds__(256) void ln_rows(const float* __restrict__ x,
    const float* __restrict__ g, const float* __restrict__ b, float* __restrict__ out){
  int row = blockIdx.x, t = threadIdx.x;
  __shared__ float red[256];
  float v = x[(size_t)row*256 + t];
  red[t] = v; __syncthreads();
  for(int s2 = 128; s2 > 0; s2 >>= 1){ if(t < s2) red[t] += red[t+s2]; __syncthreads(); }
  float mean = red[0] / 256.f; __syncthreads();
  float d = v - mean;
  red[t] = d*d; __syncthreads();
  for(int s2 = 128; s2 > 0; s2 >>= 1){ if(t < s2) red[t] += red[t+s2]; __syncthreads(); }
  float rstd = 1.f / sqrtf(red[0]/256.f + 1e-5f);
  out[(size_t)row*256 + t] = d*rstd*g[t] + b[t];
}

// ---------------- flash attention: qkv (B,S,768) -> o (B,S,256) ----------------
// grid = B*H*4, block = 128 threads; each thread owns one q row (125 rows/block).
// K/V staged in LDS in 64-key tiles; online softmax with lazy max rescale.
__global__ __launch_bounds__(128) void attn_flash(const float* __restrict__ qkv, float* __restrict__ o){
  __shared__ __align__(16) float Ks[64*32];
  __shared__ __align__(16) float Vs[64*32];
  const int blk = blockIdx.x;
  const int qq = blk & 3;
  const int bh = blk >> 2;
  const int h = bh & 7, b = bh >> 3;
  const int t = threadIdx.x;
  const int q = qq*125 + t;
  const bool active = (t < 125);
  const float scale = 0.17677669529663687f; // 1/sqrt(32)
  const float* base = qkv + (size_t)b * kS * 768;
  float4 qv[8];
  if(active){
    const float4* qp = (const float4*)(base + (size_t)q*768 + h*32);
    #pragma unroll
    for(int i = 0; i < 8; ++i){
      float4 v = qp[i];
      v.x *= scale; v.y *= scale; v.z *= scale; v.w *= scale;
      qv[i] = v;
    }
  }
  float m = -1e30f, l = 0.f;
  float4 acc[8] = {};
  for(int kt = 0; kt < 8; ++kt){
    const int k0 = kt * 64;
    const int kcount = (500 - k0) < 64 ? (500 - k0) : 64;
    __syncthreads();
    for(int idx = t; idx < kcount*8; idx += 128){
      int row = idx >> 3, c = idx & 7;
      const float* rp = base + (size_t)(k0 + row)*768 + h*32;
      ((float4*)Ks)[row*8 + c] = ((const float4*)(rp + 256))[c];
      ((float4*)Vs)[row*8 + c] = ((const float4*)(rp + 512))[c];
    }
    __syncthreads();
    if(!active) continue;
    for(int kk = 0; kk < kcount; ++kk){
      const float4* kr = (const float4*)(Ks + kk*32);
      float s = 0.f;
      #pragma unroll
      for(int i = 0; i < 8; ++i){
        float4 k4 = kr[i];
        s += qv[i].x*k4.x + qv[i].y*k4.y + qv[i].z*k4.z + qv[i].w*k4.w;
      }
      float e;
      if(s > m){
        float c = expf(m - s);
        l *= c;
        #pragma unroll
        for(int i = 0; i < 8; ++i){ acc[i].x*=c; acc[i].y*=c; acc[i].z*=c; acc[i].w*=c; }
        m = s; e = 1.f;
      } else {
        e = expf(s - m);
      }
      l += e;
      const float4* vr = (const float4*)(Vs + kk*32);
      #pragma unroll
      for(int i = 0; i < 8; ++i){
        float4 v4 = vr[i];
        acc[i].x += e*v4.x; acc[i].y += e*v4.y; acc[i].z += e*v4.z; acc[i].w += e*v4.w;
      }
    }
  }
  if(active){
    float inv = 1.f / l;
    float4* op = (float4*)(o + ((size_t)(b*kS + q))*256 + h*32);
    #pragma unroll
    for(int i = 0; i < 8; ++i){
      float4 a = acc[i];
      a.x*=inv; a.y*=inv; a.z*=inv; a.w*=inv;
      op[i] = a;
    }
  }
}

// ---------------- attention pooling + LN + head ----------------
__global__ __launch_bounds__(256) void pool_head(const float* __restrict__ x,
    const float* __restrict__ pq, const float* __restrict__ og, const float* __restrict__ ob,
    const float* __restrict__ ohW, const float* __restrict__ ohb, float* __restrict__ out){
  int b = blockIdx.x, t = threadIdx.x;
  __shared__ float lg[500];
  __shared__ float red[256];
  const float* xb = x + (size_t)b * 500 * 256;
  for(int s = t; s < 500; s += 256){
    const float* xr = xb + (size_t)s * 256;
    float d = 0.f;
    for(int c = 0; c < 256; ++c) d += xr[c] * pq[c];
    lg[s] = d * 0.0625f; // / sqrt(256)
  }
  __syncthreads();
  float m = -1e30f;
  for(int s = t; s < 500; s += 256) m = fmaxf(m, lg[s]);
  red[t] = m; __syncthreads();
  for(int s2 = 128; s2 > 0; s2 >>= 1){ if(t < s2) red[t] = fmaxf(red[t], red[t+s2]); __syncthreads(); }
  m = red[0]; __syncthreads();
  float ps = 0.f;
  for(int s = t; s < 500; s += 256){ float e = expf(lg[s] - m); lg[s] = e; ps += e; }
  red[t] = ps; __syncthreads();
  for(int s2 = 128; s2 > 0; s2 >>= 1){ if(t < s2) red[t] += red[t+s2]; __syncthreads(); }
  float inv = 1.f / red[0];
  __syncthreads();
  float acc = 0.f;
  for(int s = 0; s < 500; ++s) acc += lg[s] * xb[(size_t)s*256 + t];
  acc *= inv;                       // pooled[t]
  __syncthreads();
  red[t] = acc; __syncthreads();
  for(int s2 = 128; s2 > 0; s2 >>= 1){ if(t < s2) red[t] += red[t+s2]; __syncthreads(); }
  float mean = red[0] / 256.f; __syncthreads();
  float d = acc - mean;
  red[t] = d*d; __syncthreads();
  for(int s2 = 128; s2 > 0; s2 >>= 1){ if(t < s2) red[t] += red[t+s2]; __syncthreads(); }
  float rstd = 1.f / sqrtf(red[0]/256.f + 1e-5f);
  __syncthreads();
  float val = (d*rstd*og[t] + ob[t]) * ohW[t];
  red[t] = val; __syncthreads();
  for(int s2 = 128; s2 > 0; s2 >>= 1){ if(t < s2) red[t] += red[t+s2]; __syncthreads(); }
  if(t == 0) out[b] = red[0] + ohb[0];
}

extern "C" void kernel_launch(void* const* d_in, const int* in_sizes, int n_in,
                              void* d_out, int out_size, void* d_ws, size_t ws_size,
                              hipStream_t stream){
  const float* mel      = (const float*)d_in[0];
  const int*   events   = (const int*)d_in[1];
  const unsigned char* emask = (const unsigned char*)d_in[2];
  const float* star     = (const float*)d_in[3];
  const float* mel_W    = (const float*)d_in[4];
  const float* mel_b    = (const float*)d_in[5];
  const float* conv1_w  = (const float*)d_in[6];
  const float* conv1_b  = (const float*)d_in[7];
  const float* gn_g     = (const float*)d_in[8];
  const float* gn_b     = (const float*)d_in[9];
  const float* conv2_w  = (const float*)d_in[10];
  const float* conv2_b  = (const float*)d_in[11];
  const float* cn_g     = (const float*)d_in[12];
  const float* cn_b     = (const float*)d_in[13];
  const float* star_tab = (const float*)d_in[14];
  const float* ep_W1    = (const float*)d_in[15];
  const float* ep_b1    = (const float*)d_in[16];
  const float* ep_W2    = (const float*)d_in[17];
  const float* ep_b2    = (const float*)d_in[18];
  const float* tl_Wqkv  = (const float*)d_in[19];
  const float* tl_bqkv  = (const float*)d_in[20];
  const float* tl_Wo    = (const float*)d_in[21];
  const float* tl_bo    = (const float*)d_in[22];
  const float* tl_ln1g  = (const float*)d_in[23];
  const float* tl_ln1b  = (const float*)d_in[24];
  const float* tl_ln2g  = (const float*)d_in[25];
  const float* tl_ln2b  = (const float*)d_in[26];
  const float* tl_W1    = (const float*)d_in[27];
  const float* tl_b1    = (const float*)d_in[28];
  const float* tl_W2    = (const float*)d_in[29];
  const float* tl_b2    = (const float*)d_in[30];
  const float* pool_q   = (const float*)d_in[31];
  const float* on_g     = (const float*)d_in[32];
  const float* on_b     = (const float*)d_in[33];
  const float* oh_W     = (const float*)d_in[34];
  const float* oh_b     = (const float*)d_in[35];
  (void)in_sizes; (void)n_in; (void)out_size; (void)ws_size;

  float* ws   = (float*)d_ws;
  float* X    = ws;                 // 4,096,000 floats (B,S,D)
  float* XN   = ws + 4096000;       // 4,096,000
  float* OO   = ws + 8192000;       // 4,096,000
  float* BIG  = ws + 12288000;      // 16,384,000
  float* STATS= ws + 28672000;      // 64

  float* XMEL = OO;                 // (B,16,2000) 1.024M — dead after im2col1
  float* H1   = XN;                 // (B,1000,128) 4.096M
  float* XPRE = OO;                 // (B,S,D) conv2 out — overwrites dead XMEL
  float* COMB = BIG;                // (8192,768)
  float* EHID = BIG + 6291456;      // (8192,256)
  float* EVO  = BIG + 8388608;      // (8192,256)

  // ---- prologue ----
  mel_kernel<<<kB*8, 256, 0, stream>>>(mel, mel_W, mel_b, XMEL);
  im2col1<<<14000, 256, 0, stream>>>(XMEL, BIG);
  gemm64<true,false><<<dim3(128/64, 32000/64), 256, 0, stream>>>(BIG, conv1_w, conv1_b, H1, 32000, 128, 112);
  gn_stats<<<kB, 256, 0, stream>>>(H1, STATS);
  im2col2<<<56000, 256, 0, stream>>>(H1, STATS, gn_g, gn_b, BIG);
  gemm64<true,false><<<dim3(256/64, 16000/64), 256, 0, stream>>>(BIG, conv2_w, conv2_b, XPRE, 16000, 256, 896);
  postconv<<<16000, 256, 0, stream>>>(XPRE, cn_g, cn_b, star, star_tab, X);
  // events
  event_feat<<<kB*kNEV, 256, 0, stream>>>(events, COMB);
  gemm64<true,false><<<dim3(256/64, 8192/64), 256, 0, stream>>>(COMB, ep_W1, ep_b1, EHID, 8192, 256, 768);
  gemm64<false,false><<<dim3(256/64, 8192/64), 256, 0, stream>>>(EHID, ep_W2, ep_b2, EVO, 8192, 256, 256);
  ev_scatter<<<kB*kNEV, 256, 0, stream>>>(EVO, events, emask, X);

  // ---- transformer layers ----
  for(int i = 0; i < 6; ++i){
    ln_rows<<<16000, 256, 0, stream>>>(X, tl_ln1g + i*256, tl_ln1b + i*256, XN);
    gemm64<false,false><<<dim3(768/64, 16000/64), 256, 0, stream>>>(XN, tl_Wqkv + (size_t)i*768*256, tl_bqkv + i*768, BIG, 16000, 768, 256);
    attn_flash<<<kB*kH*4, 128, 0, stream>>>(BIG, OO);
    gemm64<false,true><<<dim3(256/64, 16000/64), 256, 0, stream>>>(OO, tl_Wo + (size_t)i*256*256, tl_bo + i*256, X, 16000, 256, 256);
    ln_rows<<<16000, 256, 0, stream>>>(X, tl_ln2g + i*256, tl_ln2b + i*256, XN);
    gemm64<true,false><<<dim3(1024/64, 16000/64), 256, 0, stream>>>(XN, tl_W1 + (size_t)i*1024*256, tl_b1 + i*1024, BIG, 16000, 1024, 256);
    gemm64<false,true><<<dim3(256/64, 16000/64), 256, 0, stream>>>(BIG, tl_W2 + (size_t)i*256*1024, tl_b2 + i*256, X, 16000, 256, 1024);
  }

  // ---- pooling + head ----
  pool_head<<<kB, 256, 0, stream>>>(X, pool_q, on_g, on_b, oh_W, oh_b, (float*)d_out);
}

// Round 3
// 2464.964 us; speedup vs baseline: 6.8558x; 1.8417x over previous
//
#include <hip/hip_runtime.h>
#include <math.h>

namespace {
constexpr int kB = 32;
constexpr int kS = 500;
constexpr int kH = 8;
}
// -ln(10000)/127
#define LKC (-0.07252236513366287)

typedef __attribute__((ext_vector_type(8))) short s16x8;
typedef __attribute__((ext_vector_type(4))) float f32x4;

__device__ __forceinline__ float gelu_f(float x){
  return 0.5f * x * (1.0f + erff(x * 0.7071067811865476f));
}
__device__ __forceinline__ float b2f(short s){
  union { unsigned u; float f; } x; x.u = ((unsigned)(unsigned short)s) << 16; return x.f;
}
__device__ __forceinline__ short f2b(float f){
  unsigned u = __float_as_uint(f);
  unsigned r = (u + 0x7fffu + ((u >> 16) & 1u)) >> 16;
  return (short)r;
}

// ---------------- fp32 -> bf16 converter ----------------
__global__ __launch_bounds__(256) void f2b_kernel(const float* __restrict__ in,
    short* __restrict__ out, int n){
  int i = blockIdx.x * 256 + threadIdx.x;
  if(i < n) out[i] = f2b(in[i]);
}
// conv1 weight: (128,112) -> bf16 padded to (128,128)
__global__ __launch_bounds__(128) void conv1w_pad(const float* __restrict__ w, short* __restrict__ out){
  int n = blockIdx.x, k = threadIdx.x;
  out[n*128 + k] = (k < 112) ? f2b(w[n*112 + k]) : (short)0;
}

// ---------------- MFMA GEMM: C[M,N] (op)= [GELU](A[M,K]@W[N,K]^T + bias) ----------------
// A, W bf16 row-major; bias fp32. OUT: 0=store fp32, 1=add fp32, 2=store bf16.
// M%128==0, N%128==0, K%32==0. 256 threads = 4 waves, each wave a 64x64 quadrant.
template<int OUT, bool DOGELU>
__global__ __launch_bounds__(256) void gemm_mfma(const short* __restrict__ A,
    const short* __restrict__ W, const float* __restrict__ bias,
    void* __restrict__ Cv, int M, int N, int K){
  __shared__ __align__(16) short Al[128*32];
  __shared__ __align__(16) short Wl[128*32];
  const int t = threadIdx.x;
  const int wid = t >> 6, lane = t & 63;
  const int m0 = blockIdx.y * 128, n0 = blockIdx.x * 128;
  const int wr = (wid >> 1) * 64, wc = (wid & 1) * 64;
  const int srow = t >> 2, scol = (t & 3) * 8;
  const short* Ag = A + (size_t)(m0 + srow) * K + scol;
  const short* Wg = W + (size_t)(n0 + srow) * K + scol;
  const int frow = lane & 15, fcol = (lane >> 4) * 8;
  f32x4 acc[4][4] = {};
  for(int k0 = 0; k0 < K; k0 += 32){
    s16x8 av0 = *(const s16x8*)(Ag + k0);
    s16x8 av1 = *(const s16x8*)(Ag + (size_t)64*K + k0);
    s16x8 wv0 = *(const s16x8*)(Wg + k0);
    s16x8 wv1 = *(const s16x8*)(Wg + (size_t)64*K + k0);
    __syncthreads();
    *(s16x8*)&Al[srow*32 + scol] = av0;
    *(s16x8*)&Al[(srow+64)*32 + scol] = av1;
    *(s16x8*)&Wl[srow*32 + scol] = wv0;
    *(s16x8*)&Wl[(srow+64)*32 + scol] = wv1;
    __syncthreads();
    s16x8 a[4], b[4];
    #pragma unroll
    for(int mi = 0; mi < 4; ++mi) a[mi] = *(const s16x8*)&Al[(wr + mi*16 + frow)*32 + fcol];
    #pragma unroll
    for(int ni = 0; ni < 4; ++ni) b[ni] = *(const s16x8*)&Wl[(wc + ni*16 + frow)*32 + fcol];
    #pragma unroll
    for(int mi = 0; mi < 4; ++mi)
      #pragma unroll
      for(int ni = 0; ni < 4; ++ni)
        acc[mi][ni] = __builtin_amdgcn_mfma_f32_16x16x32_bf16(a[mi], b[ni], acc[mi][ni], 0, 0, 0);
  }
  #pragma unroll
  for(int mi = 0; mi < 4; ++mi){
    #pragma unroll
    for(int ni = 0; ni < 4; ++ni){
      const int col = n0 + wc + ni*16 + (lane & 15);
      const float bv = bias[col];
      #pragma unroll
      for(int r = 0; r < 4; ++r){
        const int row = m0 + wr + mi*16 + (lane >> 4)*4 + r;
        float v = acc[mi][ni][r] + bv;
        if(DOGELU) v = gelu_f(v);
        if(OUT == 0) ((float*)Cv)[(size_t)row*N + col] = v;
        else if(OUT == 1) ((float*)Cv)[(size_t)row*N + col] += v;
        else ((short*)Cv)[(size_t)row*N + col] = f2b(v);
      }
    }
  }
}

// ---------------- mel compress: (B,80,2000) -> (B,16,2000) ----------------
__global__ __launch_bounds__(256) void mel_kernel(const float* __restrict__ mel,
    const float* __restrict__ W, const float* __restrict__ bias, float* __restrict__ xm){
  __shared__ float Ws[16][80];
  __shared__ float bs[16];
  const int t = threadIdx.x;
  for(int i = t; i < 16*80; i += 256) Ws[i/80][i%80] = W[i];
  if(t < 16) bs[t] = bias[t];
  __syncthreads();
  int blk = blockIdx.x;
  int b = blk >> 3;
  int tc = (blk & 7) * 256 + t;
  if(tc >= 2000) return;
  float acc[16];
  #pragma unroll
  for(int o = 0; o < 16; ++o) acc[o] = bs[o];
  for(int c = 0; c < 80; ++c){
    float v = mel[((size_t)b*80 + c)*2000 + tc];
    #pragma unroll
    for(int o = 0; o < 16; ++o) acc[o] += v * Ws[o][c];
  }
  #pragma unroll
  for(int o = 0; o < 16; ++o) xm[((size_t)b*16 + o)*2000 + tc] = acc[o];
}

// ---------------- im2col conv1 -> bf16, K padded to 128 ----------------
__global__ __launch_bounds__(256) void im2col1b(const float* __restrict__ xm, short* __restrict__ A){
  size_t idx = (size_t)blockIdx.x * 256 + threadIdx.x; // 32000*128
  int col = idx & 127;
  size_t row = idx >> 7;
  int t1 = row % 1000, b = row / 1000;
  float v = 0.f;
  if(col < 112){
    int i = col / 7, k = col % 7;
    int src = 2*t1 + k - 3;
    if(src >= 0 && src < 2000) v = xm[((size_t)b*16 + i)*2000 + src];
  }
  A[idx] = f2b(v);
}

// ---------------- GroupNorm(1) stats over h1 (B,1000,128) ----------------
__global__ __launch_bounds__(256) void gn_stats(const float* __restrict__ h1, float* __restrict__ stats){
  int b = blockIdx.x, t = threadIdx.x;
  __shared__ double rs[256], rq[256];
  double s = 0, q = 0;
  const float* p = h1 + (size_t)b * 128000;
  for(int i = t; i < 128000; i += 256){ double v = p[i]; s += v; q += v*v; }
  rs[t] = s; rq[t] = q; __syncthreads();
  for(int s2 = 128; s2 > 0; s2 >>= 1){
    if(t < s2){ rs[t] += rs[t+s2]; rq[t] += rq[t+s2]; }
    __syncthreads();
  }
  if(t == 0){
    double mean = rs[0] / 128000.0;
    double var  = rq[0] / 128000.0 - mean*mean;
    stats[b*2]   = (float)mean;
    stats[b*2+1] = (float)(1.0 / sqrt(var + 1e-5));
  }
}

// ---------------- im2col conv2 (fused GroupNorm) -> bf16 ----------------
__global__ __launch_bounds__(256) void im2col2b(const float* __restrict__ h1,
    const float* __restrict__ stats, const float* __restrict__ gg,
    const float* __restrict__ gb, short* __restrict__ A){
  size_t idx = (size_t)blockIdx.x * 256 + threadIdx.x; // 16000*896
  int col = idx % 896;
  size_t row = idx / 896;
  int t2 = row % 500, b = row / 500;
  int i = col / 7, k = col % 7;
  int src = 2*t2 + k - 3;
  float v = 0.f;
  if(src >= 0 && src < 1000){
    float raw = h1[((size_t)b*1000 + src)*128 + i];
    v = (raw - stats[b*2]) * stats[b*2+1] * gg[i] + gb[i];
  }
  A[idx] = f2b(v);
}

// ---------------- post-conv: LN(D) + sinpos + star table -> X (fp32) ----------------
__global__ __launch_bounds__(256) void postconv(const float* __restrict__ xp,
    const float* __restrict__ cg, const float* __restrict__ cb,
    const float* __restrict__ star, const float* __restrict__ stab,
    float* __restrict__ x){
  int row = blockIdx.x, t = threadIdx.x;
  int s = row % 500, b = row / 500;
  __shared__ float red[256];
  float v = xp[(size_t)row*256 + t];
  red[t] = v; __syncthreads();
  for(int s2 = 128; s2 > 0; s2 >>= 1){ if(t < s2) red[t] += red[t+s2]; __syncthreads(); }
  float mean = red[0] / 256.f; __syncthreads();
  float d = v - mean;
  red[t] = d*d; __syncthreads();
  for(int s2 = 128; s2 > 0; s2 >>= 1){ if(t < s2) red[t] += red[t+s2]; __syncthreads(); }
  float rstd = 1.f / sqrtf(red[0]/256.f + 1e-5f);
  int j = t & 127;
  double f = exp((double)j * LKC);
  double a = (double)s * f;
  float pe = (float)(t < 128 ? sin(a) : cos(a));
  int bucket = (int)(star[b] * 2.0f);
  bucket = bucket < 0 ? 0 : (bucket > 19 ? 19 : bucket);
  x[(size_t)row*256 + t] = d*rstd*cg[t] + cb[t] + pe + stab[bucket*256 + t];
}

// ---------------- event features -> combined bf16 (B*NEV, 768) ----------------
__global__ __launch_bounds__(256) void event_feat(const int* __restrict__ events, short* __restrict__ comb){
  int blk = blockIdx.x;           // 8192
  int e = blk & 255, b = blk >> 8;
  const int* ev = events + b*256;
  int t = threadIdx.x;
  auto gof = [&](int i){ int j = i < 1 ? 1 : i; int d = ev[j] - ev[j-1]; return d < 1 ? 1 : d; };
  int gi = gof(e);
  double rb = 1.0, ra = 1.0;
  if(e != 0){
    rb = (double)gi / (double)gof(e-1);
    rb = rb < 0.1 ? 0.1 : (rb > 10.0 ? 10.0 : rb);
  }
  if(e != 255){
    ra = (double)gof(e+1) / (double)gi;
    ra = ra < 0.1 ? 0.1 : (ra > 10.0 ? 10.0 : ra);
  }
  int rbi = (int)(rb * 50.0);
  int rai = (int)(ra * 50.0);
  int gap = 5 * gi;
  int j = t & 127;
  double f = exp((double)j * LKC);
  double a0 = (double)rbi * f, a1 = (double)rai * f, a2 = (double)gap * f;
  size_t base = (size_t)blk * 768;
  comb[base + t]       = f2b((float)(t < 128 ? sin(a0) : cos(a0)));
  comb[base + 256 + t] = f2b((float)(t < 128 ? sin(a1) : cos(a1)));
  comb[base + 512 + t] = f2b((float)(t < 128 ? sin(a2) : cos(a2)));
}

// ---------------- scatter-add events into X ----------------
__global__ __launch_bounds__(256) void ev_scatter(const float* __restrict__ evout,
    const int* __restrict__ events, const unsigned char* __restrict__ mask,
    float* __restrict__ x){
  int blk = blockIdx.x; // 8192
  int e = blk & 255, b = blk >> 8;
  if(mask[b*256 + e]) return;
  int tp = events[b*256 + e] >> 2;
  tp = tp < 0 ? 0 : (tp > 499 ? 499 : tp);
  int t = threadIdx.x;
  atomicAdd(&x[((size_t)b*500 + tp)*256 + t], evout[(size_t)blk*256 + t]);
}

// ---------------- LayerNorm rows of 256 -> bf16 ----------------
__global__ __launch_bounds__(256) void ln_rows(const float* __restrict__ x,
    const float* __restrict__ g, const float* __restrict__ b, short* __restrict__ out){
  int row = blockIdx.x, t = threadIdx.x;
  __shared__ float red[256];
  float v = x[(size_t)row*256 + t];
  red[t] = v; __syncthreads();
  for(int s2 = 128; s2 > 0; s2 >>= 1){ if(t < s2) red[t] += red[t+s2]; __syncthreads(); }
  float mean = red[0] / 256.f; __syncthreads();
  float d = v - mean;
  red[t] = d*d; __syncthreads();
  for(int s2 = 128; s2 > 0; s2 >>= 1){ if(t < s2) red[t] += red[t+s2]; __syncthreads(); }
  float rstd = 1.f / sqrtf(red[0]/256.f + 1e-5f);
  out[(size_t)row*256 + t] = f2b(d*rstd*g[t] + b[t]);
}

// ---------------- flash attention partials: split-K x4 ----------------
// grid = B*H*4(qq)*4(ks); block 128; thread = one q row over 125 keys.
__global__ __launch_bounds__(128) void attn_part(const short* __restrict__ qkv,
    float* __restrict__ pml, short* __restrict__ pacc){
  __shared__ __align__(16) float Ks[64*32];
  __shared__ __align__(16) float Vs[64*32];
  const int blk = blockIdx.x;
  const int ksp = blk & 3, qq = (blk >> 2) & 3, bh = blk >> 4;
  const int h = bh & 7, b = bh >> 3;
  const int t = threadIdx.x;
  const int q = qq*125 + t;
  const bool active = (t < 125);
  const float scale = 0.17677669529663687f; // 1/sqrt(32)
  const short* base = qkv + (size_t)b * kS * 768;
  float qv[32];
  if(active){
    const short* qp = base + (size_t)q*768 + h*32;
    #pragma unroll
    for(int c = 0; c < 4; ++c){
      s16x8 v = *(const s16x8*)(qp + c*8);
      #pragma unroll
      for(int j = 0; j < 8; ++j) qv[c*8+j] = b2f(v[j]) * scale;
    }
  }
  float m = -1e30f, l = 0.f;
  float4 acc[8] = {};
  const int kbase = ksp * 125;
  for(int kt = 0; kt < 2; ++kt){
    const int k0 = kbase + kt*64;
    const int kcount = (125 - kt*64) < 64 ? (125 - kt*64) : 64;
    __syncthreads();
    for(int idx = t; idx < kcount*4; idx += 128){
      int row = idx >> 2, c = idx & 3;
      const short* rp = base + (size_t)(k0 + row)*768 + 256 + h*32 + c*8;
      s16x8 kv = *(const s16x8*)rp;
      s16x8 vv = *(const s16x8*)(rp + 256);
      float* kd = Ks + row*32 + c*8;
      float* vd = Vs + row*32 + c*8;
      #pragma unroll
      for(int j = 0; j < 8; ++j){ kd[j] = b2f(kv[j]); vd[j] = b2f(vv[j]); }
    }
    __syncthreads();
    if(!active) continue;
    for(int kk = 0; kk < kcount; ++kk){
      const float4* kr = (const float4*)(Ks + kk*32);
      float s = 0.f;
      #pragma unroll
      for(int i = 0; i < 8; ++i){
        float4 k4 = kr[i];
        s += qv[i*4+0]*k4.x + qv[i*4+1]*k4.y + qv[i*4+2]*k4.z + qv[i*4+3]*k4.w;
      }
      float e;
      if(s > m){
        float c = expf(m - s);
        l *= c;
        #pragma unroll
        for(int i = 0; i < 8; ++i){ acc[i].x*=c; acc[i].y*=c; acc[i].z*=c; acc[i].w*=c; }
        m = s; e = 1.f;
      } else {
        e = expf(s - m);
      }
      l += e;
      const float4* vr = (const float4*)(Vs + kk*32);
      #pragma unroll
      for(int i = 0; i < 8; ++i){
        float4 v4 = vr[i];
        acc[i].x += e*v4.x; acc[i].y += e*v4.y; acc[i].z += e*v4.z; acc[i].w += e*v4.w;
      }
    }
  }
  if(active){
    size_t p = ((size_t)(b*8 + h)*500 + q)*4 + ksp;
    pml[p*2] = m; pml[p*2+1] = l;
    short* pa = pacc + p*32;
    #pragma unroll
    for(int i = 0; i < 8; ++i){
      pa[i*4+0] = f2b(acc[i].x); pa[i*4+1] = f2b(acc[i].y);
      pa[i*4+2] = f2b(acc[i].z); pa[i*4+3] = f2b(acc[i].w);
    }
  }
}

// ---------------- merge split-K partials -> O bf16 (B,S,256) ----------------
__global__ __launch_bounds__(256) void attn_merge(const float* __restrict__ pml,
    const short* __restrict__ pacc, short* __restrict__ o){
  int g = blockIdx.x*8 + (threadIdx.x >> 5);   // 0..127999 = (b*8+h)*500+q
  int d = threadIdx.x & 31;
  int b = g / 4000, h = (g / 500) & 7, q = g % 500;
  size_t p0 = (size_t)g * 4;
  float m0 = pml[(p0+0)*2], m1 = pml[(p0+1)*2], m2 = pml[(p0+2)*2], m3 = pml[(p0+3)*2];
  float M = fmaxf(fmaxf(m0,m1), fmaxf(m2,m3));
  float L = 0.f, A = 0.f;
  #pragma unroll
  for(int i = 0; i < 4; ++i){
    float w = expf(pml[(p0+i)*2] - M);
    L += pml[(p0+i)*2+1] * w;
    A += b2f(pacc[(p0+i)*32 + d]) * w;
  }
  o[((size_t)(b*kS + q))*256 + h*32 + d] = f2b(A / L);
}

// ---------------- attention pooling + LN + head ----------------
__global__ __launch_bounds__(256) void pool_head(const float* __restrict__ x,
    const float* __restrict__ pq, const float* __restrict__ og, const float* __restrict__ ob,
    const float* __restrict__ ohW, const float* __restrict__ ohb, float* __restrict__ out){
  int b = blockIdx.x, t = threadIdx.x;
  __shared__ float lg[500];
  __shared__ float red[256];
  const float* xb = x + (size_t)b * 500 * 256;
  for(int s = t; s < 500; s += 256){
    const float* xr = xb + (size_t)s * 256;
    float d = 0.f;
    for(int c = 0; c < 256; ++c) d += xr[c] * pq[c];
    lg[s] = d * 0.0625f;
  }
  __syncthreads();
  float m = -1e30f;
  for(int s = t; s < 500; s += 256) m = fmaxf(m, lg[s]);
  red[t] = m; __syncthreads();
  for(int s2 = 128; s2 > 0; s2 >>= 1){ if(t < s2) red[t] = fmaxf(red[t], red[t+s2]); __syncthreads(); }
  m = red[0]; __syncthreads();
  float ps = 0.f;
  for(int s = t; s < 500; s += 256){ float e = expf(lg[s] - m); lg[s] = e; ps += e; }
  red[t] = ps; __syncthreads();
  for(int s2 = 128; s2 > 0; s2 >>= 1){ if(t < s2) red[t] += red[t+s2]; __syncthreads(); }
  float inv = 1.f / red[0];
  __syncthreads();
  float acc = 0.f;
  for(int s = 0; s < 500; ++s) acc += lg[s] * xb[(size_t)s*256 + t];
  acc *= inv;
  __syncthreads();
  red[t] = acc; __syncthreads();
  for(int s2 = 128; s2 > 0; s2 >>= 1){ if(t < s2) red[t] += red[t+s2]; __syncthreads(); }
  float mean = red[0] / 256.f; __syncthreads();
  float d = acc - mean;
  red[t] = d*d; __syncthreads();
  for(int s2 = 128; s2 > 0; s2 >>= 1){ if(t < s2) red[t] += red[t+s2]; __syncthreads(); }
  float rstd = 1.f / sqrtf(red[0]/256.f + 1e-5f);
  __syncthreads();
  float val = (d*rstd*og[t] + ob[t]) * ohW[t];
  red[t] = val; __syncthreads();
  for(int s2 = 128; s2 > 0; s2 >>= 1){ if(t < s2) red[t] += red[t+s2]; __syncthreads(); }
  if(t == 0) out[b] = red[0] + ohb[0];
}

extern "C" void kernel_launch(void* const* d_in, const int* in_sizes, int n_in,
                              void* d_out, int out_size, void* d_ws, size_t ws_size,
                              hipStream_t stream){
  const float* mel      = (const float*)d_in[0];
  const int*   events   = (const int*)d_in[1];
  const unsigned char* emask = (const unsigned char*)d_in[2];
  const float* star     = (const float*)d_in[3];
  const float* mel_W    = (const float*)d_in[4];
  const float* mel_b    = (const float*)d_in[5];
  const float* conv1_w  = (const float*)d_in[6];
  const float* conv1_b  = (const float*)d_in[7];
  const float* gn_g     = (const float*)d_in[8];
  const float* gn_b     = (const float*)d_in[9];
  const float* conv2_w  = (const float*)d_in[10];
  const float* conv2_b  = (const float*)d_in[11];
  const float* cn_g     = (const float*)d_in[12];
  const float* cn_b     = (const float*)d_in[13];
  const float* star_tab = (const float*)d_in[14];
  const float* ep_W1    = (const float*)d_in[15];
  const float* ep_b1    = (const float*)d_in[16];
  const float* ep_W2    = (const float*)d_in[17];
  const float* ep_b2    = (const float*)d_in[18];
  const float* tl_Wqkv  = (const float*)d_in[19];
  const float* tl_bqkv  = (const float*)d_in[20];
  const float* tl_Wo    = (const float*)d_in[21];
  const float* tl_bo    = (const float*)d_in[22];
  const float* tl_ln1g  = (const float*)d_in[23];
  const float* tl_ln1b  = (const float*)d_in[24];
  const float* tl_ln2g  = (const float*)d_in[25];
  const float* tl_ln2b  = (const float*)d_in[26];
  const float* tl_W1    = (const float*)d_in[27];
  const float* tl_b1    = (const float*)d_in[28];
  const float* tl_W2    = (const float*)d_in[29];
  const float* tl_b2    = (const float*)d_in[30];
  const float* pool_q   = (const float*)d_in[31];
  const float* on_g     = (const float*)d_in[32];
  const float* on_b     = (const float*)d_in[33];
  const float* oh_W     = (const float*)d_in[34];
  const float* oh_b     = (const float*)d_in[35];
  (void)in_sizes; (void)n_in; (void)out_size; (void)ws_size;

  float* ws  = (float*)d_ws;
  float* X   = ws;                        // fp32 (B,S,256)          [0, 4.096M)
  short* XNB = (short*)(ws + 4096000);    // bf16 (B,S,256)
  short* OB  = (short*)(ws + 6144000);    // bf16 attn out (B,S,256)
  short* WB  = (short*)(ws + 8192000);    // bf16 weights (5.23M shorts)
  float* BIG = ws + 10812000;             // 17.86M floats scratch
  float* STATS = ws + 28671900;

  // WB sub-offsets (shorts)
  short* WBc1 = WB + 0;         // 128x128
  short* WBc2 = WB + 16384;     // 256x896
  short* WBe1 = WB + 245760;    // 256x768
  short* WBe2 = WB + 442368;    // 256x256
  short* WBqk = WB + 507904;    // 6 x 768x256
  short* WBwo = WB + 1687552;   // 6 x 256x256
  short* WBw1 = WB + 2080768;   // 6 x 1024x256
  short* WBw2 = WB + 3653632;   // 6 x 256x1024

  // BIG sub-layouts (element offsets in floats)
  float* XMEL = BIG;                       // (B,16,2000) fp32 1.024M
  short* A1B  = (short*)(BIG + 1024000);   // (32000,128) bf16
  float* H1   = BIG + 3072000;             // (B,1000,128) fp32 4.096M
  short* A2B  = (short*)(BIG + 7168000);   // (16000,896) bf16
  float* XPRE = BIG;                       // (B,S,256) fp32 (over dead XMEL/A1B)
  short* COMBB= (short*)BIG;               // (8192,768) bf16
  short* EHIDB= (short*)(BIG + 3146000);   // (8192,256) bf16
  float* EVO  = BIG + 4195000;             // (8192,256) fp32
  short* QKVB = (short*)BIG;               // (16000,768) bf16 6.144M floats
  float* PML  = BIG + 6144000;             // 512000 x {m,l} fp32
  short* PACC = (short*)(BIG + 7168000);   // 512000 x 32 bf16
  short* HIDB = (short*)(BIG + 7168000);   // (16000,1024) bf16 (aliases PACC, disjoint lifetime)

  // ---- weight conversion ----
  conv1w_pad<<<128, 128, 0, stream>>>(conv1_w, WBc1);
  f2b_kernel<<<896, 256, 0, stream>>>(conv2_w, WBc2, 229376);
  f2b_kernel<<<768, 256, 0, stream>>>(ep_W1, WBe1, 196608);
  f2b_kernel<<<256, 256, 0, stream>>>(ep_W2, WBe2, 65536);
  f2b_kernel<<<4608, 256, 0, stream>>>(tl_Wqkv, WBqk, 1179648);
  f2b_kernel<<<1536, 256, 0, stream>>>(tl_Wo, WBwo, 393216);
  f2b_kernel<<<6144, 256, 0, stream>>>(tl_W1, WBw1, 1572864);
  f2b_kernel<<<6144, 256, 0, stream>>>(tl_W2, WBw2, 1572864);

  // ---- prologue ----
  mel_kernel<<<kB*8, 256, 0, stream>>>(mel, mel_W, mel_b, XMEL);
  im2col1b<<<16000, 256, 0, stream>>>(XMEL, A1B);
  gemm_mfma<0,true><<<dim3(1, 250), 256, 0, stream>>>(A1B, WBc1, conv1_b, H1, 32000, 128, 128);
  gn_stats<<<kB, 256, 0, stream>>>(H1, STATS);
  im2col2b<<<56000, 256, 0, stream>>>(H1, STATS, gn_g, gn_b, A2B);
  gemm_mfma<0,true><<<dim3(2, 125), 256, 0, stream>>>(A2B, WBc2, conv2_b, XPRE, 16000, 256, 896);
  postconv<<<16000, 256, 0, stream>>>(XPRE, cn_g, cn_b, star, star_tab, X);
  // events
  event_feat<<<kB*256, 256, 0, stream>>>(events, COMBB);
  gemm_mfma<2,true><<<dim3(2, 64), 256, 0, stream>>>(COMBB, WBe1, ep_b1, EHIDB, 8192, 256, 768);
  gemm_mfma<0,false><<<dim3(2, 64), 256, 0, stream>>>(EHIDB, WBe2, ep_b2, EVO, 8192, 256, 256);
  ev_scatter<<<kB*256, 256, 0, stream>>>(EVO, events, emask, X);

  // ---- transformer layers ----
  for(int i = 0; i < 6; ++i){
    ln_rows<<<16000, 256, 0, stream>>>(X, tl_ln1g + i*256, tl_ln1b + i*256, XNB);
    gemm_mfma<2,false><<<dim3(6, 125), 256, 0, stream>>>(XNB, WBqk + (size_t)i*196608, tl_bqkv + i*768, QKVB, 16000, 768, 256);
    attn_part<<<kB*kH*16, 128, 0, stream>>>(QKVB, PML, PACC);
    attn_merge<<<16000, 256, 0, stream>>>(PML, PACC, OB);
    gemm_mfma<1,false><<<dim3(2, 125), 256, 0, stream>>>(OB, WBwo + (size_t)i*65536, tl_bo + i*256, X, 16000, 256, 256);
    ln_rows<<<16000, 256, 0, stream>>>(X, tl_ln2g + i*256, tl_ln2b + i*256, XNB);
    gemm_mfma<2,true><<<dim3(8, 125), 256, 0, stream>>>(XNB, WBw1 + (size_t)i*262144, tl_b1 + i*1024, HIDB, 16000, 1024, 256);
    gemm_mfma<1,false><<<dim3(2, 125), 256, 0, stream>>>(HIDB, WBw2 + (size_t)i*262144, tl_b2 + i*256, X, 16000, 256, 1024);
  }

  // ---- pooling + head ----
  pool_head<<<kB, 256, 0, stream>>>(X, pool_q, on_g, on_b, oh_W, oh_b, (float*)d_out);
}

// Round 4
// 1790.320 us; speedup vs baseline: 9.4393x; 1.3768x over previous
//
#include <hip/hip_runtime.h>
#include <math.h>

namespace {
constexpr int kB = 32;
constexpr int kS = 500;
constexpr int kH = 8;
}
// -ln(10000)/127
#define LKC (-0.07252236513366287)

typedef __attribute__((ext_vector_type(8))) short s16x8;
typedef __attribute__((ext_vector_type(4))) float f32x4;

__device__ __forceinline__ float gelu_f(float x){
  return 0.5f * x * (1.0f + erff(x * 0.7071067811865476f));
}
__device__ __forceinline__ float b2f(short s){
  union { unsigned u; float f; } x; x.u = ((unsigned)(unsigned short)s) << 16; return x.f;
}
__device__ __forceinline__ short f2b(float f){
  unsigned u = __float_as_uint(f);
  unsigned r = (u + 0x7fffu + ((u >> 16) & 1u)) >> 16;
  return (short)r;
}

// ---------------- fp32 -> bf16 converter ----------------
__global__ __launch_bounds__(256) void f2b_kernel(const float* __restrict__ in,
    short* __restrict__ out, int n){
  int i = blockIdx.x * 256 + threadIdx.x;
  if(i < n) out[i] = f2b(in[i]);
}
// conv1 weight: (128,112) -> bf16 padded to (128,128)
__global__ __launch_bounds__(128) void conv1w_pad(const float* __restrict__ w, short* __restrict__ out){
  int n = blockIdx.x, k = threadIdx.x;
  out[n*128 + k] = (k < 112) ? f2b(w[n*112 + k]) : (short)0;
}

// ---------------- MFMA GEMM: C[M,N] (op)= [GELU](A[M,K]@W[N,K]^T + bias) ----------------
// A, W bf16 row-major; bias fp32. OUT: 0=store fp32, 1=add fp32, 2=store bf16.
// M%128==0, N%128==0, K%32==0. 256 threads = 4 waves, each wave a 64x64 quadrant.
template<int OUT, bool DOGELU>
__global__ __launch_bounds__(256) void gemm_mfma(const short* __restrict__ A,
    const short* __restrict__ W, const float* __restrict__ bias,
    void* __restrict__ Cv, int M, int N, int K){
  __shared__ __align__(16) short Al[128*32];
  __shared__ __align__(16) short Wl[128*32];
  const int t = threadIdx.x;
  const int wid = t >> 6, lane = t & 63;
  const int m0 = blockIdx.y * 128, n0 = blockIdx.x * 128;
  const int wr = (wid >> 1) * 64, wc = (wid & 1) * 64;
  const int srow = t >> 2, scol = (t & 3) * 8;
  const short* Ag = A + (size_t)(m0 + srow) * K + scol;
  const short* Wg = W + (size_t)(n0 + srow) * K + scol;
  const int frow = lane & 15, fcol = (lane >> 4) * 8;
  f32x4 acc[4][4] = {};
  for(int k0 = 0; k0 < K; k0 += 32){
    s16x8 av0 = *(const s16x8*)(Ag + k0);
    s16x8 av1 = *(const s16x8*)(Ag + (size_t)64*K + k0);
    s16x8 wv0 = *(const s16x8*)(Wg + k0);
    s16x8 wv1 = *(const s16x8*)(Wg + (size_t)64*K + k0);
    __syncthreads();
    *(s16x8*)&Al[srow*32 + scol] = av0;
    *(s16x8*)&Al[(srow+64)*32 + scol] = av1;
    *(s16x8*)&Wl[srow*32 + scol] = wv0;
    *(s16x8*)&Wl[(srow+64)*32 + scol] = wv1;
    __syncthreads();
    s16x8 a[4], b[4];
    #pragma unroll
    for(int mi = 0; mi < 4; ++mi) a[mi] = *(const s16x8*)&Al[(wr + mi*16 + frow)*32 + fcol];
    #pragma unroll
    for(int ni = 0; ni < 4; ++ni) b[ni] = *(const s16x8*)&Wl[(wc + ni*16 + frow)*32 + fcol];
    #pragma unroll
    for(int mi = 0; mi < 4; ++mi)
      #pragma unroll
      for(int ni = 0; ni < 4; ++ni)
        acc[mi][ni] = __builtin_amdgcn_mfma_f32_16x16x32_bf16(a[mi], b[ni], acc[mi][ni], 0, 0, 0);
  }
  #pragma unroll
  for(int mi = 0; mi < 4; ++mi){
    #pragma unroll
    for(int ni = 0; ni < 4; ++ni){
      const int col = n0 + wc + ni*16 + (lane & 15);
      const float bv = bias[col];
      #pragma unroll
      for(int r = 0; r < 4; ++r){
        const int row = m0 + wr + mi*16 + (lane >> 4)*4 + r;
        float v = acc[mi][ni][r] + bv;
        if(DOGELU) v = gelu_f(v);
        if(OUT == 0) ((float*)Cv)[(size_t)row*N + col] = v;
        else if(OUT == 1) ((float*)Cv)[(size_t)row*N + col] += v;
        else ((short*)Cv)[(size_t)row*N + col] = f2b(v);
      }
    }
  }
}

// ---------------- mel compress: (B,80,2000) -> (B,16,2000) ----------------
__global__ __launch_bounds__(256) void mel_kernel(const float* __restrict__ mel,
    const float* __restrict__ W, const float* __restrict__ bias, float* __restrict__ xm){
  __shared__ float Ws[16][80];
  __shared__ float bs[16];
  const int t = threadIdx.x;
  for(int i = t; i < 16*80; i += 256) Ws[i/80][i%80] = W[i];
  if(t < 16) bs[t] = bias[t];
  __syncthreads();
  int blk = blockIdx.x;
  int b = blk >> 3;
  int tc = (blk & 7) * 256 + t;
  if(tc >= 2000) return;
  float acc[16];
  #pragma unroll
  for(int o = 0; o < 16; ++o) acc[o] = bs[o];
  for(int c = 0; c < 80; ++c){
    float v = mel[((size_t)b*80 + c)*2000 + tc];
    #pragma unroll
    for(int o = 0; o < 16; ++o) acc[o] += v * Ws[o][c];
  }
  #pragma unroll
  for(int o = 0; o < 16; ++o) xm[((size_t)b*16 + o)*2000 + tc] = acc[o];
}

// ---------------- im2col conv1 -> bf16, K padded to 128 ----------------
__global__ __launch_bounds__(256) void im2col1b(const float* __restrict__ xm, short* __restrict__ A){
  size_t idx = (size_t)blockIdx.x * 256 + threadIdx.x; // 32000*128
  int col = idx & 127;
  size_t row = idx >> 7;
  int t1 = row % 1000, b = row / 1000;
  float v = 0.f;
  if(col < 112){
    int i = col / 7, k = col % 7;
    int src = 2*t1 + k - 3;
    if(src >= 0 && src < 2000) v = xm[((size_t)b*16 + i)*2000 + src];
  }
  A[idx] = f2b(v);
}

// ---------------- GroupNorm(1) stats over h1 (B,1000,128) ----------------
__global__ __launch_bounds__(256) void gn_stats(const float* __restrict__ h1, float* __restrict__ stats){
  int b = blockIdx.x, t = threadIdx.x;
  __shared__ double rs[256], rq[256];
  double s = 0, q = 0;
  const float* p = h1 + (size_t)b * 128000;
  for(int i = t; i < 128000; i += 256){ double v = p[i]; s += v; q += v*v; }
  rs[t] = s; rq[t] = q; __syncthreads();
  for(int s2 = 128; s2 > 0; s2 >>= 1){
    if(t < s2){ rs[t] += rs[t+s2]; rq[t] += rq[t+s2]; }
    __syncthreads();
  }
  if(t == 0){
    double mean = rs[0] / 128000.0;
    double var  = rq[0] / 128000.0 - mean*mean;
    stats[b*2]   = (float)mean;
    stats[b*2+1] = (float)(1.0 / sqrt(var + 1e-5));
  }
}

// ---------------- im2col conv2 (fused GroupNorm) -> bf16 ----------------
__global__ __launch_bounds__(256) void im2col2b(const float* __restrict__ h1,
    const float* __restrict__ stats, const float* __restrict__ gg,
    const float* __restrict__ gb, short* __restrict__ A){
  size_t idx = (size_t)blockIdx.x * 256 + threadIdx.x; // 16000*896
  int col = idx % 896;
  size_t row = idx / 896;
  int t2 = row % 500, b = row / 500;
  int i = col / 7, k = col % 7;
  int src = 2*t2 + k - 3;
  float v = 0.f;
  if(src >= 0 && src < 1000){
    float raw = h1[((size_t)b*1000 + src)*128 + i];
    v = (raw - stats[b*2]) * stats[b*2+1] * gg[i] + gb[i];
  }
  A[idx] = f2b(v);
}

// ---------------- post-conv: LN(D) + sinpos + star table -> X (fp32) ----------------
__global__ __launch_bounds__(256) void postconv(const float* __restrict__ xp,
    const float* __restrict__ cg, const float* __restrict__ cb,
    const float* __restrict__ star, const float* __restrict__ stab,
    float* __restrict__ x){
  int row = blockIdx.x, t = threadIdx.x;
  int s = row % 500, b = row / 500;
  __shared__ float red[256];
  float v = xp[(size_t)row*256 + t];
  red[t] = v; __syncthreads();
  for(int s2 = 128; s2 > 0; s2 >>= 1){ if(t < s2) red[t] += red[t+s2]; __syncthreads(); }
  float mean = red[0] / 256.f; __syncthreads();
  float d = v - mean;
  red[t] = d*d; __syncthreads();
  for(int s2 = 128; s2 > 0; s2 >>= 1){ if(t < s2) red[t] += red[t+s2]; __syncthreads(); }
  float rstd = 1.f / sqrtf(red[0]/256.f + 1e-5f);
  int j = t & 127;
  double f = exp((double)j * LKC);
  double a = (double)s * f;
  float pe = (float)(t < 128 ? sin(a) : cos(a));
  int bucket = (int)(star[b] * 2.0f);
  bucket = bucket < 0 ? 0 : (bucket > 19 ? 19 : bucket);
  x[(size_t)row*256 + t] = d*rstd*cg[t] + cb[t] + pe + stab[bucket*256 + t];
}

// ---------------- event features -> combined bf16 (B*NEV, 768) ----------------
__global__ __launch_bounds__(256) void event_feat(const int* __restrict__ events, short* __restrict__ comb){
  int blk = blockIdx.x;           // 8192
  int e = blk & 255, b = blk >> 8;
  const int* ev = events + b*256;
  int t = threadIdx.x;
  auto gof = [&](int i){ int j = i < 1 ? 1 : i; int d = ev[j] - ev[j-1]; return d < 1 ? 1 : d; };
  int gi = gof(e);
  double rb = 1.0, ra = 1.0;
  if(e != 0){
    rb = (double)gi / (double)gof(e-1);
    rb = rb < 0.1 ? 0.1 : (rb > 10.0 ? 10.0 : rb);
  }
  if(e != 255){
    ra = (double)gof(e+1) / (double)gi;
    ra = ra < 0.1 ? 0.1 : (ra > 10.0 ? 10.0 : ra);
  }
  int rbi = (int)(rb * 50.0);
  int rai = (int)(ra * 50.0);
  int gap = 5 * gi;
  int j = t & 127;
  double f = exp((double)j * LKC);
  double a0 = (double)rbi * f, a1 = (double)rai * f, a2 = (double)gap * f;
  size_t base = (size_t)blk * 768;
  comb[base + t]       = f2b((float)(t < 128 ? sin(a0) : cos(a0)));
  comb[base + 256 + t] = f2b((float)(t < 128 ? sin(a1) : cos(a1)));
  comb[base + 512 + t] = f2b((float)(t < 128 ? sin(a2) : cos(a2)));
}

// ---------------- scatter-add events into X ----------------
__global__ __launch_bounds__(256) void ev_scatter(const float* __restrict__ evout,
    const int* __restrict__ events, const unsigned char* __restrict__ mask,
    float* __restrict__ x){
  int blk = blockIdx.x; // 8192
  int e = blk & 255, b = blk >> 8;
  if(mask[b*256 + e]) return;
  int tp = events[b*256 + e] >> 2;
  tp = tp < 0 ? 0 : (tp > 499 ? 499 : tp);
  int t = threadIdx.x;
  atomicAdd(&x[((size_t)b*500 + tp)*256 + t], evout[(size_t)blk*256 + t]);
}

// ---------------- LayerNorm rows of 256 -> bf16 ----------------
__global__ __launch_bounds__(256) void ln_rows(const float* __restrict__ x,
    const float* __restrict__ g, const float* __restrict__ b, short* __restrict__ out){
  int row = blockIdx.x, t = threadIdx.x;
  __shared__ float red[256];
  float v = x[(size_t)row*256 + t];
  red[t] = v; __syncthreads();
  for(int s2 = 128; s2 > 0; s2 >>= 1){ if(t < s2) red[t] += red[t+s2]; __syncthreads(); }
  float mean = red[0] / 256.f; __syncthreads();
  float d = v - mean;
  red[t] = d*d; __syncthreads();
  for(int s2 = 128; s2 > 0; s2 >>= 1){ if(t < s2) red[t] += red[t+s2]; __syncthreads(); }
  float rstd = 1.f / sqrtf(red[0]/256.f + 1e-5f);
  out[(size_t)row*256 + t] = f2b(d*rstd*g[t] + b[t]);
}

// ---------------- MFMA flash attention: qkv bf16 (B,S,768) -> o bf16 (B,S,256) ----------------
// grid = B*H (256); block = 512 (8 waves). K[512][32] + V^T[32][520] staged in LDS.
// Swapped QK^T (scores S^T: q = lane&15), full-row softmax in regs,
// P -> bf16 via per-wave LDS buffer -> B-operand of PV mfma.
__global__ __launch_bounds__(512, 2) void attn_mfma(const short* __restrict__ qkv,
    short* __restrict__ o){
  __shared__ __align__(16) short Kl[512*32];     // 32 KB
  __shared__ __align__(16) short Vt[32*520];     // 33.3 KB (pad 8 -> stride 520)
  __shared__ __align__(16) short Pl[8][640];     // per-wave P buffer, row stride 40 shorts
  const int bh = blockIdx.x;
  const int h = bh & 7, b = bh >> 3;
  const int t = threadIdx.x;
  const int wid = t >> 6, lane = t & 63;
  const int lq = lane & 15, lg = lane >> 4;
  const short* base = qkv + (size_t)b * kS * 768;
  // ---- stage K rows + V transposed ----
  for(int idx = t; idx < 2048; idx += 512){
    int row = idx >> 2, c = idx & 3;
    s16x8 kv = {0,0,0,0,0,0,0,0};
    s16x8 vv = {0,0,0,0,0,0,0,0};
    if(row < kS){
      const short* rp = base + (size_t)row*768 + 256 + h*32 + c*8;
      kv = *(const s16x8*)rp;
      vv = *(const s16x8*)(rp + 256);
    }
    *(s16x8*)&Kl[row*32 + c*8] = kv;
    #pragma unroll
    for(int j = 0; j < 8; ++j) Vt[(c*8+j)*520 + row] = vv[j];
  }
  __syncthreads();
  const float scale = 0.17677669529663687f; // 1/sqrt(32)
  short* pw = &Pl[wid][0];
  for(int qi = 0; qi < 4; ++qi){
    const int qt = wid*4 + qi;
    const int q0 = qt*16;
    int qrow = q0 + lq; if(qrow > kS-1) qrow = kS-1;
    s16x8 qf = *(const s16x8*)(base + (size_t)qrow*768 + h*32 + lg*8);
    // ---- scores S^T: lane holds q=lq, keys kt*16 + lg*4 + r ----
    f32x4 sc[32];
    #pragma unroll
    for(int kt = 0; kt < 32; ++kt){
      s16x8 kf = *(const s16x8*)&Kl[(kt*16 + lq)*32 + lg*8];
      f32x4 z = {0.f,0.f,0.f,0.f};
      sc[kt] = __builtin_amdgcn_mfma_f32_16x16x32_bf16(kf, qf, z, 0, 0, 0);
    }
    // mask padded keys 500..511 (frag 31, lane groups lg>=1)
    if(lg >= 1){ sc[31][0] = -1e30f; sc[31][1] = -1e30f; sc[31][2] = -1e30f; sc[31][3] = -1e30f; }
    // ---- softmax (exact, full row) ----
    float m = -1e30f;
    #pragma unroll
    for(int kt = 0; kt < 32; ++kt)
      m = fmaxf(m, fmaxf(fmaxf(sc[kt][0], sc[kt][1]), fmaxf(sc[kt][2], sc[kt][3])));
    m = fmaxf(m, __shfl_xor(m, 16, 64));
    m = fmaxf(m, __shfl_xor(m, 32, 64));
    float l = 0.f;
    #pragma unroll
    for(int kt = 0; kt < 32; ++kt){
      #pragma unroll
      for(int r = 0; r < 4; ++r){
        float p = expf((sc[kt][r] - m) * scale);
        sc[kt][r] = p;
        l += p;
      }
    }
    l += __shfl_xor(l, 16, 64);
    l += __shfl_xor(l, 32, 64);
    // ---- PV: O^T[d][q] accumulated over 16 windows of 32 keys ----
    f32x4 oa0 = {0.f,0.f,0.f,0.f}, oa1 = {0.f,0.f,0.f,0.f};
    #pragma unroll
    for(int kt2 = 0; kt2 < 16; ++kt2){
      #pragma unroll
      for(int f = 0; f < 2; ++f){
        f32x4 p = sc[kt2*2 + f];
        uint2 pk;
        pk.x = (unsigned)(unsigned short)f2b(p[0]) | ((unsigned)(unsigned short)f2b(p[1]) << 16);
        pk.y = (unsigned)(unsigned short)f2b(p[2]) | ((unsigned)(unsigned short)f2b(p[3]) << 16);
        *(uint2*)&pw[lq*40 + f*16 + lg*4] = pk;
      }
      s16x8 pf = *(const s16x8*)&pw[lq*40 + lg*8];
      s16x8 v0 = *(const s16x8*)&Vt[lq*520 + kt2*32 + lg*8];
      s16x8 v1 = *(const s16x8*)&Vt[(16+lq)*520 + kt2*32 + lg*8];
      oa0 = __builtin_amdgcn_mfma_f32_16x16x32_bf16(v0, pf, oa0, 0, 0, 0);
      oa1 = __builtin_amdgcn_mfma_f32_16x16x32_bf16(v1, pf, oa1, 0, 0, 0);
    }
    // ---- epilogue: O[q][d] = O^T/l ----
    float inv = 1.f / l;
    int qw = q0 + lq;
    if(qw < kS){
      short* op = o + ((size_t)(b*kS + qw))*256 + h*32;
      uint2 w0, w1;
      w0.x = (unsigned)(unsigned short)f2b(oa0[0]*inv) | ((unsigned)(unsigned short)f2b(oa0[1]*inv) << 16);
      w0.y = (unsigned)(unsigned short)f2b(oa0[2]*inv) | ((unsigned)(unsigned short)f2b(oa0[3]*inv) << 16);
      w1.x = (unsigned)(unsigned short)f2b(oa1[0]*inv) | ((unsigned)(unsigned short)f2b(oa1[1]*inv) << 16);
      w1.y = (unsigned)(unsigned short)f2b(oa1[2]*inv) | ((unsigned)(unsigned short)f2b(oa1[3]*inv) << 16);
      *(uint2*)&op[lg*4] = w0;
      *(uint2*)&op[16 + lg*4] = w1;
    }
  }
}

// ---------------- attention pooling + LN + head ----------------
__global__ __launch_bounds__(256) void pool_head(const float* __restrict__ x,
    const float* __restrict__ pq, const float* __restrict__ og, const float* __restrict__ ob,
    const float* __restrict__ ohW, const float* __restrict__ ohb, float* __restrict__ out){
  int b = blockIdx.x, t = threadIdx.x;
  __shared__ float lg[500];
  __shared__ float red[256];
  const float* xb = x + (size_t)b * 500 * 256;
  for(int s = t; s < 500; s += 256){
    const float* xr = xb + (size_t)s * 256;
    float d = 0.f;
    for(int c = 0; c < 256; ++c) d += xr[c] * pq[c];
    lg[s] = d * 0.0625f;
  }
  __syncthreads();
  float m = -1e30f;
  for(int s = t; s < 500; s += 256) m = fmaxf(m, lg[s]);
  red[t] = m; __syncthreads();
  for(int s2 = 128; s2 > 0; s2 >>= 1){ if(t < s2) red[t] = fmaxf(red[t], red[t+s2]); __syncthreads(); }
  m = red[0]; __syncthreads();
  float ps = 0.f;
  for(int s = t; s < 500; s += 256){ float e = expf(lg[s] - m); lg[s] = e; ps += e; }
  red[t] = ps; __syncthreads();
  for(int s2 = 128; s2 > 0; s2 >>= 1){ if(t < s2) red[t] += red[t+s2]; __syncthreads(); }
  float inv = 1.f / red[0];
  __syncthreads();
  float acc = 0.f;
  for(int s = 0; s < 500; ++s) acc += lg[s] * xb[(size_t)s*256 + t];
  acc *= inv;
  __syncthreads();
  red[t] = acc; __syncthreads();
  for(int s2 = 128; s2 > 0; s2 >>= 1){ if(t < s2) red[t] += red[t+s2]; __syncthreads(); }
  float mean = red[0] / 256.f; __syncthreads();
  float d = acc - mean;
  red[t] = d*d; __syncthreads();
  for(int s2 = 128; s2 > 0; s2 >>= 1){ if(t < s2) red[t] += red[t+s2]; __syncthreads(); }
  float rstd = 1.f / sqrtf(red[0]/256.f + 1e-5f);
  __syncthreads();
  float val = (d*rstd*og[t] + ob[t]) * ohW[t];
  red[t] = val; __syncthreads();
  for(int s2 = 128; s2 > 0; s2 >>= 1){ if(t < s2) red[t] += red[t+s2]; __syncthreads(); }
  if(t == 0) out[b] = red[0] + ohb[0];
}

extern "C" void kernel_launch(void* const* d_in, const int* in_sizes, int n_in,
                              void* d_out, int out_size, void* d_ws, size_t ws_size,
                              hipStream_t stream){
  const float* mel      = (const float*)d_in[0];
  const int*   events   = (const int*)d_in[1];
  const unsigned char* emask = (const unsigned char*)d_in[2];
  const float* star     = (const float*)d_in[3];
  const float* mel_W    = (const float*)d_in[4];
  const float* mel_b    = (const float*)d_in[5];
  const float* conv1_w  = (const float*)d_in[6];
  const float* conv1_b  = (const float*)d_in[7];
  const float* gn_g     = (const float*)d_in[8];
  const float* gn_b     = (const float*)d_in[9];
  const float* conv2_w  = (const float*)d_in[10];
  const float* conv2_b  = (const float*)d_in[11];
  const float* cn_g     = (const float*)d_in[12];
  const float* cn_b     = (const float*)d_in[13];
  const float* star_tab = (const float*)d_in[14];
  const float* ep_W1    = (const float*)d_in[15];
  const float* ep_b1    = (const float*)d_in[16];
  const float* ep_W2    = (const float*)d_in[17];
  const float* ep_b2    = (const float*)d_in[18];
  const float* tl_Wqkv  = (const float*)d_in[19];
  const float* tl_bqkv  = (const float*)d_in[20];
  const float* tl_Wo    = (const float*)d_in[21];
  const float* tl_bo    = (const float*)d_in[22];
  const float* tl_ln1g  = (const float*)d_in[23];
  const float* tl_ln1b  = (const float*)d_in[24];
  const float* tl_ln2g  = (const float*)d_in[25];
  const float* tl_ln2b  = (const float*)d_in[26];
  const float* tl_W1    = (const float*)d_in[27];
  const float* tl_b1    = (const float*)d_in[28];
  const float* tl_W2    = (const float*)d_in[29];
  const float* tl_b2    = (const float*)d_in[30];
  const float* pool_q   = (const float*)d_in[31];
  const float* on_g     = (const float*)d_in[32];
  const float* on_b     = (const float*)d_in[33];
  const float* oh_W     = (const float*)d_in[34];
  const float* oh_b     = (const float*)d_in[35];
  (void)in_sizes; (void)n_in; (void)out_size; (void)ws_size;

  float* ws  = (float*)d_ws;
  float* X   = ws;                        // fp32 (B,S,256)          [0, 4.096M)
  short* XNB = (short*)(ws + 4096000);    // bf16 (B,S,256)
  short* OB  = (short*)(ws + 6144000);    // bf16 attn out (B,S,256)
  short* WB  = (short*)(ws + 8192000);    // bf16 weights (5.23M shorts)
  float* BIG = ws + 10812000;             // 17.86M floats scratch
  float* STATS = ws + 28671900;

  // WB sub-offsets (shorts)
  short* WBc1 = WB + 0;         // 128x128
  short* WBc2 = WB + 16384;     // 256x896
  short* WBe1 = WB + 245760;    // 256x768
  short* WBe2 = WB + 442368;    // 256x256
  short* WBqk = WB + 507904;    // 6 x 768x256
  short* WBwo = WB + 1687552;   // 6 x 256x256
  short* WBw1 = WB + 2080768;   // 6 x 1024x256
  short* WBw2 = WB + 3653632;   // 6 x 256x1024

  // BIG sub-layouts (element offsets in floats)
  float* XMEL = BIG;                       // (B,16,2000) fp32 1.024M
  short* A1B  = (short*)(BIG + 1024000);   // (32000,128) bf16
  float* H1   = BIG + 3072000;             // (B,1000,128) fp32 4.096M
  short* A2B  = (short*)(BIG + 7168000);   // (16000,896) bf16
  float* XPRE = BIG;                       // (B,S,256) fp32 (over dead XMEL/A1B)
  short* COMBB= (short*)BIG;               // (8192,768) bf16
  short* EHIDB= (short*)(BIG + 3146000);   // (8192,256) bf16
  float* EVO  = BIG + 4195000;             // (8192,256) fp32
  short* QKVB = (short*)BIG;               // (16000,768) bf16 = 6.144M floats
  short* HIDB = (short*)(BIG + 7168000);   // (16000,1024) bf16

  // ---- weight conversion ----
  conv1w_pad<<<128, 128, 0, stream>>>(conv1_w, WBc1);
  f2b_kernel<<<896, 256, 0, stream>>>(conv2_w, WBc2, 229376);
  f2b_kernel<<<768, 256, 0, stream>>>(ep_W1, WBe1, 196608);
  f2b_kernel<<<256, 256, 0, stream>>>(ep_W2, WBe2, 65536);
  f2b_kernel<<<4608, 256, 0, stream>>>(tl_Wqkv, WBqk, 1179648);
  f2b_kernel<<<1536, 256, 0, stream>>>(tl_Wo, WBwo, 393216);
  f2b_kernel<<<6144, 256, 0, stream>>>(tl_W1, WBw1, 1572864);
  f2b_kernel<<<6144, 256, 0, stream>>>(tl_W2, WBw2, 1572864);

  // ---- prologue ----
  mel_kernel<<<kB*8, 256, 0, stream>>>(mel, mel_W, mel_b, XMEL);
  im2col1b<<<16000, 256, 0, stream>>>(XMEL, A1B);
  gemm_mfma<0,true><<<dim3(1, 250), 256, 0, stream>>>(A1B, WBc1, conv1_b, H1, 32000, 128, 128);
  gn_stats<<<kB, 256, 0, stream>>>(H1, STATS);
  im2col2b<<<56000, 256, 0, stream>>>(H1, STATS, gn_g, gn_b, A2B);
  gemm_mfma<0,true><<<dim3(2, 125), 256, 0, stream>>>(A2B, WBc2, conv2_b, XPRE, 16000, 256, 896);
  postconv<<<16000, 256, 0, stream>>>(XPRE, cn_g, cn_b, star, star_tab, X);
  // events
  event_feat<<<kB*256, 256, 0, stream>>>(events, COMBB);
  gemm_mfma<2,true><<<dim3(2, 64), 256, 0, stream>>>(COMBB, WBe1, ep_b1, EHIDB, 8192, 256, 768);
  gemm_mfma<0,false><<<dim3(2, 64), 256, 0, stream>>>(EHIDB, WBe2, ep_b2, EVO, 8192, 256, 256);
  ev_scatter<<<kB*256, 256, 0, stream>>>(EVO, events, emask, X);

  // ---- transformer layers ----
  for(int i = 0; i < 6; ++i){
    ln_rows<<<16000, 256, 0, stream>>>(X, tl_ln1g + i*256, tl_ln1b + i*256, XNB);
    gemm_mfma<2,false><<<dim3(6, 125), 256, 0, stream>>>(XNB, WBqk + (size_t)i*196608, tl_bqkv + i*768, QKVB, 16000, 768, 256);
    attn_mfma<<<kB*kH, 512, 0, stream>>>(QKVB, OB);
    gemm_mfma<1,false><<<dim3(2, 125), 256, 0, stream>>>(OB, WBwo + (size_t)i*65536, tl_bo + i*256, X, 16000, 256, 256);
    ln_rows<<<16000, 256, 0, stream>>>(X, tl_ln2g + i*256, tl_ln2b + i*256, XNB);
    gemm_mfma<2,true><<<dim3(8, 125), 256, 0, stream>>>(XNB, WBw1 + (size_t)i*262144, tl_b1 + i*1024, HIDB, 16000, 1024, 256);
    gemm_mfma<1,false><<<dim3(2, 125), 256, 0, stream>>>(HIDB, WBw2 + (size_t)i*262144, tl_b2 + i*256, X, 16000, 256, 1024);
  }

  // ---- pooling + head ----
  pool_head<<<kB, 256, 0, stream>>>(X, pool_q, on_g, on_b, oh_W, oh_b, (float*)d_out);
}

// Round 5
// 1599.767 us; speedup vs baseline: 10.5637x; 1.1191x over previous
//
#include <hip/hip_runtime.h>
#include <math.h>

namespace {
constexpr int kB = 32;
constexpr int kS = 500;
constexpr int kH = 8;
}
// -ln(10000)/127
#define LKC (-0.07252236513366287)

typedef __attribute__((ext_vector_type(8))) short s16x8;
typedef __attribute__((ext_vector_type(4))) float f32x4;

__device__ __forceinline__ float gelu_f(float x){
  return 0.5f * x * (1.0f + erff(x * 0.7071067811865476f));
}
__device__ __forceinline__ float b2f(short s){
  union { unsigned u; float f; } x; x.u = ((unsigned)(unsigned short)s) << 16; return x.f;
}
__device__ __forceinline__ short f2b(float f){
  unsigned u = __float_as_uint(f);
  unsigned r = (u + 0x7fffu + ((u >> 16) & 1u)) >> 16;
  return (short)r;
}

// ---------------- fp32 -> bf16 converter ----------------
__global__ __launch_bounds__(256) void f2b_kernel(const float* __restrict__ in,
    short* __restrict__ out, int n){
  int i = blockIdx.x * 256 + threadIdx.x;
  if(i < n) out[i] = f2b(in[i]);
}
// conv1 weight: (128,112) -> bf16 padded to (128,128)
__global__ __launch_bounds__(128) void conv1w_pad(const float* __restrict__ w, short* __restrict__ out){
  int n = blockIdx.x, k = threadIdx.x;
  out[n*128 + k] = (k < 112) ? f2b(w[n*112 + k]) : (short)0;
}

// ---------------- MFMA GEMM v2: C[M,N] (op)= [GELU](A[M,K]@W[N,K]^T + bias) ----------------
// A, W bf16 row-major; bias fp32. OUT: 0=store fp32, 1=add fp32, 2=store bf16.
// M%128==0, N%128==0, K%64==0. 256 threads = 4 waves, each wave a 64x64 quadrant.
// BK=64; LDS row stride 64 shorts (8 x 16B slots); XOR swizzle phys_slot = slot^(row&7):
// staging writes are lane-linear (conflict-free), frag reads 2-way (free).
template<int OUT, bool DOGELU>
__global__ __launch_bounds__(256) void gemm_mfma(const short* __restrict__ A,
    const short* __restrict__ W, const float* __restrict__ bias,
    void* __restrict__ Cv, int M, int N, int K){
  __shared__ __align__(16) short Al[128*64];
  __shared__ __align__(16) short Wl[128*64];
  const int t = threadIdx.x;
  const int wid = t >> 6, lane = t & 63;
  const int m0 = blockIdx.y * 128, n0 = blockIdx.x * 128;
  const int wr = (wid >> 1) * 64, wc = (wid & 1) * 64;
  const int frow = lane & 15, lg = lane >> 4;
  // staging map: chunk c = t + 256*j -> row = rA + 32j, phys slot = t&7,
  // logical slot = (t&7) ^ (row&7) (row&7 == rA&7 for all j)
  const int rA = t >> 3;
  const int sA = (t & 7) ^ (rA & 7);
  const short* Aq = A + (size_t)(m0 + rA) * K + sA * 8;
  const short* Wq = W + (size_t)(n0 + rA) * K + sA * 8;
  f32x4 acc[4][4] = {};
  for(int k0 = 0; k0 < K; k0 += 64){
    s16x8 av[4], wv[4];
    #pragma unroll
    for(int j = 0; j < 4; ++j){
      av[j] = *(const s16x8*)(Aq + k0 + (size_t)(32*j)*K);
      wv[j] = *(const s16x8*)(Wq + k0 + (size_t)(32*j)*K);
    }
    __syncthreads();
    #pragma unroll
    for(int j = 0; j < 4; ++j){
      *(s16x8*)&Al[t*8 + j*2048] = av[j];
      *(s16x8*)&Wl[t*8 + j*2048] = wv[j];
    }
    __syncthreads();
    #pragma unroll
    for(int kh = 0; kh < 2; ++kh){
      s16x8 a[4], b[4];
      #pragma unroll
      for(int mi = 0; mi < 4; ++mi){
        int r = wr + mi*16 + frow;
        a[mi] = *(const s16x8*)&Al[r*64 + (((kh*4 + lg) ^ (r & 7)) * 8)];
      }
      #pragma unroll
      for(int ni = 0; ni < 4; ++ni){
        int r = wc + ni*16 + frow;
        b[ni] = *(const s16x8*)&Wl[r*64 + (((kh*4 + lg) ^ (r & 7)) * 8)];
      }
      #pragma unroll
      for(int mi = 0; mi < 4; ++mi)
        #pragma unroll
        for(int ni = 0; ni < 4; ++ni)
          acc[mi][ni] = __builtin_amdgcn_mfma_f32_16x16x32_bf16(a[mi], b[ni], acc[mi][ni], 0, 0, 0);
    }
  }
  #pragma unroll
  for(int mi = 0; mi < 4; ++mi){
    #pragma unroll
    for(int ni = 0; ni < 4; ++ni){
      const int col = n0 + wc + ni*16 + (lane & 15);
      const float bv = bias[col];
      #pragma unroll
      for(int r = 0; r < 4; ++r){
        const int row = m0 + wr + mi*16 + (lane >> 4)*4 + r;
        float v = acc[mi][ni][r] + bv;
        if(DOGELU) v = gelu_f(v);
        if(OUT == 0) ((float*)Cv)[(size_t)row*N + col] = v;
        else if(OUT == 1) ((float*)Cv)[(size_t)row*N + col] += v;
        else ((short*)Cv)[(size_t)row*N + col] = f2b(v);
      }
    }
  }
}

// ---------------- mel compress: (B,80,2000) -> (B,16,2000) ----------------
__global__ __launch_bounds__(256) void mel_kernel(const float* __restrict__ mel,
    const float* __restrict__ W, const float* __restrict__ bias, float* __restrict__ xm){
  __shared__ float Ws[16][80];
  __shared__ float bs[16];
  const int t = threadIdx.x;
  for(int i = t; i < 16*80; i += 256) Ws[i/80][i%80] = W[i];
  if(t < 16) bs[t] = bias[t];
  __syncthreads();
  int blk = blockIdx.x;
  int b = blk >> 3;
  int tc = (blk & 7) * 256 + t;
  if(tc >= 2000) return;
  float acc[16];
  #pragma unroll
  for(int o = 0; o < 16; ++o) acc[o] = bs[o];
  for(int c = 0; c < 80; ++c){
    float v = mel[((size_t)b*80 + c)*2000 + tc];
    #pragma unroll
    for(int o = 0; o < 16; ++o) acc[o] += v * Ws[o][c];
  }
  #pragma unroll
  for(int o = 0; o < 16; ++o) xm[((size_t)b*16 + o)*2000 + tc] = acc[o];
}

// ---------------- im2col conv1 -> bf16, K padded to 128 ----------------
__global__ __launch_bounds__(256) void im2col1b(const float* __restrict__ xm, short* __restrict__ A){
  size_t idx = (size_t)blockIdx.x * 256 + threadIdx.x; // 32000*128
  int col = idx & 127;
  size_t row = idx >> 7;
  int t1 = row % 1000, b = row / 1000;
  float v = 0.f;
  if(col < 112){
    int i = col / 7, k = col % 7;
    int src = 2*t1 + k - 3;
    if(src >= 0 && src < 2000) v = xm[((size_t)b*16 + i)*2000 + src];
  }
  A[idx] = f2b(v);
}

// ---------------- GroupNorm(1) stats: two-stage ----------------
__global__ __launch_bounds__(256) void gn_part(const float* __restrict__ h1, double* __restrict__ part){
  int blk = blockIdx.x;  // 256 = 32 b x 8 segs
  const float* p = h1 + (size_t)blk * 16000;
  int t = threadIdx.x;
  double s = 0, q = 0;
  for(int i = t; i < 16000; i += 256){ double v = p[i]; s += v; q += v*v; }
  __shared__ double rs[256], rq[256];
  rs[t] = s; rq[t] = q; __syncthreads();
  for(int s2 = 128; s2 > 0; s2 >>= 1){
    if(t < s2){ rs[t] += rs[t+s2]; rq[t] += rq[t+s2]; }
    __syncthreads();
  }
  if(t == 0){ part[blk*2] = rs[0]; part[blk*2+1] = rq[0]; }
}
__global__ __launch_bounds__(256) void gn_final(const double* __restrict__ part, float* __restrict__ stats){
  int t = threadIdx.x;     // 256 = 32 b x 8
  int b = t >> 3;
  double s = part[t*2], q = part[t*2+1];
  s += __shfl_xor(s, 1); q += __shfl_xor(q, 1);
  s += __shfl_xor(s, 2); q += __shfl_xor(q, 2);
  s += __shfl_xor(s, 4); q += __shfl_xor(q, 4);
  if((t & 7) == 0){
    double mean = s / 128000.0;
    double var  = q / 128000.0 - mean*mean;
    stats[b*2]   = (float)mean;
    stats[b*2+1] = (float)(1.0 / sqrt(var + 1e-5));
  }
}

// ---------------- im2col conv2 (fused GroupNorm) -> bf16 ----------------
__global__ __launch_bounds__(256) void im2col2b(const float* __restrict__ h1,
    const float* __restrict__ stats, const float* __restrict__ gg,
    const float* __restrict__ gb, short* __restrict__ A){
  size_t idx = (size_t)blockIdx.x * 256 + threadIdx.x; // 16000*896
  int col = idx % 896;
  size_t row = idx / 896;
  int t2 = row % 500, b = row / 500;
  int i = col / 7, k = col % 7;
  int src = 2*t2 + k - 3;
  float v = 0.f;
  if(src >= 0 && src < 1000){
    float raw = h1[((size_t)b*1000 + src)*128 + i];
    v = (raw - stats[b*2]) * stats[b*2+1] * gg[i] + gb[i];
  }
  A[idx] = f2b(v);
}

// ---------------- post-conv: LN(D) + sinpos + star table -> X (fp32) ----------------
__global__ __launch_bounds__(256) void postconv(const float* __restrict__ xp,
    const float* __restrict__ cg, const float* __restrict__ cb,
    const float* __restrict__ star, const float* __restrict__ stab,
    float* __restrict__ x){
  int row = blockIdx.x, t = threadIdx.x;
  int s = row % 500, b = row / 500;
  __shared__ float red[256];
  float v = xp[(size_t)row*256 + t];
  red[t] = v; __syncthreads();
  for(int s2 = 128; s2 > 0; s2 >>= 1){ if(t < s2) red[t] += red[t+s2]; __syncthreads(); }
  float mean = red[0] / 256.f; __syncthreads();
  float d = v - mean;
  red[t] = d*d; __syncthreads();
  for(int s2 = 128; s2 > 0; s2 >>= 1){ if(t < s2) red[t] += red[t+s2]; __syncthreads(); }
  float rstd = 1.f / sqrtf(red[0]/256.f + 1e-5f);
  int j = t & 127;
  double f = exp((double)j * LKC);
  double a = (double)s * f;
  float pe = (float)(t < 128 ? sin(a) : cos(a));
  int bucket = (int)(star[b] * 2.0f);
  bucket = bucket < 0 ? 0 : (bucket > 19 ? 19 : bucket);
  x[(size_t)row*256 + t] = d*rstd*cg[t] + cb[t] + pe + stab[bucket*256 + t];
}

// ---------------- event features -> combined bf16 (B*NEV, 768) ----------------
__global__ __launch_bounds__(256) void event_feat(const int* __restrict__ events, short* __restrict__ comb){
  int blk = blockIdx.x;           // 8192
  int e = blk & 255, b = blk >> 8;
  const int* ev = events + b*256;
  int t = threadIdx.x;
  auto gof = [&](int i){ int j = i < 1 ? 1 : i; int d = ev[j] - ev[j-1]; return d < 1 ? 1 : d; };
  int gi = gof(e);
  double rb = 1.0, ra = 1.0;
  if(e != 0){
    rb = (double)gi / (double)gof(e-1);
    rb = rb < 0.1 ? 0.1 : (rb > 10.0 ? 10.0 : rb);
  }
  if(e != 255){
    ra = (double)gof(e+1) / (double)gi;
    ra = ra < 0.1 ? 0.1 : (ra > 10.0 ? 10.0 : ra);
  }
  int rbi = (int)(rb * 50.0);
  int rai = (int)(ra * 50.0);
  int gap = 5 * gi;
  int j = t & 127;
  double f = exp((double)j * LKC);
  double a0 = (double)rbi * f, a1 = (double)rai * f, a2 = (double)gap * f;
  size_t base = (size_t)blk * 768;
  comb[base + t]       = f2b((float)(t < 128 ? sin(a0) : cos(a0)));
  comb[base + 256 + t] = f2b((float)(t < 128 ? sin(a1) : cos(a1)));
  comb[base + 512 + t] = f2b((float)(t < 128 ? sin(a2) : cos(a2)));
}

// ---------------- scatter-add events into X ----------------
__global__ __launch_bounds__(256) void ev_scatter(const float* __restrict__ evout,
    const int* __restrict__ events, const unsigned char* __restrict__ mask,
    float* __restrict__ x){
  int blk = blockIdx.x; // 8192
  int e = blk & 255, b = blk >> 8;
  if(mask[b*256 + e]) return;
  int tp = events[b*256 + e] >> 2;
  tp = tp < 0 ? 0 : (tp > 499 ? 499 : tp);
  int t = threadIdx.x;
  atomicAdd(&x[((size_t)b*500 + tp)*256 + t], evout[(size_t)blk*256 + t]);
}

// ---------------- LayerNorm rows of 256 -> bf16 (wave-shuffle reduce) ----------------
__global__ __launch_bounds__(256) void ln_rows(const float* __restrict__ x,
    const float* __restrict__ g, const float* __restrict__ b, short* __restrict__ out){
  int row = blockIdx.x, t = threadIdx.x;
  int wid = t >> 6, lane = t & 63;
  __shared__ float sm[8];
  float v = x[(size_t)row*256 + t];
  float s = v;
  #pragma unroll
  for(int o = 1; o < 64; o <<= 1) s += __shfl_xor(s, o);
  if(lane == 0) sm[wid] = s;
  __syncthreads();
  float mean = (sm[0] + sm[1] + sm[2] + sm[3]) * (1.f/256.f);
  float d = v - mean;
  float q = d*d;
  #pragma unroll
  for(int o = 1; o < 64; o <<= 1) q += __shfl_xor(q, o);
  if(lane == 0) sm[4 + wid] = q;
  __syncthreads();
  float rstd = 1.f / sqrtf((sm[4] + sm[5] + sm[6] + sm[7]) * (1.f/256.f) + 1e-5f);
  out[(size_t)row*256 + t] = f2b(d*rstd*g[t] + b[t]);
}

// ---------------- MFMA flash attention: qkv bf16 (B,S,768) -> o bf16 (B,S,256) ----------------
__global__ __launch_bounds__(512, 2) void attn_mfma(const short* __restrict__ qkv,
    short* __restrict__ o){
  __shared__ __align__(16) short Kl[512*32];     // 32 KB
  __shared__ __align__(16) short Vt[32*520];     // 33.3 KB (pad 8 -> stride 520)
  __shared__ __align__(16) short Pl[8][640];     // per-wave P buffer, row stride 40 shorts
  const int bh = blockIdx.x;
  const int h = bh & 7, b = bh >> 3;
  const int t = threadIdx.x;
  const int wid = t >> 6, lane = t & 63;
  const int lq = lane & 15, lg = lane >> 4;
  const short* base = qkv + (size_t)b * kS * 768;
  for(int idx = t; idx < 2048; idx += 512){
    int row = idx >> 2, c = idx & 3;
    s16x8 kv = {0,0,0,0,0,0,0,0};
    s16x8 vv = {0,0,0,0,0,0,0,0};
    if(row < kS){
      const short* rp = base + (size_t)row*768 + 256 + h*32 + c*8;
      kv = *(const s16x8*)rp;
      vv = *(const s16x8*)(rp + 256);
    }
    *(s16x8*)&Kl[row*32 + c*8] = kv;
    #pragma unroll
    for(int j = 0; j < 8; ++j) Vt[(c*8+j)*520 + row] = vv[j];
  }
  __syncthreads();
  const float scale = 0.17677669529663687f; // 1/sqrt(32)
  short* pw = &Pl[wid][0];
  for(int qi = 0; qi < 4; ++qi){
    const int qt = wid*4 + qi;
    const int q0 = qt*16;
    int qrow = q0 + lq; if(qrow > kS-1) qrow = kS-1;
    s16x8 qf = *(const s16x8*)(base + (size_t)qrow*768 + h*32 + lg*8);
    f32x4 sc[32];
    #pragma unroll
    for(int kt = 0; kt < 32; ++kt){
      s16x8 kf = *(const s16x8*)&Kl[(kt*16 + lq)*32 + lg*8];
      f32x4 z = {0.f,0.f,0.f,0.f};
      sc[kt] = __builtin_amdgcn_mfma_f32_16x16x32_bf16(kf, qf, z, 0, 0, 0);
    }
    if(lg >= 1){ sc[31][0] = -1e30f; sc[31][1] = -1e30f; sc[31][2] = -1e30f; sc[31][3] = -1e30f; }
    float m = -1e30f;
    #pragma unroll
    for(int kt = 0; kt < 32; ++kt)
      m = fmaxf(m, fmaxf(fmaxf(sc[kt][0], sc[kt][1]), fmaxf(sc[kt][2], sc[kt][3])));
    m = fmaxf(m, __shfl_xor(m, 16, 64));
    m = fmaxf(m, __shfl_xor(m, 32, 64));
    float l = 0.f;
    #pragma unroll
    for(int kt = 0; kt < 32; ++kt){
      #pragma unroll
      for(int r = 0; r < 4; ++r){
        float p = expf((sc[kt][r] - m) * scale);
        sc[kt][r] = p;
        l += p;
      }
    }
    l += __shfl_xor(l, 16, 64);
    l += __shfl_xor(l, 32, 64);
    f32x4 oa0 = {0.f,0.f,0.f,0.f}, oa1 = {0.f,0.f,0.f,0.f};
    #pragma unroll
    for(int kt2 = 0; kt2 < 16; ++kt2){
      #pragma unroll
      for(int f = 0; f < 2; ++f){
        f32x4 p = sc[kt2*2 + f];
        uint2 pk;
        pk.x = (unsigned)(unsigned short)f2b(p[0]) | ((unsigned)(unsigned short)f2b(p[1]) << 16);
        pk.y = (unsigned)(unsigned short)f2b(p[2]) | ((unsigned)(unsigned short)f2b(p[3]) << 16);
        *(uint2*)&pw[lq*40 + f*16 + lg*4] = pk;
      }
      s16x8 pf = *(const s16x8*)&pw[lq*40 + lg*8];
      s16x8 v0 = *(const s16x8*)&Vt[lq*520 + kt2*32 + lg*8];
      s16x8 v1 = *(const s16x8*)&Vt[(16+lq)*520 + kt2*32 + lg*8];
      oa0 = __builtin_amdgcn_mfma_f32_16x16x32_bf16(v0, pf, oa0, 0, 0, 0);
      oa1 = __builtin_amdgcn_mfma_f32_16x16x32_bf16(v1, pf, oa1, 0, 0, 0);
    }
    float inv = 1.f / l;
    int qw = q0 + lq;
    if(qw < kS){
      short* op = o + ((size_t)(b*kS + qw))*256 + h*32;
      uint2 w0, w1;
      w0.x = (unsigned)(unsigned short)f2b(oa0[0]*inv) | ((unsigned)(unsigned short)f2b(oa0[1]*inv) << 16);
      w0.y = (unsigned)(unsigned short)f2b(oa0[2]*inv) | ((unsigned)(unsigned short)f2b(oa0[3]*inv) << 16);
      w1.x = (unsigned)(unsigned short)f2b(oa1[0]*inv) | ((unsigned)(unsigned short)f2b(oa1[1]*inv) << 16);
      w1.y = (unsigned)(unsigned short)f2b(oa1[2]*inv) | ((unsigned)(unsigned short)f2b(oa1[3]*inv) << 16);
      *(uint2*)&op[lg*4] = w0;
      *(uint2*)&op[16 + lg*4] = w1;
    }
  }
}

// ---------------- attention pooling + LN + head ----------------
__global__ __launch_bounds__(256) void pool_head(const float* __restrict__ x,
    const float* __restrict__ pq, const float* __restrict__ og, const float* __restrict__ ob,
    const float* __restrict__ ohW, const float* __restrict__ ohb, float* __restrict__ out){
  int b = blockIdx.x, t = threadIdx.x;
  __shared__ float lg[500];
  __shared__ float red[256];
  const float* xb = x + (size_t)b * 500 * 256;
  for(int s = t; s < 500; s += 256){
    const float* xr = xb + (size_t)s * 256;
    float d = 0.f;
    for(int c = 0; c < 256; ++c) d += xr[c] * pq[c];
    lg[s] = d * 0.0625f;
  }
  __syncthreads();
  float m = -1e30f;
  for(int s = t; s < 500; s += 256) m = fmaxf(m, lg[s]);
  red[t] = m; __syncthreads();
  for(int s2 = 128; s2 > 0; s2 >>= 1){ if(t < s2) red[t] = fmaxf(red[t], red[t+s2]); __syncthreads(); }
  m = red[0]; __syncthreads();
  float ps = 0.f;
  for(int s = t; s < 500; s += 256){ float e = expf(lg[s] - m); lg[s] = e; ps += e; }
  red[t] = ps; __syncthreads();
  for(int s2 = 128; s2 > 0; s2 >>= 1){ if(t < s2) red[t] += red[t+s2]; __syncthreads(); }
  float inv = 1.f / red[0];
  __syncthreads();
  float acc = 0.f;
  for(int s = 0; s < 500; ++s) acc += lg[s] * xb[(size_t)s*256 + t];
  acc *= inv;
  __syncthreads();
  red[t] = acc; __syncthreads();
  for(int s2 = 128; s2 > 0; s2 >>= 1){ if(t < s2) red[t] += red[t+s2]; __syncthreads(); }
  float mean = red[0] / 256.f; __syncthreads();
  float d = acc - mean;
  red[t] = d*d; __syncthreads();
  for(int s2 = 128; s2 > 0; s2 >>= 1){ if(t < s2) red[t] += red[t+s2]; __syncthreads(); }
  float rstd = 1.f / sqrtf(red[0]/256.f + 1e-5f);
  __syncthreads();
  float val = (d*rstd*og[t] + ob[t]) * ohW[t];
  red[t] = val; __syncthreads();
  for(int s2 = 128; s2 > 0; s2 >>= 1){ if(t < s2) red[t] += red[t+s2]; __syncthreads(); }
  if(t == 0) out[b] = red[0] + ohb[0];
}

extern "C" void kernel_launch(void* const* d_in, const int* in_sizes, int n_in,
                              void* d_out, int out_size, void* d_ws, size_t ws_size,
                              hipStream_t stream){
  const float* mel      = (const float*)d_in[0];
  const int*   events   = (const int*)d_in[1];
  const unsigned char* emask = (const unsigned char*)d_in[2];
  const float* star     = (const float*)d_in[3];
  const float* mel_W    = (const float*)d_in[4];
  const float* mel_b    = (const float*)d_in[5];
  const float* conv1_w  = (const float*)d_in[6];
  const float* conv1_b  = (const float*)d_in[7];
  const float* gn_g     = (const float*)d_in[8];
  const float* gn_b     = (const float*)d_in[9];
  const float* conv2_w  = (const float*)d_in[10];
  const float* conv2_b  = (const float*)d_in[11];
  const float* cn_g     = (const float*)d_in[12];
  const float* cn_b     = (const float*)d_in[13];
  const float* star_tab = (const float*)d_in[14];
  const float* ep_W1    = (const float*)d_in[15];
  const float* ep_b1    = (const float*)d_in[16];
  const float* ep_W2    = (const float*)d_in[17];
  const float* ep_b2    = (const float*)d_in[18];
  const float* tl_Wqkv  = (const float*)d_in[19];
  const float* tl_bqkv  = (const float*)d_in[20];
  const float* tl_Wo    = (const float*)d_in[21];
  const float* tl_bo    = (const float*)d_in[22];
  const float* tl_ln1g  = (const float*)d_in[23];
  const float* tl_ln1b  = (const float*)d_in[24];
  const float* tl_ln2g  = (const float*)d_in[25];
  const float* tl_ln2b  = (const float*)d_in[26];
  const float* tl_W1    = (const float*)d_in[27];
  const float* tl_b1    = (const float*)d_in[28];
  const float* tl_W2    = (const float*)d_in[29];
  const float* tl_b2    = (const float*)d_in[30];
  const float* pool_q   = (const float*)d_in[31];
  const float* on_g     = (const float*)d_in[32];
  const float* on_b     = (const float*)d_in[33];
  const float* oh_W     = (const float*)d_in[34];
  const float* oh_b     = (const float*)d_in[35];
  (void)in_sizes; (void)n_in; (void)out_size; (void)ws_size;

  float* ws  = (float*)d_ws;
  float* X   = ws;                        // fp32 (B,S,256)          [0, 4.096M)
  short* XNB = (short*)(ws + 4096000);    // bf16 (B,S,256)
  short* OB  = (short*)(ws + 6144000);    // bf16 attn out (B,S,256)
  short* WB  = (short*)(ws + 8192000);    // bf16 weights (5.23M shorts)
  float* BIG = ws + 10812000;             // 17.86M floats scratch
  double* PART = (double*)(ws + 28668000);// 256 x {s,q} doubles (1024 floats)
  float* STATS = ws + 28671900;

  // WB sub-offsets (shorts)
  short* WBc1 = WB + 0;         // 128x128
  short* WBc2 = WB + 16384;     // 256x896
  short* WBe1 = WB + 245760;    // 256x768
  short* WBe2 = WB + 442368;    // 256x256
  short* WBqk = WB + 507904;    // 6 x 768x256
  short* WBwo = WB + 1687552;   // 6 x 256x256
  short* WBw1 = WB + 2080768;   // 6 x 1024x256
  short* WBw2 = WB + 3653632;   // 6 x 256x1024

  // BIG sub-layouts (element offsets in floats)
  float* XMEL = BIG;                       // (B,16,2000) fp32 1.024M
  short* A1B  = (short*)(BIG + 1024000);   // (32000,128) bf16
  float* H1   = BIG + 3072000;             // (B,1000,128) fp32 4.096M
  short* A2B  = (short*)(BIG + 7168000);   // (16000,896) bf16
  float* XPRE = BIG;                       // (B,S,256) fp32 (over dead XMEL/A1B)
  short* COMBB= (short*)BIG;               // (8192,768) bf16
  short* EHIDB= (short*)(BIG + 3146000);   // (8192,256) bf16
  float* EVO  = BIG + 4195000;             // (8192,256) fp32
  short* QKVB = (short*)BIG;               // (16000,768) bf16 = 6.144M floats
  short* HIDB = (short*)(BIG + 7168000);   // (16000,1024) bf16

  // ---- weight conversion ----
  conv1w_pad<<<128, 128, 0, stream>>>(conv1_w, WBc1);
  f2b_kernel<<<896, 256, 0, stream>>>(conv2_w, WBc2, 229376);
  f2b_kernel<<<768, 256, 0, stream>>>(ep_W1, WBe1, 196608);
  f2b_kernel<<<256, 256, 0, stream>>>(ep_W2, WBe2, 65536);
  f2b_kernel<<<4608, 256, 0, stream>>>(tl_Wqkv, WBqk, 1179648);
  f2b_kernel<<<1536, 256, 0, stream>>>(tl_Wo, WBwo, 393216);
  f2b_kernel<<<6144, 256, 0, stream>>>(tl_W1, WBw1, 1572864);
  f2b_kernel<<<6144, 256, 0, stream>>>(tl_W2, WBw2, 1572864);

  // ---- prologue ----
  mel_kernel<<<kB*8, 256, 0, stream>>>(mel, mel_W, mel_b, XMEL);
  im2col1b<<<16000, 256, 0, stream>>>(XMEL, A1B);
  gemm_mfma<0,true><<<dim3(1, 250), 256, 0, stream>>>(A1B, WBc1, conv1_b, H1, 32000, 128, 128);
  gn_part<<<256, 256, 0, stream>>>(H1, PART);
  gn_final<<<1, 256, 0, stream>>>(PART, STATS);
  im2col2b<<<56000, 256, 0, stream>>>(H1, STATS, gn_g, gn_b, A2B);
  gemm_mfma<0,true><<<dim3(2, 125), 256, 0, stream>>>(A2B, WBc2, conv2_b, XPRE, 16000, 256, 896);
  postconv<<<16000, 256, 0, stream>>>(XPRE, cn_g, cn_b, star, star_tab, X);
  // events
  event_feat<<<kB*256, 256, 0, stream>>>(events, COMBB);
  gemm_mfma<2,true><<<dim3(2, 64), 256, 0, stream>>>(COMBB, WBe1, ep_b1, EHIDB, 8192, 256, 768);
  gemm_mfma<0,false><<<dim3(2, 64), 256, 0, stream>>>(EHIDB, WBe2, ep_b2, EVO, 8192, 256, 256);
  ev_scatter<<<kB*256, 256, 0, stream>>>(EVO, events, emask, X);

  // ---- transformer layers ----
  for(int i = 0; i < 6; ++i){
    ln_rows<<<16000, 256, 0, stream>>>(X, tl_ln1g + i*256, tl_ln1b + i*256, XNB);
    gemm_mfma<2,false><<<dim3(6, 125), 256, 0, stream>>>(XNB, WBqk + (size_t)i*196608, tl_bqkv + i*768, QKVB, 16000, 768, 256);
    attn_mfma<<<kB*kH, 512, 0, stream>>>(QKVB, OB);
    gemm_mfma<1,false><<<dim3(2, 125), 256, 0, stream>>>(OB, WBwo + (size_t)i*65536, tl_bo + i*256, X, 16000, 256, 256);
    ln_rows<<<16000, 256, 0, stream>>>(X, tl_ln2g + i*256, tl_ln2b + i*256, XNB);
    gemm_mfma<2,true><<<dim3(8, 125), 256, 0, stream>>>(XNB, WBw1 + (size_t)i*262144, tl_b1 + i*1024, HIDB, 16000, 1024, 256);
    gemm_mfma<1,false><<<dim3(2, 125), 256, 0, stream>>>(HIDB, WBw2 + (size_t)i*262144, tl_b2 + i*256, X, 16000, 256, 1024);
  }

  // ---- pooling + head ----
  pool_head<<<kB, 256, 0, stream>>>(X, pool_q, on_g, on_b, oh_W, oh_b, (float*)d_out);
}

// Round 6
// 994.952 us; speedup vs baseline: 16.9851x; 1.6079x over previous
//
#include <hip/hip_runtime.h>
#include <math.h>

namespace {
constexpr int kB = 32;
constexpr int kS = 500;
constexpr int kH = 8;
}
// -ln(10000)/127
#define LKC (-0.07252236513366287)

typedef __attribute__((ext_vector_type(8))) short s16x8;
typedef __attribute__((ext_vector_type(4))) float f32x4;

__device__ __forceinline__ float gelu_f(float x){
  return 0.5f * x * (1.0f + erff(x * 0.7071067811865476f));
}
__device__ __forceinline__ float b2f(short s){
  union { unsigned u; float f; } x; x.u = ((unsigned)(unsigned short)s) << 16; return x.f;
}
__device__ __forceinline__ short f2b(float f){
  unsigned u = __float_as_uint(f);
  unsigned r = (u + 0x7fffu + ((u >> 16) & 1u)) >> 16;
  return (short)r;
}

// ---------------- fp32 -> bf16 converter ----------------
__global__ __launch_bounds__(256) void f2b_kernel(const float* __restrict__ in,
    short* __restrict__ out, int n){
  int i = blockIdx.x * 256 + threadIdx.x;
  if(i < n) out[i] = f2b(in[i]);
}
// conv1 weight: (128,112) -> bf16 padded to (128,128)
__global__ __launch_bounds__(128) void conv1w_pad(const float* __restrict__ w, short* __restrict__ out){
  int n = blockIdx.x, k = threadIdx.x;
  out[n*128 + k] = (k < 112) ? f2b(w[n*112 + k]) : (short)0;
}

// ---------------- MFMA GEMM (256 thr, 128x128 tile): prologue/event GEMMs ----------------
template<int OUT, bool DOGELU>
__global__ __launch_bounds__(256) void gemm_mfma(const short* __restrict__ A,
    const short* __restrict__ W, const float* __restrict__ bias,
    void* __restrict__ Cv, int M, int N, int K){
  __shared__ __align__(16) short Al[128*64];
  __shared__ __align__(16) short Wl[128*64];
  const int t = threadIdx.x;
  const int wid = t >> 6, lane = t & 63;
  const int m0 = blockIdx.y * 128, n0 = blockIdx.x * 128;
  const int wr = (wid >> 1) * 64, wc = (wid & 1) * 64;
  const int frow = lane & 15, lg = lane >> 4;
  const int rA = t >> 3;
  const int sA = (t & 7) ^ (rA & 7);
  const short* Aq = A + (size_t)(m0 + rA) * K + sA * 8;
  const short* Wq = W + (size_t)(n0 + rA) * K + sA * 8;
  f32x4 acc[4][4] = {};
  for(int k0 = 0; k0 < K; k0 += 64){
    s16x8 av[4], wv[4];
    #pragma unroll
    for(int j = 0; j < 4; ++j){
      av[j] = *(const s16x8*)(Aq + k0 + (size_t)(32*j)*K);
      wv[j] = *(const s16x8*)(Wq + k0 + (size_t)(32*j)*K);
    }
    __syncthreads();
    #pragma unroll
    for(int j = 0; j < 4; ++j){
      *(s16x8*)&Al[t*8 + j*2048] = av[j];
      *(s16x8*)&Wl[t*8 + j*2048] = wv[j];
    }
    __syncthreads();
    #pragma unroll
    for(int kh = 0; kh < 2; ++kh){
      s16x8 a[4], b[4];
      #pragma unroll
      for(int mi = 0; mi < 4; ++mi){
        int r = wr + mi*16 + frow;
        a[mi] = *(const s16x8*)&Al[r*64 + (((kh*4 + lg) ^ (r & 7)) * 8)];
      }
      #pragma unroll
      for(int ni = 0; ni < 4; ++ni){
        int r = wc + ni*16 + frow;
        b[ni] = *(const s16x8*)&Wl[r*64 + (((kh*4 + lg) ^ (r & 7)) * 8)];
      }
      #pragma unroll
      for(int mi = 0; mi < 4; ++mi)
        #pragma unroll
        for(int ni = 0; ni < 4; ++ni)
          acc[mi][ni] = __builtin_amdgcn_mfma_f32_16x16x32_bf16(a[mi], b[ni], acc[mi][ni], 0, 0, 0);
    }
  }
  #pragma unroll
  for(int mi = 0; mi < 4; ++mi){
    #pragma unroll
    for(int ni = 0; ni < 4; ++ni){
      const int col = n0 + wc + ni*16 + (lane & 15);
      const float bv = bias[col];
      #pragma unroll
      for(int r = 0; r < 4; ++r){
        const int row = m0 + wr + mi*16 + (lane >> 4)*4 + r;
        float v = acc[mi][ni][r] + bv;
        if(DOGELU) v = gelu_f(v);
        if(OUT == 0) ((float*)Cv)[(size_t)row*N + col] = v;
        else if(OUT == 1) ((float*)Cv)[(size_t)row*N + col] += v;
        else ((short*)Cv)[(size_t)row*N + col] = f2b(v);
      }
    }
  }
}

// ---------------- gemm512: 64Mx256N tile, 512 threads, BK=64 ----------------
// OUT: 2=store bf16 (QKV, W1). grid (N/256, M/64).
template<bool DOGELU>
__global__ __launch_bounds__(512) void gemm512(const short* __restrict__ A,
    const short* __restrict__ W, const float* __restrict__ bias,
    short* __restrict__ C, int M, int N, int K){
  __shared__ __align__(16) short Al[64*64];
  __shared__ __align__(16) short Wl[256*64];
  const int t = threadIdx.x;
  const int wid = t >> 6, lane = t & 63;
  const int m0 = blockIdx.y * 64, n0 = blockIdx.x * 256;
  const int wm = wid >> 2, wn = wid & 3;
  const int frow = lane & 15, lg = lane >> 4;
  const int rA = t >> 3;
  const int sA = (t & 7) ^ (rA & 7);
  const short* Aq = A + (size_t)(m0 + rA) * K + sA * 8;
  const short* Wq = W + (size_t)(n0 + rA) * K + sA * 8;
  f32x4 acc[2][4] = {};
  for(int k0 = 0; k0 < K; k0 += 64){
    s16x8 av = *(const s16x8*)(Aq + k0);
    s16x8 wv[4];
    #pragma unroll
    for(int j = 0; j < 4; ++j)
      wv[j] = *(const s16x8*)(Wq + k0 + (size_t)(64*j)*K);
    __syncthreads();
    *(s16x8*)&Al[t*8] = av;
    #pragma unroll
    for(int j = 0; j < 4; ++j)
      *(s16x8*)&Wl[t*8 + j*4096] = wv[j];
    __syncthreads();
    #pragma unroll
    for(int kh = 0; kh < 2; ++kh){
      s16x8 a[2], b[4];
      #pragma unroll
      for(int mi = 0; mi < 2; ++mi){
        int r = wm*32 + mi*16 + frow;
        a[mi] = *(const s16x8*)&Al[r*64 + (((kh*4 + lg) ^ (r & 7)) * 8)];
      }
      #pragma unroll
      for(int ni = 0; ni < 4; ++ni){
        int r = wn*64 + ni*16 + frow;
        b[ni] = *(const s16x8*)&Wl[r*64 + (((kh*4 + lg) ^ (r & 7)) * 8)];
      }
      #pragma unroll
      for(int mi = 0; mi < 2; ++mi)
        #pragma unroll
        for(int ni = 0; ni < 4; ++ni)
          acc[mi][ni] = __builtin_amdgcn_mfma_f32_16x16x32_bf16(a[mi], b[ni], acc[mi][ni], 0, 0, 0);
    }
  }
  #pragma unroll
  for(int mi = 0; mi < 2; ++mi){
    #pragma unroll
    for(int ni = 0; ni < 4; ++ni){
      const int col = n0 + wn*64 + ni*16 + (lane & 15);
      const float bv = bias[col];
      #pragma unroll
      for(int r = 0; r < 4; ++r){
        const int row = m0 + wm*32 + mi*16 + (lane >> 4)*4 + r;
        float v = acc[mi][ni][r] + bv;
        if(DOGELU) v = gelu_f(v);
        C[(size_t)row*N + col] = f2b(v);
      }
    }
  }
}

// ---------------- gemm_ln: 64Mx256N, N==256: X += A@W^T+bias; optional row-LN -> XNB ----------------
template<bool DOLN>
__global__ __launch_bounds__(512) void gemm_ln(const short* __restrict__ A,
    const short* __restrict__ W, const float* __restrict__ bias,
    float* __restrict__ X, const float* __restrict__ lg_, const float* __restrict__ lb_,
    short* __restrict__ XNB, int M, int K){
  __shared__ __align__(16) short Al[64*64];
  __shared__ __align__(16) short Wl[256*64];
  __shared__ float sbuf[64][4];
  const int t = threadIdx.x;
  const int wid = t >> 6, lane = t & 63;
  const int m0 = blockIdx.y * 64;
  const int wm = wid >> 2, wn = wid & 3;
  const int frow = lane & 15, lg = lane >> 4;
  const int lq = lane & 15;
  const int rA = t >> 3;
  const int sA = (t & 7) ^ (rA & 7);
  const short* Aq = A + (size_t)(m0 + rA) * K + sA * 8;
  const short* Wq = W + (size_t)rA * K + sA * 8;
  f32x4 acc[2][4] = {};
  for(int k0 = 0; k0 < K; k0 += 64){
    s16x8 av = *(const s16x8*)(Aq + k0);
    s16x8 wv[4];
    #pragma unroll
    for(int j = 0; j < 4; ++j)
      wv[j] = *(const s16x8*)(Wq + k0 + (size_t)(64*j)*K);
    __syncthreads();
    *(s16x8*)&Al[t*8] = av;
    #pragma unroll
    for(int j = 0; j < 4; ++j)
      *(s16x8*)&Wl[t*8 + j*4096] = wv[j];
    __syncthreads();
    #pragma unroll
    for(int kh = 0; kh < 2; ++kh){
      s16x8 a[2], b[4];
      #pragma unroll
      for(int mi = 0; mi < 2; ++mi){
        int r = wm*32 + mi*16 + frow;
        a[mi] = *(const s16x8*)&Al[r*64 + (((kh*4 + lg) ^ (r & 7)) * 8)];
      }
      #pragma unroll
      for(int ni = 0; ni < 4; ++ni){
        int r = wn*64 + ni*16 + frow;
        b[ni] = *(const s16x8*)&Wl[r*64 + (((kh*4 + lg) ^ (r & 7)) * 8)];
      }
      #pragma unroll
      for(int mi = 0; mi < 2; ++mi)
        #pragma unroll
        for(int ni = 0; ni < 4; ++ni)
          acc[mi][ni] = __builtin_amdgcn_mfma_f32_16x16x32_bf16(a[mi], b[ni], acc[mi][ni], 0, 0, 0);
    }
  }
  // v = acc + bias + residual
  float v[2][4][4];
  #pragma unroll
  for(int mi = 0; mi < 2; ++mi)
    #pragma unroll
    for(int ni = 0; ni < 4; ++ni){
      const int col = wn*64 + ni*16 + lq;
      const float bv = bias[col];
      #pragma unroll
      for(int r = 0; r < 4; ++r){
        const int row = m0 + wm*32 + mi*16 + lg*4 + r;
        v[mi][ni][r] = acc[mi][ni][r] + bv + X[(size_t)row*256 + col];
      }
    }
  __syncthreads();   // protect sbuf (reused across K-loop's Al? separate buffer, just order)
  float vmean[2][4], vrstd[2][4];
  if(DOLN){
    // pass 1: row sums
    #pragma unroll
    for(int mi = 0; mi < 2; ++mi)
      #pragma unroll
      for(int r = 0; r < 4; ++r){
        float s = v[mi][0][r] + v[mi][1][r] + v[mi][2][r] + v[mi][3][r];
        s += __shfl_xor(s, 1); s += __shfl_xor(s, 2);
        s += __shfl_xor(s, 4); s += __shfl_xor(s, 8);
        if(lq == 0) sbuf[wm*32 + mi*16 + lg*4 + r][wn] = s;
      }
    __syncthreads();
    #pragma unroll
    for(int mi = 0; mi < 2; ++mi)
      #pragma unroll
      for(int r = 0; r < 4; ++r){
        int rl = wm*32 + mi*16 + lg*4 + r;
        vmean[mi][r] = (sbuf[rl][0] + sbuf[rl][1] + sbuf[rl][2] + sbuf[rl][3]) * (1.f/256.f);
      }
    __syncthreads();
    // pass 2: variance
    #pragma unroll
    for(int mi = 0; mi < 2; ++mi)
      #pragma unroll
      for(int r = 0; r < 4; ++r){
        float q = 0.f;
        #pragma unroll
        for(int ni = 0; ni < 4; ++ni){ float d = v[mi][ni][r] - vmean[mi][r]; q += d*d; }
        q += __shfl_xor(q, 1); q += __shfl_xor(q, 2);
        q += __shfl_xor(q, 4); q += __shfl_xor(q, 8);
        if(lq == 0) sbuf[wm*32 + mi*16 + lg*4 + r][wn] = q;
      }
    __syncthreads();
    #pragma unroll
    for(int mi = 0; mi < 2; ++mi)
      #pragma unroll
      for(int r = 0; r < 4; ++r){
        int rl = wm*32 + mi*16 + lg*4 + r;
        float Q = sbuf[rl][0] + sbuf[rl][1] + sbuf[rl][2] + sbuf[rl][3];
        vrstd[mi][r] = 1.f / sqrtf(Q * (1.f/256.f) + 1e-5f);
      }
  }
  #pragma unroll
  for(int mi = 0; mi < 2; ++mi)
    #pragma unroll
    for(int ni = 0; ni < 4; ++ni){
      const int col = wn*64 + ni*16 + lq;
      float gg = 0.f, bb = 0.f;
      if(DOLN){ gg = lg_[col]; bb = lb_[col]; }
      #pragma unroll
      for(int r = 0; r < 4; ++r){
        const int row = m0 + wm*32 + mi*16 + lg*4 + r;
        float val = v[mi][ni][r];
        X[(size_t)row*256 + col] = val;
        if(DOLN)
          XNB[(size_t)row*256 + col] = f2b((val - vmean[mi][r]) * vrstd[mi][r] * gg + bb);
      }
    }
}

// ---------------- mel compress: (B,80,2000) -> (B,16,2000) ----------------
__global__ __launch_bounds__(256) void mel_kernel(const float* __restrict__ mel,
    const float* __restrict__ W, const float* __restrict__ bias, float* __restrict__ xm){
  __shared__ float Ws[16][80];
  __shared__ float bs[16];
  const int t = threadIdx.x;
  for(int i = t; i < 16*80; i += 256) Ws[i/80][i%80] = W[i];
  if(t < 16) bs[t] = bias[t];
  __syncthreads();
  int blk = blockIdx.x;
  int b = blk >> 3;
  int tc = (blk & 7) * 256 + t;
  if(tc >= 2000) return;
  float acc[16];
  #pragma unroll
  for(int o = 0; o < 16; ++o) acc[o] = bs[o];
  for(int c = 0; c < 80; ++c){
    float v = mel[((size_t)b*80 + c)*2000 + tc];
    #pragma unroll
    for(int o = 0; o < 16; ++o) acc[o] += v * Ws[o][c];
  }
  #pragma unroll
  for(int o = 0; o < 16; ++o) xm[((size_t)b*16 + o)*2000 + tc] = acc[o];
}

// ---------------- im2col conv1 -> bf16, K padded to 128 ----------------
__global__ __launch_bounds__(256) void im2col1b(const float* __restrict__ xm, short* __restrict__ A){
  size_t idx = (size_t)blockIdx.x * 256 + threadIdx.x; // 32000*128
  int col = idx & 127;
  size_t row = idx >> 7;
  int t1 = row % 1000, b = row / 1000;
  float v = 0.f;
  if(col < 112){
    int i = col / 7, k = col % 7;
    int src = 2*t1 + k - 3;
    if(src >= 0 && src < 2000) v = xm[((size_t)b*16 + i)*2000 + src];
  }
  A[idx] = f2b(v);
}

// ---------------- GroupNorm(1) stats: two-stage ----------------
__global__ __launch_bounds__(256) void gn_part(const float* __restrict__ h1, double* __restrict__ part){
  int blk = blockIdx.x;  // 256 = 32 b x 8 segs
  const float* p = h1 + (size_t)blk * 16000;
  int t = threadIdx.x;
  double s = 0, q = 0;
  for(int i = t; i < 16000; i += 256){ double v = p[i]; s += v; q += v*v; }
  __shared__ double rs[256], rq[256];
  rs[t] = s; rq[t] = q; __syncthreads();
  for(int s2 = 128; s2 > 0; s2 >>= 1){
    if(t < s2){ rs[t] += rs[t+s2]; rq[t] += rq[t+s2]; }
    __syncthreads();
  }
  if(t == 0){ part[blk*2] = rs[0]; part[blk*2+1] = rq[0]; }
}
__global__ __launch_bounds__(256) void gn_final(const double* __restrict__ part, float* __restrict__ stats){
  int t = threadIdx.x;     // 256 = 32 b x 8
  int b = t >> 3;
  double s = part[t*2], q = part[t*2+1];
  s += __shfl_xor(s, 1); q += __shfl_xor(q, 1);
  s += __shfl_xor(s, 2); q += __shfl_xor(q, 2);
  s += __shfl_xor(s, 4); q += __shfl_xor(q, 4);
  if((t & 7) == 0){
    double mean = s / 128000.0;
    double var  = q / 128000.0 - mean*mean;
    stats[b*2]   = (float)mean;
    stats[b*2+1] = (float)(1.0 / sqrt(var + 1e-5));
  }
}

// ---------------- im2col conv2 (fused GroupNorm) -> bf16 ----------------
__global__ __launch_bounds__(256) void im2col2b(const float* __restrict__ h1,
    const float* __restrict__ stats, const float* __restrict__ gg,
    const float* __restrict__ gb, short* __restrict__ A){
  size_t idx = (size_t)blockIdx.x * 256 + threadIdx.x; // 16000*896
  int col = idx % 896;
  size_t row = idx / 896;
  int t2 = row % 500, b = row / 500;
  int i = col / 7, k = col % 7;
  int src = 2*t2 + k - 3;
  float v = 0.f;
  if(src >= 0 && src < 1000){
    float raw = h1[((size_t)b*1000 + src)*128 + i];
    v = (raw - stats[b*2]) * stats[b*2+1] * gg[i] + gb[i];
  }
  A[idx] = f2b(v);
}

// ---------------- post-conv: LN(D) + sinpos + star table -> X (fp32) ----------------
__global__ __launch_bounds__(256) void postconv(const float* __restrict__ xp,
    const float* __restrict__ cg, const float* __restrict__ cb,
    const float* __restrict__ star, const float* __restrict__ stab,
    float* __restrict__ x){
  int row = blockIdx.x, t = threadIdx.x;
  int s = row % 500, b = row / 500;
  __shared__ float red[256];
  float v = xp[(size_t)row*256 + t];
  red[t] = v; __syncthreads();
  for(int s2 = 128; s2 > 0; s2 >>= 1){ if(t < s2) red[t] += red[t+s2]; __syncthreads(); }
  float mean = red[0] / 256.f; __syncthreads();
  float d = v - mean;
  red[t] = d*d; __syncthreads();
  for(int s2 = 128; s2 > 0; s2 >>= 1){ if(t < s2) red[t] += red[t+s2]; __syncthreads(); }
  float rstd = 1.f / sqrtf(red[0]/256.f + 1e-5f);
  int j = t & 127;
  double f = exp((double)j * LKC);
  double a = (double)s * f;
  float pe = (float)(t < 128 ? sin(a) : cos(a));
  int bucket = (int)(star[b] * 2.0f);
  bucket = bucket < 0 ? 0 : (bucket > 19 ? 19 : bucket);
  x[(size_t)row*256 + t] = d*rstd*cg[t] + cb[t] + pe + stab[bucket*256 + t];
}

// ---------------- event features -> combined bf16 (B*NEV, 768) ----------------
__global__ __launch_bounds__(256) void event_feat(const int* __restrict__ events, short* __restrict__ comb){
  int blk = blockIdx.x;           // 8192
  int e = blk & 255, b = blk >> 8;
  const int* ev = events + b*256;
  int t = threadIdx.x;
  auto gof = [&](int i){ int j = i < 1 ? 1 : i; int d = ev[j] - ev[j-1]; return d < 1 ? 1 : d; };
  int gi = gof(e);
  double rb = 1.0, ra = 1.0;
  if(e != 0){
    rb = (double)gi / (double)gof(e-1);
    rb = rb < 0.1 ? 0.1 : (rb > 10.0 ? 10.0 : rb);
  }
  if(e != 255){
    ra = (double)gof(e+1) / (double)gi;
    ra = ra < 0.1 ? 0.1 : (ra > 10.0 ? 10.0 : ra);
  }
  int rbi = (int)(rb * 50.0);
  int rai = (int)(ra * 50.0);
  int gap = 5 * gi;
  int j = t & 127;
  double f = exp((double)j * LKC);
  double a0 = (double)rbi * f, a1 = (double)rai * f, a2 = (double)gap * f;
  size_t base = (size_t)blk * 768;
  comb[base + t]       = f2b((float)(t < 128 ? sin(a0) : cos(a0)));
  comb[base + 256 + t] = f2b((float)(t < 128 ? sin(a1) : cos(a1)));
  comb[base + 512 + t] = f2b((float)(t < 128 ? sin(a2) : cos(a2)));
}

// ---------------- scatter-add events into X ----------------
__global__ __launch_bounds__(256) void ev_scatter(const float* __restrict__ evout,
    const int* __restrict__ events, const unsigned char* __restrict__ mask,
    float* __restrict__ x){
  int blk = blockIdx.x; // 8192
  int e = blk & 255, b = blk >> 8;
  if(mask[b*256 + e]) return;
  int tp = events[b*256 + e] >> 2;
  tp = tp < 0 ? 0 : (tp > 499 ? 499 : tp);
  int t = threadIdx.x;
  atomicAdd(&x[((size_t)b*500 + tp)*256 + t], evout[(size_t)blk*256 + t]);
}

// ---------------- LayerNorm rows of 256 -> bf16 (wave-shuffle reduce) ----------------
__global__ __launch_bounds__(256) void ln_rows(const float* __restrict__ x,
    const float* __restrict__ g, const float* __restrict__ b, short* __restrict__ out){
  int row = blockIdx.x, t = threadIdx.x;
  int wid = t >> 6, lane = t & 63;
  __shared__ float sm[8];
  float v = x[(size_t)row*256 + t];
  float s = v;
  #pragma unroll
  for(int o = 1; o < 64; o <<= 1) s += __shfl_xor(s, o);
  if(lane == 0) sm[wid] = s;
  __syncthreads();
  float mean = (sm[0] + sm[1] + sm[2] + sm[3]) * (1.f/256.f);
  float d = v - mean;
  float q = d*d;
  #pragma unroll
  for(int o = 1; o < 64; o <<= 1) q += __shfl_xor(q, o);
  if(lane == 0) sm[4 + wid] = q;
  __syncthreads();
  float rstd = 1.f / sqrtf((sm[4] + sm[5] + sm[6] + sm[7]) * (1.f/256.f) + 1e-5f);
  out[(size_t)row*256 + t] = f2b(d*rstd*g[t] + b[t]);
}

// ---------------- MFMA flash attention: qkv bf16 (B,S,768) -> o bf16 (B,S,256) ----------------
// grid 256 (XCD-swizzled b,h); 512 threads. Kl stride 40 (bank-balanced),
// Vt write rotation (conflict-free transpose writes).
__global__ __launch_bounds__(512) void attn_mfma(const short* __restrict__ qkv,
    short* __restrict__ o){
  __shared__ __align__(16) short Kl[512*40];     // 40 KB
  __shared__ __align__(16) short Vt[32*520];     // 33.3 KB
  __shared__ __align__(16) short Pl[8][640];     // per-wave P buffer, row stride 40 shorts
  const int i = blockIdx.x;
  // XCD swizzle: all 8 heads of a given b land on the same XCD (i%8).
  const int b = (i & 7)*4 + ((i >> 3) & 3);
  const int h = i >> 5;
  const int t = threadIdx.x;
  const int wid = t >> 6, lane = t & 63;
  const int lq = lane & 15, lg = lane >> 4;
  const short* base = qkv + (size_t)b * kS * 768;
  // ---- stage K (stride 40) + V transposed (rotation writes) ----
  {
    const int c = t & 3;
    for(int idx = t; idx < 2048; idx += 512){
      int row = idx >> 2;
      s16x8 kv = {0,0,0,0,0,0,0,0};
      unsigned vu0 = 0, vu1 = 0, vu2 = 0, vu3 = 0;
      if(row < kS){
        const short* rp = base + (size_t)row*768 + 256 + h*32 + c*8;
        kv = *(const s16x8*)rp;
        uint4 vv = *(const uint4*)(rp + 256);
        vu0 = vv.x; vu1 = vv.y; vu2 = vv.z; vu3 = vv.w;
      }
      *(s16x8*)&Kl[row*40 + c*8] = kv;
      // dword-rotate by c: rd[k] = ud[(k+c)&3]
      unsigned b0 = (c & 2) ? vu2 : vu0, b1 = (c & 2) ? vu3 : vu1;
      unsigned b2 = (c & 2) ? vu0 : vu2, b3 = (c & 2) ? vu1 : vu3;
      unsigned r0 = (c & 1) ? b1 : b0, r1 = (c & 1) ? b2 : b1;
      unsigned r2 = (c & 1) ? b3 : b2, r3 = (c & 1) ? b0 : b3;
      // element j0 of rotated = vv[(j0+2c)&7]; write d = c*8 + ((j0+2c)&7)
      #pragma unroll
      for(int j0 = 0; j0 < 8; ++j0){
        unsigned w = (j0 >> 1) == 0 ? r0 : (j0 >> 1) == 1 ? r1 : (j0 >> 1) == 2 ? r2 : r3;
        short val = (short)((j0 & 1) ? (w >> 16) : (w & 0xffff));
        int d = c*8 + ((j0 + 2*c) & 7);
        Vt[d*520 + row] = val;
      }
    }
  }
  __syncthreads();
  const float scale = 0.17677669529663687f; // 1/sqrt(32)
  short* pw = &Pl[wid][0];
  for(int qi = 0; qi < 4; ++qi){
    const int qt = wid*4 + qi;
    const int q0 = qt*16;
    int qrow = q0 + lq; if(qrow > kS-1) qrow = kS-1;
    s16x8 qf = *(const s16x8*)(base + (size_t)qrow*768 + h*32 + lg*8);
    f32x4 sc[32];
    __builtin_amdgcn_s_setprio(1);
    #pragma unroll
    for(int kt = 0; kt < 32; ++kt){
      s16x8 kf = *(const s16x8*)&Kl[(kt*16 + lq)*40 + lg*8];
      f32x4 z = {0.f,0.f,0.f,0.f};
      sc[kt] = __builtin_amdgcn_mfma_f32_16x16x32_bf16(kf, qf, z, 0, 0, 0);
    }
    __builtin_amdgcn_s_setprio(0);
    if(lg >= 1){ sc[31][0] = -1e30f; sc[31][1] = -1e30f; sc[31][2] = -1e30f; sc[31][3] = -1e30f; }
    float m = -1e30f;
    #pragma unroll
    for(int kt = 0; kt < 32; ++kt)
      m = fmaxf(m, fmaxf(fmaxf(sc[kt][0], sc[kt][1]), fmaxf(sc[kt][2], sc[kt][3])));
    m = fmaxf(m, __shfl_xor(m, 16, 64));
    m = fmaxf(m, __shfl_xor(m, 32, 64));
    float l = 0.f;
    #pragma unroll
    for(int kt = 0; kt < 32; ++kt){
      #pragma unroll
      for(int r = 0; r < 4; ++r){
        float p = expf((sc[kt][r] - m) * scale);
        sc[kt][r] = p;
        l += p;
      }
    }
    l += __shfl_xor(l, 16, 64);
    l += __shfl_xor(l, 32, 64);
    f32x4 oa0 = {0.f,0.f,0.f,0.f}, oa1 = {0.f,0.f,0.f,0.f};
    #pragma unroll
    for(int kt2 = 0; kt2 < 16; ++kt2){
      #pragma unroll
      for(int f = 0; f < 2; ++f){
        f32x4 p = sc[kt2*2 + f];
        uint2 pk;
        pk.x = (unsigned)(unsigned short)f2b(p[0]) | ((unsigned)(unsigned short)f2b(p[1]) << 16);
        pk.y = (unsigned)(unsigned short)f2b(p[2]) | ((unsigned)(unsigned short)f2b(p[3]) << 16);
        *(uint2*)&pw[lq*40 + f*16 + lg*4] = pk;
      }
      s16x8 pf = *(const s16x8*)&pw[lq*40 + lg*8];
      s16x8 v0 = *(const s16x8*)&Vt[lq*520 + kt2*32 + lg*8];
      s16x8 v1 = *(const s16x8*)&Vt[(16+lq)*520 + kt2*32 + lg*8];
      __builtin_amdgcn_s_setprio(1);
      oa0 = __builtin_amdgcn_mfma_f32_16x16x32_bf16(v0, pf, oa0, 0, 0, 0);
      oa1 = __builtin_amdgcn_mfma_f32_16x16x32_bf16(v1, pf, oa1, 0, 0, 0);
      __builtin_amdgcn_s_setprio(0);
    }
    float inv = 1.f / l;
    int qw = q0 + lq;
    if(qw < kS){
      short* op = o + ((size_t)(b*kS + qw))*256 + h*32;
      uint2 w0, w1;
      w0.x = (unsigned)(unsigned short)f2b(oa0[0]*inv) | ((unsigned)(unsigned short)f2b(oa0[1]*inv) << 16);
      w0.y = (unsigned)(unsigned short)f2b(oa0[2]*inv) | ((unsigned)(unsigned short)f2b(oa0[3]*inv) << 16);
      w1.x = (unsigned)(unsigned short)f2b(oa1[0]*inv) | ((unsigned)(unsigned short)f2b(oa1[1]*inv) << 16);
      w1.y = (unsigned)(unsigned short)f2b(oa1[2]*inv) | ((unsigned)(unsigned short)f2b(oa1[3]*inv) << 16);
      *(uint2*)&op[lg*4] = w0;
      *(uint2*)&op[16 + lg*4] = w1;
    }
  }
}

// ---------------- attention pooling + LN + head ----------------
__global__ __launch_bounds__(256) void pool_head(const float* __restrict__ x,
    const float* __restrict__ pq, const float* __restrict__ og, const float* __restrict__ ob,
    const float* __restrict__ ohW, const float* __restrict__ ohb, float* __restrict__ out){
  int b = blockIdx.x, t = threadIdx.x;
  __shared__ float lg[500];
  __shared__ float red[256];
  const float* xb = x + (size_t)b * 500 * 256;
  for(int s = t; s < 500; s += 256){
    const float* xr = xb + (size_t)s * 256;
    float d = 0.f;
    for(int c = 0; c < 256; ++c) d += xr[c] * pq[c];
    lg[s] = d * 0.0625f;
  }
  __syncthreads();
  float m = -1e30f;
  for(int s = t; s < 500; s += 256) m = fmaxf(m, lg[s]);
  red[t] = m; __syncthreads();
  for(int s2 = 128; s2 > 0; s2 >>= 1){ if(t < s2) red[t] = fmaxf(red[t], red[t+s2]); __syncthreads(); }
  m = red[0]; __syncthreads();
  float ps = 0.f;
  for(int s = t; s < 500; s += 256){ float e = expf(lg[s] - m); lg[s] = e; ps += e; }
  red[t] = ps; __syncthreads();
  for(int s2 = 128; s2 > 0; s2 >>= 1){ if(t < s2) red[t] += red[t+s2]; __syncthreads(); }
  float inv = 1.f / red[0];
  __syncthreads();
  float acc = 0.f;
  for(int s = 0; s < 500; ++s) acc += lg[s] * xb[(size_t)s*256 + t];
  acc *= inv;
  __syncthreads();
  red[t] = acc; __syncthreads();
  for(int s2 = 128; s2 > 0; s2 >>= 1){ if(t < s2) red[t] += red[t+s2]; __syncthreads(); }
  float mean = red[0] / 256.f; __syncthreads();
  float d = acc - mean;
  red[t] = d*d; __syncthreads();
  for(int s2 = 128; s2 > 0; s2 >>= 1){ if(t < s2) red[t] += red[t+s2]; __syncthreads(); }
  float rstd = 1.f / sqrtf(red[0]/256.f + 1e-5f);
  __syncthreads();
  float val = (d*rstd*og[t] + ob[t]) * ohW[t];
  red[t] = val; __syncthreads();
  for(int s2 = 128; s2 > 0; s2 >>= 1){ if(t < s2) red[t] += red[t+s2]; __syncthreads(); }
  if(t == 0) out[b] = red[0] + ohb[0];
}

extern "C" void kernel_launch(void* const* d_in, const int* in_sizes, int n_in,
                              void* d_out, int out_size, void* d_ws, size_t ws_size,
                              hipStream_t stream){
  const float* mel      = (const float*)d_in[0];
  const int*   events   = (const int*)d_in[1];
  const unsigned char* emask = (const unsigned char*)d_in[2];
  const float* star     = (const float*)d_in[3];
  const float* mel_W    = (const float*)d_in[4];
  const float* mel_b    = (const float*)d_in[5];
  const float* conv1_w  = (const float*)d_in[6];
  const float* conv1_b  = (const float*)d_in[7];
  const float* gn_g     = (const float*)d_in[8];
  const float* gn_b     = (const float*)d_in[9];
  const float* conv2_w  = (const float*)d_in[10];
  const float* conv2_b  = (const float*)d_in[11];
  const float* cn_g     = (const float*)d_in[12];
  const float* cn_b     = (const float*)d_in[13];
  const float* star_tab = (const float*)d_in[14];
  const float* ep_W1    = (const float*)d_in[15];
  const float* ep_b1    = (const float*)d_in[16];
  const float* ep_W2    = (const float*)d_in[17];
  const float* ep_b2    = (const float*)d_in[18];
  const float* tl_Wqkv  = (const float*)d_in[19];
  const float* tl_bqkv  = (const float*)d_in[20];
  const float* tl_Wo    = (const float*)d_in[21];
  const float* tl_bo    = (const float*)d_in[22];
  const float* tl_ln1g  = (const float*)d_in[23];
  const float* tl_ln1b  = (const float*)d_in[24];
  const float* tl_ln2g  = (const float*)d_in[25];
  const float* tl_ln2b  = (const float*)d_in[26];
  const float* tl_W1    = (const float*)d_in[27];
  const float* tl_b1    = (const float*)d_in[28];
  const float* tl_W2    = (const float*)d_in[29];
  const float* tl_b2    = (const float*)d_in[30];
  const float* pool_q   = (const float*)d_in[31];
  const float* on_g     = (const float*)d_in[32];
  const float* on_b     = (const float*)d_in[33];
  const float* oh_W     = (const float*)d_in[34];
  const float* oh_b     = (const float*)d_in[35];
  (void)in_sizes; (void)n_in; (void)out_size; (void)ws_size;

  float* ws  = (float*)d_ws;
  float* X   = ws;                        // fp32 (B,S,256)
  short* XNB = (short*)(ws + 4096000);    // bf16 (B,S,256)
  short* OB  = (short*)(ws + 6144000);    // bf16 attn out (B,S,256)
  short* WB  = (short*)(ws + 8192000);    // bf16 weights
  float* BIG = ws + 10812000;             // scratch
  double* PART = (double*)(ws + 28668000);
  float* STATS = ws + 28671900;

  // WB sub-offsets (shorts)
  short* WBc1 = WB + 0;         // 128x128
  short* WBc2 = WB + 16384;     // 256x896
  short* WBe1 = WB + 245760;    // 256x768
  short* WBe2 = WB + 442368;    // 256x256
  short* WBqk = WB + 507904;    // 6 x 768x256
  short* WBwo = WB + 1687552;   // 6 x 256x256
  short* WBw1 = WB + 2080768;   // 6 x 1024x256
  short* WBw2 = WB + 3653632;   // 6 x 256x1024

  // BIG sub-layouts
  float* XMEL = BIG;                       // (B,16,2000)
  short* A1B  = (short*)(BIG + 1024000);   // (32000,128) bf16
  float* H1   = BIG + 3072000;             // (B,1000,128)
  short* A2B  = (short*)(BIG + 7168000);   // (16000,896) bf16
  float* XPRE = BIG;                       // (B,S,256)
  short* COMBB= (short*)BIG;               // (8192,768) bf16
  short* EHIDB= (short*)(BIG + 3146000);   // (8192,256) bf16
  float* EVO  = BIG + 4195000;             // (8192,256) fp32
  short* QKVB = (short*)BIG;               // (16000,768) bf16
  short* HIDB = (short*)(BIG + 7168000);   // (16000,1024) bf16

  // ---- weight conversion ----
  conv1w_pad<<<128, 128, 0, stream>>>(conv1_w, WBc1);
  f2b_kernel<<<896, 256, 0, stream>>>(conv2_w, WBc2, 229376);
  f2b_kernel<<<768, 256, 0, stream>>>(ep_W1, WBe1, 196608);
  f2b_kernel<<<256, 256, 0, stream>>>(ep_W2, WBe2, 65536);
  f2b_kernel<<<4608, 256, 0, stream>>>(tl_Wqkv, WBqk, 1179648);
  f2b_kernel<<<1536, 256, 0, stream>>>(tl_Wo, WBwo, 393216);
  f2b_kernel<<<6144, 256, 0, stream>>>(tl_W1, WBw1, 1572864);
  f2b_kernel<<<6144, 256, 0, stream>>>(tl_W2, WBw2, 1572864);

  // ---- prologue ----
  mel_kernel<<<kB*8, 256, 0, stream>>>(mel, mel_W, mel_b, XMEL);
  im2col1b<<<16000, 256, 0, stream>>>(XMEL, A1B);
  gemm_mfma<0,true><<<dim3(1, 250), 256, 0, stream>>>(A1B, WBc1, conv1_b, H1, 32000, 128, 128);
  gn_part<<<256, 256, 0, stream>>>(H1, PART);
  gn_final<<<1, 256, 0, stream>>>(PART, STATS);
  im2col2b<<<56000, 256, 0, stream>>>(H1, STATS, gn_g, gn_b, A2B);
  gemm_mfma<0,true><<<dim3(2, 125), 256, 0, stream>>>(A2B, WBc2, conv2_b, XPRE, 16000, 256, 896);
  postconv<<<16000, 256, 0, stream>>>(XPRE, cn_g, cn_b, star, star_tab, X);
  // events
  event_feat<<<kB*256, 256, 0, stream>>>(events, COMBB);
  gemm_mfma<2,true><<<dim3(2, 64), 256, 0, stream>>>(COMBB, WBe1, ep_b1, EHIDB, 8192, 256, 768);
  gemm_mfma<0,false><<<dim3(2, 64), 256, 0, stream>>>(EHIDB, WBe2, ep_b2, EVO, 8192, 256, 256);
  ev_scatter<<<kB*256, 256, 0, stream>>>(EVO, events, emask, X);

  // ---- transformer layers ----
  ln_rows<<<16000, 256, 0, stream>>>(X, tl_ln1g, tl_ln1b, XNB);   // ln1[0]
  for(int i = 0; i < 6; ++i){
    gemm512<false><<<dim3(3, 250), 512, 0, stream>>>(XNB, WBqk + (size_t)i*196608, tl_bqkv + i*768, QKVB, 16000, 768, 256);
    attn_mfma<<<kB*kH, 512, 0, stream>>>(QKVB, OB);
    gemm_ln<true><<<dim3(1, 250), 512, 0, stream>>>(OB, WBwo + (size_t)i*65536, tl_bo + i*256,
        X, tl_ln2g + i*256, tl_ln2b + i*256, XNB, 16000, 256);
    gemm512<true><<<dim3(4, 250), 512, 0, stream>>>(XNB, WBw1 + (size_t)i*262144, tl_b1 + i*1024, HIDB, 16000, 1024, 256);
    if(i < 5)
      gemm_ln<true><<<dim3(1, 250), 512, 0, stream>>>(HIDB, WBw2 + (size_t)i*262144, tl_b2 + i*256,
          X, tl_ln1g + (i+1)*256, tl_ln1b + (i+1)*256, XNB, 16000, 1024);
    else
      gemm_ln<false><<<dim3(1, 250), 512, 0, stream>>>(HIDB, WBw2 + (size_t)i*262144, tl_b2 + i*256,
          X, tl_ln1g, tl_ln1b, XNB, 16000, 1024);
  }

  // ---- pooling + head ----
  pool_head<<<kB, 256, 0, stream>>>(X, pool_q, on_g, on_b, oh_W, oh_b, (float*)d_out);
}

// Round 7
// 870.767 us; speedup vs baseline: 19.4075x; 1.1426x over previous
//
#include <hip/hip_runtime.h>
#include <math.h>

namespace {
constexpr int kB = 32;
constexpr int kS = 500;
constexpr int kH = 8;
}
// -ln(10000)/127
#define LKC (-0.07252236513366287)

typedef __attribute__((ext_vector_type(8))) short s16x8;
typedef __attribute__((ext_vector_type(4))) float f32x4;

__device__ __forceinline__ float gelu_f(float x){
  return 0.5f * x * (1.0f + erff(x * 0.7071067811865476f));
}
__device__ __forceinline__ float b2f(short s){
  union { unsigned u; float f; } x; x.u = ((unsigned)(unsigned short)s) << 16; return x.f;
}
__device__ __forceinline__ short f2b(float f){
  unsigned u = __float_as_uint(f);
  unsigned r = (u + 0x7fffu + ((u >> 16) & 1u)) >> 16;
  return (short)r;
}
// packed 2xfp32 -> 2xbf16 (RNE), D.lo = S0
__device__ __forceinline__ unsigned cvtpk(float lo, float hi){
  unsigned r;
  asm("v_cvt_pk_bf16_f32 %0, %1, %2" : "=v"(r) : "v"(lo), "v"(hi));
  return r;
}

// ---------------- fp32 -> bf16 converter ----------------
__global__ __launch_bounds__(256) void f2b_kernel(const float* __restrict__ in,
    short* __restrict__ out, int n){
  int i = blockIdx.x * 256 + threadIdx.x;
  if(i < n) out[i] = f2b(in[i]);
}
// conv1 weight: (128,112) -> bf16 padded to (128,128)
__global__ __launch_bounds__(128) void conv1w_pad(const float* __restrict__ w, short* __restrict__ out){
  int n = blockIdx.x, k = threadIdx.x;
  out[n*128 + k] = (k < 112) ? f2b(w[n*112 + k]) : (short)0;
}

// ---------------- MFMA GEMM (256 thr, 128x128 tile): prologue/event GEMMs ----------------
template<int OUT, bool DOGELU>
__global__ __launch_bounds__(256) void gemm_mfma(const short* __restrict__ A,
    const short* __restrict__ W, const float* __restrict__ bias,
    void* __restrict__ Cv, int M, int N, int K){
  __shared__ __align__(16) short Al[128*64];
  __shared__ __align__(16) short Wl[128*64];
  const int t = threadIdx.x;
  const int wid = t >> 6, lane = t & 63;
  const int m0 = blockIdx.y * 128, n0 = blockIdx.x * 128;
  const int wr = (wid >> 1) * 64, wc = (wid & 1) * 64;
  const int frow = lane & 15, lg = lane >> 4;
  const int rA = t >> 3;
  const int sA = (t & 7) ^ (rA & 7);
  const short* Aq = A + (size_t)(m0 + rA) * K + sA * 8;
  const short* Wq = W + (size_t)(n0 + rA) * K + sA * 8;
  f32x4 acc[4][4] = {};
  for(int k0 = 0; k0 < K; k0 += 64){
    s16x8 av[4], wv[4];
    #pragma unroll
    for(int j = 0; j < 4; ++j){
      av[j] = *(const s16x8*)(Aq + k0 + (size_t)(32*j)*K);
      wv[j] = *(const s16x8*)(Wq + k0 + (size_t)(32*j)*K);
    }
    __syncthreads();
    #pragma unroll
    for(int j = 0; j < 4; ++j){
      *(s16x8*)&Al[t*8 + j*2048] = av[j];
      *(s16x8*)&Wl[t*8 + j*2048] = wv[j];
    }
    __syncthreads();
    #pragma unroll
    for(int kh = 0; kh < 2; ++kh){
      s16x8 a[4], b[4];
      #pragma unroll
      for(int mi = 0; mi < 4; ++mi){
        int r = wr + mi*16 + frow;
        a[mi] = *(const s16x8*)&Al[r*64 + (((kh*4 + lg) ^ (r & 7)) * 8)];
      }
      #pragma unroll
      for(int ni = 0; ni < 4; ++ni){
        int r = wc + ni*16 + frow;
        b[ni] = *(const s16x8*)&Wl[r*64 + (((kh*4 + lg) ^ (r & 7)) * 8)];
      }
      #pragma unroll
      for(int mi = 0; mi < 4; ++mi)
        #pragma unroll
        for(int ni = 0; ni < 4; ++ni)
          acc[mi][ni] = __builtin_amdgcn_mfma_f32_16x16x32_bf16(a[mi], b[ni], acc[mi][ni], 0, 0, 0);
    }
  }
  #pragma unroll
  for(int mi = 0; mi < 4; ++mi){
    #pragma unroll
    for(int ni = 0; ni < 4; ++ni){
      const int col = n0 + wc + ni*16 + (lane & 15);
      const float bv = bias[col];
      #pragma unroll
      for(int r = 0; r < 4; ++r){
        const int row = m0 + wr + mi*16 + (lane >> 4)*4 + r;
        float v = acc[mi][ni][r] + bv;
        if(DOGELU) v = gelu_f(v);
        if(OUT == 0) ((float*)Cv)[(size_t)row*N + col] = v;
        else if(OUT == 1) ((float*)Cv)[(size_t)row*N + col] += v;
        else ((short*)Cv)[(size_t)row*N + col] = f2b(v);
      }
    }
  }
}

// ---------------- gemm512: 128Mx256N tile, 512 threads (8 waves of 64x64), BK=64 ----------------
template<bool DOGELU>
__global__ __launch_bounds__(512) void gemm512(const short* __restrict__ A,
    const short* __restrict__ W, const float* __restrict__ bias,
    short* __restrict__ C, int M, int N, int K){
  __shared__ __align__(16) short Al[128*64];
  __shared__ __align__(16) short Wl[256*64];
  const int t = threadIdx.x;
  const int wid = t >> 6, lane = t & 63;
  const int m0 = blockIdx.y * 128, n0 = blockIdx.x * 256;
  const int wm = wid >> 2, wn = wid & 3;
  const int frow = lane & 15, lg = lane >> 4;
  const int rA = t >> 3;
  const int sA = (t & 7) ^ (rA & 7);
  const short* Aq = A + (size_t)(m0 + rA) * K + sA * 8;
  const short* Wq = W + (size_t)(n0 + rA) * K + sA * 8;
  f32x4 acc[4][4] = {};
  for(int k0 = 0; k0 < K; k0 += 64){
    s16x8 av[2], wv[4];
    av[0] = *(const s16x8*)(Aq + k0);
    av[1] = *(const s16x8*)(Aq + k0 + (size_t)64*K);
    #pragma unroll
    for(int j = 0; j < 4; ++j)
      wv[j] = *(const s16x8*)(Wq + k0 + (size_t)(64*j)*K);
    __syncthreads();
    *(s16x8*)&Al[t*8] = av[0];
    *(s16x8*)&Al[t*8 + 4096] = av[1];
    #pragma unroll
    for(int j = 0; j < 4; ++j)
      *(s16x8*)&Wl[t*8 + j*4096] = wv[j];
    __syncthreads();
    #pragma unroll
    for(int kh = 0; kh < 2; ++kh){
      s16x8 a[4], b[4];
      #pragma unroll
      for(int mi = 0; mi < 4; ++mi){
        int r = wm*64 + mi*16 + frow;
        a[mi] = *(const s16x8*)&Al[r*64 + (((kh*4 + lg) ^ (r & 7)) * 8)];
      }
      #pragma unroll
      for(int ni = 0; ni < 4; ++ni){
        int r = wn*64 + ni*16 + frow;
        b[ni] = *(const s16x8*)&Wl[r*64 + (((kh*4 + lg) ^ (r & 7)) * 8)];
      }
      #pragma unroll
      for(int mi = 0; mi < 4; ++mi)
        #pragma unroll
        for(int ni = 0; ni < 4; ++ni)
          acc[mi][ni] = __builtin_amdgcn_mfma_f32_16x16x32_bf16(a[mi], b[ni], acc[mi][ni], 0, 0, 0);
    }
  }
  #pragma unroll
  for(int mi = 0; mi < 4; ++mi){
    #pragma unroll
    for(int ni = 0; ni < 4; ++ni){
      const int col = n0 + wn*64 + ni*16 + (lane & 15);
      const float bv = bias[col];
      #pragma unroll
      for(int r = 0; r < 4; ++r){
        const int row = m0 + wm*64 + mi*16 + (lane >> 4)*4 + r;
        float v = acc[mi][ni][r] + bv;
        if(DOGELU) v = gelu_f(v);
        C[(size_t)row*N + col] = f2b(v);
      }
    }
  }
}

// ---------------- gemm_ln: 64Mx256N, N==256: X += A@W^T+bias; optional row-LN -> XNB ----------------
template<bool DOLN>
__global__ __launch_bounds__(512) void gemm_ln(const short* __restrict__ A,
    const short* __restrict__ W, const float* __restrict__ bias,
    float* __restrict__ X, const float* __restrict__ lg_, const float* __restrict__ lb_,
    short* __restrict__ XNB, int M, int K){
  __shared__ __align__(16) short Al[64*64];
  __shared__ __align__(16) short Wl[256*64];
  __shared__ float sbuf[64][4];
  const int t = threadIdx.x;
  const int wid = t >> 6, lane = t & 63;
  const int m0 = blockIdx.y * 64;
  const int wm = wid >> 2, wn = wid & 3;
  const int frow = lane & 15, lg = lane >> 4;
  const int lq = lane & 15;
  const int rA = t >> 3;
  const int sA = (t & 7) ^ (rA & 7);
  const short* Aq = A + (size_t)(m0 + rA) * K + sA * 8;
  const short* Wq = W + (size_t)rA * K + sA * 8;
  f32x4 acc[2][4] = {};
  for(int k0 = 0; k0 < K; k0 += 64){
    s16x8 av = *(const s16x8*)(Aq + k0);
    s16x8 wv[4];
    #pragma unroll
    for(int j = 0; j < 4; ++j)
      wv[j] = *(const s16x8*)(Wq + k0 + (size_t)(64*j)*K);
    __syncthreads();
    *(s16x8*)&Al[t*8] = av;
    #pragma unroll
    for(int j = 0; j < 4; ++j)
      *(s16x8*)&Wl[t*8 + j*4096] = wv[j];
    __syncthreads();
    #pragma unroll
    for(int kh = 0; kh < 2; ++kh){
      s16x8 a[2], b[4];
      #pragma unroll
      for(int mi = 0; mi < 2; ++mi){
        int r = wm*32 + mi*16 + frow;
        a[mi] = *(const s16x8*)&Al[r*64 + (((kh*4 + lg) ^ (r & 7)) * 8)];
      }
      #pragma unroll
      for(int ni = 0; ni < 4; ++ni){
        int r = wn*64 + ni*16 + frow;
        b[ni] = *(const s16x8*)&Wl[r*64 + (((kh*4 + lg) ^ (r & 7)) * 8)];
      }
      #pragma unroll
      for(int mi = 0; mi < 2; ++mi)
        #pragma unroll
        for(int ni = 0; ni < 4; ++ni)
          acc[mi][ni] = __builtin_amdgcn_mfma_f32_16x16x32_bf16(a[mi], b[ni], acc[mi][ni], 0, 0, 0);
    }
  }
  // v = acc + bias + residual
  float v[2][4][4];
  #pragma unroll
  for(int mi = 0; mi < 2; ++mi)
    #pragma unroll
    for(int ni = 0; ni < 4; ++ni){
      const int col = wn*64 + ni*16 + lq;
      const float bv = bias[col];
      #pragma unroll
      for(int r = 0; r < 4; ++r){
        const int row = m0 + wm*32 + mi*16 + lg*4 + r;
        v[mi][ni][r] = acc[mi][ni][r] + bv + X[(size_t)row*256 + col];
      }
    }
  __syncthreads();
  float vmean[2][4], vrstd[2][4];
  if(DOLN){
    #pragma unroll
    for(int mi = 0; mi < 2; ++mi)
      #pragma unroll
      for(int r = 0; r < 4; ++r){
        float s = v[mi][0][r] + v[mi][1][r] + v[mi][2][r] + v[mi][3][r];
        s += __shfl_xor(s, 1); s += __shfl_xor(s, 2);
        s += __shfl_xor(s, 4); s += __shfl_xor(s, 8);
        if(lq == 0) sbuf[wm*32 + mi*16 + lg*4 + r][wn] = s;
      }
    __syncthreads();
    #pragma unroll
    for(int mi = 0; mi < 2; ++mi)
      #pragma unroll
      for(int r = 0; r < 4; ++r){
        int rl = wm*32 + mi*16 + lg*4 + r;
        vmean[mi][r] = (sbuf[rl][0] + sbuf[rl][1] + sbuf[rl][2] + sbuf[rl][3]) * (1.f/256.f);
      }
    __syncthreads();
    #pragma unroll
    for(int mi = 0; mi < 2; ++mi)
      #pragma unroll
      for(int r = 0; r < 4; ++r){
        float q = 0.f;
        #pragma unroll
        for(int ni = 0; ni < 4; ++ni){ float d = v[mi][ni][r] - vmean[mi][r]; q += d*d; }
        q += __shfl_xor(q, 1); q += __shfl_xor(q, 2);
        q += __shfl_xor(q, 4); q += __shfl_xor(q, 8);
        if(lq == 0) sbuf[wm*32 + mi*16 + lg*4 + r][wn] = q;
      }
    __syncthreads();
    #pragma unroll
    for(int mi = 0; mi < 2; ++mi)
      #pragma unroll
      for(int r = 0; r < 4; ++r){
        int rl = wm*32 + mi*16 + lg*4 + r;
        float Q = sbuf[rl][0] + sbuf[rl][1] + sbuf[rl][2] + sbuf[rl][3];
        vrstd[mi][r] = 1.f / sqrtf(Q * (1.f/256.f) + 1e-5f);
      }
  }
  #pragma unroll
  for(int mi = 0; mi < 2; ++mi)
    #pragma unroll
    for(int ni = 0; ni < 4; ++ni){
      const int col = wn*64 + ni*16 + lq;
      float gg = 0.f, bb = 0.f;
      if(DOLN){ gg = lg_[col]; bb = lb_[col]; }
      #pragma unroll
      for(int r = 0; r < 4; ++r){
        const int row = m0 + wm*32 + mi*16 + lg*4 + r;
        float val = v[mi][ni][r];
        X[(size_t)row*256 + col] = val;
        if(DOLN)
          XNB[(size_t)row*256 + col] = f2b((val - vmean[mi][r]) * vrstd[mi][r] * gg + bb);
      }
    }
}

// ---------------- mel compress: (B,80,2000) -> (B,16,2000) ----------------
__global__ __launch_bounds__(256) void mel_kernel(const float* __restrict__ mel,
    const float* __restrict__ W, const float* __restrict__ bias, float* __restrict__ xm){
  __shared__ float Ws[16][80];
  __shared__ float bs[16];
  const int t = threadIdx.x;
  for(int i = t; i < 16*80; i += 256) Ws[i/80][i%80] = W[i];
  if(t < 16) bs[t] = bias[t];
  __syncthreads();
  int blk = blockIdx.x;
  int b = blk >> 3;
  int tc = (blk & 7) * 256 + t;
  if(tc >= 2000) return;
  float acc[16];
  #pragma unroll
  for(int o = 0; o < 16; ++o) acc[o] = bs[o];
  for(int c = 0; c < 80; ++c){
    float v = mel[((size_t)b*80 + c)*2000 + tc];
    #pragma unroll
    for(int o = 0; o < 16; ++o) acc[o] += v * Ws[o][c];
  }
  #pragma unroll
  for(int o = 0; o < 16; ++o) xm[((size_t)b*16 + o)*2000 + tc] = acc[o];
}

// ---------------- im2col conv1 -> bf16, K padded to 128 ----------------
__global__ __launch_bounds__(256) void im2col1b(const float* __restrict__ xm, short* __restrict__ A){
  size_t idx = (size_t)blockIdx.x * 256 + threadIdx.x; // 32000*128
  int col = idx & 127;
  size_t row = idx >> 7;
  int t1 = row % 1000, b = row / 1000;
  float v = 0.f;
  if(col < 112){
    int i = col / 7, k = col % 7;
    int src = 2*t1 + k - 3;
    if(src >= 0 && src < 2000) v = xm[((size_t)b*16 + i)*2000 + src];
  }
  A[idx] = f2b(v);
}

// ---------------- GroupNorm(1) stats: two-stage ----------------
__global__ __launch_bounds__(256) void gn_part(const float* __restrict__ h1, double* __restrict__ part){
  int blk = blockIdx.x;  // 256 = 32 b x 8 segs
  const float* p = h1 + (size_t)blk * 16000;
  int t = threadIdx.x;
  double s = 0, q = 0;
  for(int i = t; i < 16000; i += 256){ double v = p[i]; s += v; q += v*v; }
  __shared__ double rs[256], rq[256];
  rs[t] = s; rq[t] = q; __syncthreads();
  for(int s2 = 128; s2 > 0; s2 >>= 1){
    if(t < s2){ rs[t] += rs[t+s2]; rq[t] += rq[t+s2]; }
    __syncthreads();
  }
  if(t == 0){ part[blk*2] = rs[0]; part[blk*2+1] = rq[0]; }
}
__global__ __launch_bounds__(256) void gn_final(const double* __restrict__ part, float* __restrict__ stats){
  int t = threadIdx.x;     // 256 = 32 b x 8
  int b = t >> 3;
  double s = part[t*2], q = part[t*2+1];
  s += __shfl_xor(s, 1); q += __shfl_xor(q, 1);
  s += __shfl_xor(s, 2); q += __shfl_xor(q, 2);
  s += __shfl_xor(s, 4); q += __shfl_xor(q, 4);
  if((t & 7) == 0){
    double mean = s / 128000.0;
    double var  = q / 128000.0 - mean*mean;
    stats[b*2]   = (float)mean;
    stats[b*2+1] = (float)(1.0 / sqrt(var + 1e-5));
  }
}

// ---------------- im2col conv2 (fused GroupNorm) -> bf16 ----------------
__global__ __launch_bounds__(256) void im2col2b(const float* __restrict__ h1,
    const float* __restrict__ stats, const float* __restrict__ gg,
    const float* __restrict__ gb, short* __restrict__ A){
  size_t idx = (size_t)blockIdx.x * 256 + threadIdx.x; // 16000*896
  int col = idx % 896;
  size_t row = idx / 896;
  int t2 = row % 500, b = row / 500;
  int i = col / 7, k = col % 7;
  int src = 2*t2 + k - 3;
  float v = 0.f;
  if(src >= 0 && src < 1000){
    float raw = h1[((size_t)b*1000 + src)*128 + i];
    v = (raw - stats[b*2]) * stats[b*2+1] * gg[i] + gb[i];
  }
  A[idx] = f2b(v);
}

// ---------------- post-conv: LN(D) + sinpos + star table -> X (fp32) ----------------
__global__ __launch_bounds__(256) void postconv(const float* __restrict__ xp,
    const float* __restrict__ cg, const float* __restrict__ cb,
    const float* __restrict__ star, const float* __restrict__ stab,
    float* __restrict__ x){
  int row = blockIdx.x, t = threadIdx.x;
  int s = row % 500, b = row / 500;
  __shared__ float red[256];
  float v = xp[(size_t)row*256 + t];
  red[t] = v; __syncthreads();
  for(int s2 = 128; s2 > 0; s2 >>= 1){ if(t < s2) red[t] += red[t+s2]; __syncthreads(); }
  float mean = red[0] / 256.f; __syncthreads();
  float d = v - mean;
  red[t] = d*d; __syncthreads();
  for(int s2 = 128; s2 > 0; s2 >>= 1){ if(t < s2) red[t] += red[t+s2]; __syncthreads(); }
  float rstd = 1.f / sqrtf(red[0]/256.f + 1e-5f);
  int j = t & 127;
  double f = exp((double)j * LKC);
  double a = (double)s * f;
  float pe = (float)(t < 128 ? sin(a) : cos(a));
  int bucket = (int)(star[b] * 2.0f);
  bucket = bucket < 0 ? 0 : (bucket > 19 ? 19 : bucket);
  x[(size_t)row*256 + t] = d*rstd*cg[t] + cb[t] + pe + stab[bucket*256 + t];
}

// ---------------- event features -> combined bf16 (B*NEV, 768) ----------------
__global__ __launch_bounds__(256) void event_feat(const int* __restrict__ events, short* __restrict__ comb){
  int blk = blockIdx.x;           // 8192
  int e = blk & 255, b = blk >> 8;
  const int* ev = events + b*256;
  int t = threadIdx.x;
  auto gof = [&](int i){ int j = i < 1 ? 1 : i; int d = ev[j] - ev[j-1]; return d < 1 ? 1 : d; };
  int gi = gof(e);
  double rb = 1.0, ra = 1.0;
  if(e != 0){
    rb = (double)gi / (double)gof(e-1);
    rb = rb < 0.1 ? 0.1 : (rb > 10.0 ? 10.0 : rb);
  }
  if(e != 255){
    ra = (double)gof(e+1) / (double)gi;
    ra = ra < 0.1 ? 0.1 : (ra > 10.0 ? 10.0 : ra);
  }
  int rbi = (int)(rb * 50.0);
  int rai = (int)(ra * 50.0);
  int gap = 5 * gi;
  int j = t & 127;
  double f = exp((double)j * LKC);
  double a0 = (double)rbi * f, a1 = (double)rai * f, a2 = (double)gap * f;
  size_t base = (size_t)blk * 768;
  comb[base + t]       = f2b((float)(t < 128 ? sin(a0) : cos(a0)));
  comb[base + 256 + t] = f2b((float)(t < 128 ? sin(a1) : cos(a1)));
  comb[base + 512 + t] = f2b((float)(t < 128 ? sin(a2) : cos(a2)));
}

// ---------------- scatter-add events into X ----------------
__global__ __launch_bounds__(256) void ev_scatter(const float* __restrict__ evout,
    const int* __restrict__ events, const unsigned char* __restrict__ mask,
    float* __restrict__ x){
  int blk = blockIdx.x; // 8192
  int e = blk & 255, b = blk >> 8;
  if(mask[b*256 + e]) return;
  int tp = events[b*256 + e] >> 2;
  tp = tp < 0 ? 0 : (tp > 499 ? 499 : tp);
  int t = threadIdx.x;
  atomicAdd(&x[((size_t)b*500 + tp)*256 + t], evout[(size_t)blk*256 + t]);
}

// ---------------- LayerNorm rows of 256 -> bf16 (wave-shuffle reduce) ----------------
__global__ __launch_bounds__(256) void ln_rows(const float* __restrict__ x,
    const float* __restrict__ g, const float* __restrict__ b, short* __restrict__ out){
  int row = blockIdx.x, t = threadIdx.x;
  int wid = t >> 6, lane = t & 63;
  __shared__ float sm[8];
  float v = x[(size_t)row*256 + t];
  float s = v;
  #pragma unroll
  for(int o = 1; o < 64; o <<= 1) s += __shfl_xor(s, o);
  if(lane == 0) sm[wid] = s;
  __syncthreads();
  float mean = (sm[0] + sm[1] + sm[2] + sm[3]) * (1.f/256.f);
  float d = v - mean;
  float q = d*d;
  #pragma unroll
  for(int o = 1; o < 64; o <<= 1) q += __shfl_xor(q, o);
  if(lane == 0) sm[4 + wid] = q;
  __syncthreads();
  float rstd = 1.f / sqrtf((sm[4] + sm[5] + sm[6] + sm[7]) * (1.f/256.f) + 1e-5f);
  out[(size_t)row*256 + t] = f2b(d*rstd*g[t] + b[t]);
}

// ---------------- MFMA flash attention: qkv bf16 (B,S,768) -> o bf16 (B,S,256) ----------------
// grid 256 (XCD-swizzled b,h); 512 threads. No-max softmax (exp2), cvt_pk packing.
__global__ __launch_bounds__(512) void attn_mfma(const short* __restrict__ qkv,
    short* __restrict__ o){
  __shared__ __align__(16) short Kl[512*40];     // 40 KB
  __shared__ __align__(16) short Vt[32*520];     // 33.3 KB
  __shared__ __align__(16) short Pl[8][640];     // per-wave P buffer, row stride 40 shorts
  const int i = blockIdx.x;
  const int b = (i & 7)*4 + ((i >> 3) & 3);
  const int h = i >> 5;
  const int t = threadIdx.x;
  const int wid = t >> 6, lane = t & 63;
  const int lq = lane & 15, lg = lane >> 4;
  const short* base = qkv + (size_t)b * kS * 768;
  // ---- stage K (stride 40) + V transposed (rotation writes) ----
  {
    const int c = t & 3;
    for(int idx = t; idx < 2048; idx += 512){
      int row = idx >> 2;
      s16x8 kv = {0,0,0,0,0,0,0,0};
      unsigned vu0 = 0, vu1 = 0, vu2 = 0, vu3 = 0;
      if(row < kS){
        const short* rp = base + (size_t)row*768 + 256 + h*32 + c*8;
        kv = *(const s16x8*)rp;
        uint4 vv = *(const uint4*)(rp + 256);
        vu0 = vv.x; vu1 = vv.y; vu2 = vv.z; vu3 = vv.w;
      }
      *(s16x8*)&Kl[row*40 + c*8] = kv;
      unsigned b0 = (c & 2) ? vu2 : vu0, b1 = (c & 2) ? vu3 : vu1;
      unsigned b2 = (c & 2) ? vu0 : vu2, b3 = (c & 2) ? vu1 : vu3;
      unsigned r0 = (c & 1) ? b1 : b0, r1 = (c & 1) ? b2 : b1;
      unsigned r2 = (c & 1) ? b3 : b2, r3 = (c & 1) ? b0 : b3;
      #pragma unroll
      for(int j0 = 0; j0 < 8; ++j0){
        unsigned w = (j0 >> 1) == 0 ? r0 : (j0 >> 1) == 1 ? r1 : (j0 >> 1) == 2 ? r2 : r3;
        short val = (short)((j0 & 1) ? (w >> 16) : (w & 0xffff));
        int d = c*8 + ((j0 + 2*c) & 7);
        Vt[d*520 + row] = val;
      }
    }
  }
  __syncthreads();
  // exp2 constant: softmax scale (1/sqrt(32)) * log2(e)
  const float c2 = 0.17677669529663687f * 1.4426950408889634f;
  short* pw = &Pl[wid][0];
  for(int qi = 0; qi < 4; ++qi){
    const int qt = wid*4 + qi;
    const int q0 = qt*16;
    int qrow = q0 + lq; if(qrow > kS-1) qrow = kS-1;
    s16x8 qf = *(const s16x8*)(base + (size_t)qrow*768 + h*32 + lg*8);
    f32x4 sc[32];
    __builtin_amdgcn_s_setprio(1);
    #pragma unroll
    for(int kt = 0; kt < 32; ++kt){
      s16x8 kf = *(const s16x8*)&Kl[(kt*16 + lq)*40 + lg*8];
      f32x4 z = {0.f,0.f,0.f,0.f};
      sc[kt] = __builtin_amdgcn_mfma_f32_16x16x32_bf16(kf, qf, z, 0, 0, 0);
    }
    __builtin_amdgcn_s_setprio(0);
    if(lg >= 1){ sc[31][0] = -1e30f; sc[31][1] = -1e30f; sc[31][2] = -1e30f; sc[31][3] = -1e30f; }
    // ---- softmax without max-subtract: p = 2^(s*c2); scores are O(1) bounded ----
    float l0 = 0.f, l1 = 0.f, l2 = 0.f, l3 = 0.f;
    #pragma unroll
    for(int kt = 0; kt < 32; ++kt){
      float p0 = exp2f(sc[kt][0] * c2);
      float p1 = exp2f(sc[kt][1] * c2);
      float p2 = exp2f(sc[kt][2] * c2);
      float p3 = exp2f(sc[kt][3] * c2);
      sc[kt][0] = p0; sc[kt][1] = p1; sc[kt][2] = p2; sc[kt][3] = p3;
      l0 += p0; l1 += p1; l2 += p2; l3 += p3;
    }
    float l = (l0 + l1) + (l2 + l3);
    l += __shfl_xor(l, 16, 64);
    l += __shfl_xor(l, 32, 64);
    f32x4 oa0 = {0.f,0.f,0.f,0.f}, oa1 = {0.f,0.f,0.f,0.f};
    #pragma unroll
    for(int kt2 = 0; kt2 < 16; ++kt2){
      f32x4 p0 = sc[kt2*2], p1 = sc[kt2*2+1];
      uint2 pk0, pk1;
      pk0.x = cvtpk(p0[0], p0[1]); pk0.y = cvtpk(p0[2], p0[3]);
      pk1.x = cvtpk(p1[0], p1[1]); pk1.y = cvtpk(p1[2], p1[3]);
      *(uint2*)&pw[lq*40 + lg*4] = pk0;
      *(uint2*)&pw[lq*40 + 16 + lg*4] = pk1;
      s16x8 pf = *(const s16x8*)&pw[lq*40 + lg*8];
      s16x8 v0 = *(const s16x8*)&Vt[lq*520 + kt2*32 + lg*8];
      s16x8 v1 = *(const s16x8*)&Vt[(16+lq)*520 + kt2*32 + lg*8];
      __builtin_amdgcn_s_setprio(1);
      oa0 = __builtin_amdgcn_mfma_f32_16x16x32_bf16(v0, pf, oa0, 0, 0, 0);
      oa1 = __builtin_amdgcn_mfma_f32_16x16x32_bf16(v1, pf, oa1, 0, 0, 0);
      __builtin_amdgcn_s_setprio(0);
    }
    float inv = 1.f / l;
    int qw = q0 + lq;
    if(qw < kS){
      short* op = o + ((size_t)(b*kS + qw))*256 + h*32;
      uint2 w0, w1;
      w0.x = cvtpk(oa0[0]*inv, oa0[1]*inv); w0.y = cvtpk(oa0[2]*inv, oa0[3]*inv);
      w1.x = cvtpk(oa1[0]*inv, oa1[1]*inv); w1.y = cvtpk(oa1[2]*inv, oa1[3]*inv);
      *(uint2*)&op[lg*4] = w0;
      *(uint2*)&op[16 + lg*4] = w1;
    }
  }
}

// ---------------- attention pooling + LN + head ----------------
__global__ __launch_bounds__(256) void pool_head(const float* __restrict__ x,
    const float* __restrict__ pq, const float* __restrict__ og, const float* __restrict__ ob,
    const float* __restrict__ ohW, const float* __restrict__ ohb, float* __restrict__ out){
  int b = blockIdx.x, t = threadIdx.x;
  __shared__ float lg[500];
  __shared__ float red[256];
  const float* xb = x + (size_t)b * 500 * 256;
  for(int s = t; s < 500; s += 256){
    const float* xr = xb + (size_t)s * 256;
    float d = 0.f;
    for(int c = 0; c < 256; ++c) d += xr[c] * pq[c];
    lg[s] = d * 0.0625f;
  }
  __syncthreads();
  float m = -1e30f;
  for(int s = t; s < 500; s += 256) m = fmaxf(m, lg[s]);
  red[t] = m; __syncthreads();
  for(int s2 = 128; s2 > 0; s2 >>= 1){ if(t < s2) red[t] = fmaxf(red[t], red[t+s2]); __syncthreads(); }
  m = red[0]; __syncthreads();
  float ps = 0.f;
  for(int s = t; s < 500; s += 256){ float e = expf(lg[s] - m); lg[s] = e; ps += e; }
  red[t] = ps; __syncthreads();
  for(int s2 = 128; s2 > 0; s2 >>= 1){ if(t < s2) red[t] += red[t+s2]; __syncthreads(); }
  float inv = 1.f / red[0];
  __syncthreads();
  float acc = 0.f;
  for(int s = 0; s < 500; ++s) acc += lg[s] * xb[(size_t)s*256 + t];
  acc *= inv;
  __syncthreads();
  red[t] = acc; __syncthreads();
  for(int s2 = 128; s2 > 0; s2 >>= 1){ if(t < s2) red[t] += red[t+s2]; __syncthreads(); }
  float mean = red[0] / 256.f; __syncthreads();
  float d = acc - mean;
  red[t] = d*d; __syncthreads();
  for(int s2 = 128; s2 > 0; s2 >>= 1){ if(t < s2) red[t] += red[t+s2]; __syncthreads(); }
  float rstd = 1.f / sqrtf(red[0]/256.f + 1e-5f);
  __syncthreads();
  float val = (d*rstd*og[t] + ob[t]) * ohW[t];
  red[t] = val; __syncthreads();
  for(int s2 = 128; s2 > 0; s2 >>= 1){ if(t < s2) red[t] += red[t+s2]; __syncthreads(); }
  if(t == 0) out[b] = red[0] + ohb[0];
}

extern "C" void kernel_launch(void* const* d_in, const int* in_sizes, int n_in,
                              void* d_out, int out_size, void* d_ws, size_t ws_size,
                              hipStream_t stream){
  const float* mel      = (const float*)d_in[0];
  const int*   events   = (const int*)d_in[1];
  const unsigned char* emask = (const unsigned char*)d_in[2];
  const float* star     = (const float*)d_in[3];
  const float* mel_W    = (const float*)d_in[4];
  const float* mel_b    = (const float*)d_in[5];
  const float* conv1_w  = (const float*)d_in[6];
  const float* conv1_b  = (const float*)d_in[7];
  const float* gn_g     = (const float*)d_in[8];
  const float* gn_b     = (const float*)d_in[9];
  const float* conv2_w  = (const float*)d_in[10];
  const float* conv2_b  = (const float*)d_in[11];
  const float* cn_g     = (const float*)d_in[12];
  const float* cn_b     = (const float*)d_in[13];
  const float* star_tab = (const float*)d_in[14];
  const float* ep_W1    = (const float*)d_in[15];
  const float* ep_b1    = (const float*)d_in[16];
  const float* ep_W2    = (const float*)d_in[17];
  const float* ep_b2    = (const float*)d_in[18];
  const float* tl_Wqkv  = (const float*)d_in[19];
  const float* tl_bqkv  = (const float*)d_in[20];
  const float* tl_Wo    = (const float*)d_in[21];
  const float* tl_bo    = (const float*)d_in[22];
  const float* tl_ln1g  = (const float*)d_in[23];
  const float* tl_ln1b  = (const float*)d_in[24];
  const float* tl_ln2g  = (const float*)d_in[25];
  const float* tl_ln2b  = (const float*)d_in[26];
  const float* tl_W1    = (const float*)d_in[27];
  const float* tl_b1    = (const float*)d_in[28];
  const float* tl_W2    = (const float*)d_in[29];
  const float* tl_b2    = (const float*)d_in[30];
  const float* pool_q   = (const float*)d_in[31];
  const float* on_g     = (const float*)d_in[32];
  const float* on_b     = (const float*)d_in[33];
  const float* oh_W     = (const float*)d_in[34];
  const float* oh_b     = (const float*)d_in[35];
  (void)in_sizes; (void)n_in; (void)out_size; (void)ws_size;

  float* ws  = (float*)d_ws;
  float* X   = ws;                        // fp32 (B,S,256)
  short* XNB = (short*)(ws + 4096000);    // bf16 (B,S,256)
  short* OB  = (short*)(ws + 6144000);    // bf16 attn out (B,S,256)
  short* WB  = (short*)(ws + 8192000);    // bf16 weights
  float* BIG = ws + 10812000;             // scratch
  double* PART = (double*)(ws + 28668000);
  float* STATS = ws + 28671900;

  // WB sub-offsets (shorts)
  short* WBc1 = WB + 0;         // 128x128
  short* WBc2 = WB + 16384;     // 256x896
  short* WBe1 = WB + 245760;    // 256x768
  short* WBe2 = WB + 442368;    // 256x256
  short* WBqk = WB + 507904;    // 6 x 768x256
  short* WBwo = WB + 1687552;   // 6 x 256x256
  short* WBw1 = WB + 2080768;   // 6 x 1024x256
  short* WBw2 = WB + 3653632;   // 6 x 256x1024

  // BIG sub-layouts
  float* XMEL = BIG;                       // (B,16,2000)
  short* A1B  = (short*)(BIG + 1024000);   // (32000,128) bf16
  float* H1   = BIG + 3072000;             // (B,1000,128)
  short* A2B  = (short*)(BIG + 7168000);   // (16000,896) bf16
  float* XPRE = BIG;                       // (B,S,256)
  short* COMBB= (short*)BIG;               // (8192,768) bf16
  short* EHIDB= (short*)(BIG + 3146000);   // (8192,256) bf16
  float* EVO  = BIG + 4195000;             // (8192,256) fp32
  short* QKVB = (short*)BIG;               // (16000,768) bf16
  short* HIDB = (short*)(BIG + 7168000);   // (16000,1024) bf16

  // ---- weight conversion ----
  conv1w_pad<<<128, 128, 0, stream>>>(conv1_w, WBc1);
  f2b_kernel<<<896, 256, 0, stream>>>(conv2_w, WBc2, 229376);
  f2b_kernel<<<768, 256, 0, stream>>>(ep_W1, WBe1, 196608);
  f2b_kernel<<<256, 256, 0, stream>>>(ep_W2, WBe2, 65536);
  f2b_kernel<<<4608, 256, 0, stream>>>(tl_Wqkv, WBqk, 1179648);
  f2b_kernel<<<1536, 256, 0, stream>>>(tl_Wo, WBwo, 393216);
  f2b_kernel<<<6144, 256, 0, stream>>>(tl_W1, WBw1, 1572864);
  f2b_kernel<<<6144, 256, 0, stream>>>(tl_W2, WBw2, 1572864);

  // ---- prologue ----
  mel_kernel<<<kB*8, 256, 0, stream>>>(mel, mel_W, mel_b, XMEL);
  im2col1b<<<16000, 256, 0, stream>>>(XMEL, A1B);
  gemm_mfma<0,true><<<dim3(1, 250), 256, 0, stream>>>(A1B, WBc1, conv1_b, H1, 32000, 128, 128);
  gn_part<<<256, 256, 0, stream>>>(H1, PART);
  gn_final<<<1, 256, 0, stream>>>(PART, STATS);
  im2col2b<<<56000, 256, 0, stream>>>(H1, STATS, gn_g, gn_b, A2B);
  gemm_mfma<0,true><<<dim3(2, 125), 256, 0, stream>>>(A2B, WBc2, conv2_b, XPRE, 16000, 256, 896);
  postconv<<<16000, 256, 0, stream>>>(XPRE, cn_g, cn_b, star, star_tab, X);
  // events
  event_feat<<<kB*256, 256, 0, stream>>>(events, COMBB);
  gemm_mfma<2,true><<<dim3(2, 64), 256, 0, stream>>>(COMBB, WBe1, ep_b1, EHIDB, 8192, 256, 768);
  gemm_mfma<0,false><<<dim3(2, 64), 256, 0, stream>>>(EHIDB, WBe2, ep_b2, EVO, 8192, 256, 256);
  ev_scatter<<<kB*256, 256, 0, stream>>>(EVO, events, emask, X);

  // ---- transformer layers ----
  ln_rows<<<16000, 256, 0, stream>>>(X, tl_ln1g, tl_ln1b, XNB);   // ln1[0]
  for(int i = 0; i < 6; ++i){
    gemm512<false><<<dim3(3, 125), 512, 0, stream>>>(XNB, WBqk + (size_t)i*196608, tl_bqkv + i*768, QKVB, 16000, 768, 256);
    attn_mfma<<<kB*kH, 512, 0, stream>>>(QKVB, OB);
    gemm_ln<true><<<dim3(1, 250), 512, 0, stream>>>(OB, WBwo + (size_t)i*65536, tl_bo + i*256,
        X, tl_ln2g + i*256, tl_ln2b + i*256, XNB, 16000, 256);
    gemm512<true><<<dim3(4, 125), 512, 0, stream>>>(XNB, WBw1 + (size_t)i*262144, tl_b1 + i*1024, HIDB, 16000, 1024, 256);
    if(i < 5)
      gemm_ln<true><<<dim3(1, 250), 512, 0, stream>>>(HIDB, WBw2 + (size_t)i*262144, tl_b2 + i*256,
          X, tl_ln1g + (i+1)*256, tl_ln1b + (i+1)*256, XNB, 16000, 1024);
    else
      gemm_ln<false><<<dim3(1, 250), 512, 0, stream>>>(HIDB, WBw2 + (size_t)i*262144, tl_b2 + i*256,
          X, tl_ln1g, tl_ln1b, XNB, 16000, 1024);
  }

  // ---- pooling + head ----
  pool_head<<<kB, 256, 0, stream>>>(X, pool_q, on_g, on_b, oh_W, oh_b, (float*)d_out);
}